// Round 2
// baseline (10036.381 us; speedup 1.0000x reference)
//
#include <hip/hip_runtime.h>
#include <cstddef>
#include <cstdint>

// ---------------------------------------------------------------------------
// STSN (slot-attention scene network) forward, fp32 baseline v2.
// B=32, H=W=80, C=32, S=9, ITERS=3
// Workspace trimmed to 114 MB via buffer reuse (prev 273 MB -> core dump).
// ---------------------------------------------------------------------------

namespace {

constexpr int Bb  = 32;
constexpr int HWp = 6400;   // 80*80
constexpr int Cc  = 32;
constexpr float SCALEf = 0.17677669529663687f;  // 32^-0.5

// output section offsets (floats), concatenated in return order
constexpr size_t O_COMB  = 0;          // (32,1,80,80)    204800
constexpr size_t O_RECON = 204800;     // (32,9,1,80,80) 1843200
constexpr size_t O_MASK  = 2048000;    // (32,9,1,80,80) 1843200
constexpr size_t O_SLOTS = 3891200;    // (32,9,32)         9216
constexpr size_t O_ATTN  = 3900416;    // (32,9,1,80,80) 1843200

// workspace layout (float offsets) — total 28,504,000 floats = 114.0 MB
constexpr size_t W_PEENC = 0;                       // 204800   [hw][c]
constexpr size_t W_PEDEC = W_PEENC + 204800;        // 204800   [c][hw]
constexpr size_t W_A     = W_PEDEC + 204800;        // 6553600  ping (enc, h, dec chunks)
constexpr size_t W_B     = W_A     + 6553600;       // 6553600  pong
constexpr size_t W_KEYS  = W_B     + 6553600;       // 6553600  [b][hw][c]
constexpr size_t W_VALS  = W_KEYS  + 6553600;       // 6553600  [b][hw][c]
constexpr size_t W_ATTNT = W_VALS  + 6553600;       // 1843200  unnormalized attn [b][i][j]
constexpr size_t W_LNPART= W_ATTNT + 1843200;       // 1600
constexpr size_t W_MEANR = W_LNPART+ 1600;          // 64
constexpr size_t W_Q     = W_MEANR + 64;            // 9216
constexpr size_t W_SLOTS = W_Q     + 9216;          // 9216
constexpr size_t W_APART = W_SLOTS + 9216;          // 7200
constexpr size_t W_RSUM  = W_APART + 7200;          // 288
constexpr size_t W_UPD   = W_RSUM  + 288;           // 9216
constexpr size_t W_TOTAL = W_UPD   + 9216;          // 28,504,000 floats

// ---------------- small per-thread helpers (fully unrolled, reg-resident) ----

__device__ __forceinline__ void ln32v(const float* x, const float* __restrict__ g,
                                      const float* __restrict__ b, float* y) {
  float m = 0.f;
#pragma unroll
  for (int c = 0; c < 32; ++c) m += x[c];
  m *= (1.f / 32.f);
  float v = 0.f;
#pragma unroll
  for (int c = 0; c < 32; ++c) { float d = x[c] - m; v += d * d; }
  v *= (1.f / 32.f);
  float rs = rsqrtf(v + 1e-5f);
#pragma unroll
  for (int c = 0; c < 32; ++c) y[c] = (x[c] - m) * rs * g[c] + b[c];
}

__device__ __forceinline__ void matvec32(const float* __restrict__ W,
                                         const float* __restrict__ bias,
                                         const float* x, float* y, bool relu) {
#pragma unroll
  for (int o = 0; o < 32; ++o) {
    float a = bias[o];
#pragma unroll
    for (int c = 0; c < 32; ++c) a = fmaf(x[c], W[o * 32 + c], a);
    y[o] = relu ? fmaxf(a, 0.f) : a;
  }
}

// ---------------- positional-embedding maps ---------------------------------

__global__ void k_pe_maps(const float* __restrict__ pew_e, const float* __restrict__ peb_e,
                          const float* __restrict__ pew_d, const float* __restrict__ peb_d,
                          float* __restrict__ pe_enc, float* __restrict__ pe_dec) {
  int hw = blockIdx.x * 256 + threadIdx.x;
  if (hw >= HWp) return;
  int y = hw / 80, x = hw % 80;
  float g0 = y * (1.f / 79.f), g1 = x * (1.f / 79.f);
  float g2 = 1.f - g0, g3 = 1.f - g1;
#pragma unroll
  for (int c = 0; c < 32; ++c) {
    float e = peb_e[c] + g0 * pew_e[c * 4] + g1 * pew_e[c * 4 + 1] +
              g2 * pew_e[c * 4 + 2] + g3 * pew_e[c * 4 + 3];
    pe_enc[(size_t)hw * 32 + c] = e;
    float d = peb_d[c] + g0 * pew_d[c * 4] + g1 * pew_d[c * 4 + 1] +
              g2 * pew_d[c * 4 + 2] + g3 * pew_d[c * 4 + 3];
    pe_dec[(size_t)c * HWp + hw] = d;
  }
}

// ---------------- generic direct conv (also handles convT via TRANS) --------
// tile 16x16 pixels, 128 threads, each thread 2 vertically-adjacent pixels,
// all COUT channels. Input plane for current cin staged in LDS; weights read
// with wave-uniform indices (scalar loads). SPLIT: COUT==2 planes go to two
// separate output tensors (recon / mask-logit regions of d_out).

template <int CIN, int COUT, int K, int PAD, bool TRANS, bool RELU, bool SPLIT>
__global__ __launch_bounds__(128) void k_conv(const float* __restrict__ in,
                                              const float* __restrict__ w,
                                              const float* __restrict__ bias,
                                              float* __restrict__ out,
                                              float* __restrict__ out2) {
  constexpr int TILE = 16;
  constexpr int PW = TILE + K - 1;
  __shared__ float plane[PW * PW];
  const int n = blockIdx.y;
  const int ty = blockIdx.x / 5, tx = blockIdx.x % 5;
  const int gy0 = ty * TILE - PAD, gx0 = tx * TILE - PAD;
  const int t = threadIdx.x;
  const int px = t & 15, py = t >> 4;  // py 0..7 -> rows 2*py, 2*py+1
  float acc0[COUT], acc1[COUT];
#pragma unroll
  for (int co = 0; co < COUT; ++co) { acc0[co] = 0.f; acc1[co] = 0.f; }
  const float* inp = in + (size_t)n * CIN * HWp;
  for (int ci = 0; ci < CIN; ++ci) {
    __syncthreads();
    for (int e = t; e < PW * PW; e += 128) {
      int rr = e / PW, cc = e % PW;
      int gy = gy0 + rr, gx = gx0 + cc;
      plane[e] = (gy >= 0 && gy < 80 && gx >= 0 && gx < 80) ? inp[(size_t)ci * HWp + gy * 80 + gx] : 0.f;
    }
    __syncthreads();
    float xv[(K + 1) * K];
#pragma unroll
    for (int rr = 0; rr < K + 1; ++rr)
#pragma unroll
      for (int cc = 0; cc < K; ++cc)
        xv[rr * K + cc] = plane[(2 * py + rr) * PW + px + cc];
#pragma unroll
    for (int co = 0; co < COUT; ++co) {
#pragma unroll
      for (int ky = 0; ky < K; ++ky) {
#pragma unroll
        for (int kx = 0; kx < K; ++kx) {
          float wv = TRANS ? w[((size_t)ci * COUT + co) * (K * K) + (K - 1 - ky) * K + (K - 1 - kx)]
                           : w[((size_t)co * CIN + ci) * (K * K) + ky * K + kx];
          acc0[co] = fmaf(xv[ky * K + kx], wv, acc0[co]);
          acc1[co] = fmaf(xv[(ky + 1) * K + kx], wv, acc1[co]);
        }
      }
    }
  }
  const int oy = ty * TILE + 2 * py, ox = tx * TILE + px;
#pragma unroll
  for (int co = 0; co < COUT; ++co) {
    float bv = bias[co];
    float v0 = acc0[co] + bv, v1 = acc1[co] + bv;
    if (RELU) { v0 = fmaxf(v0, 0.f); v1 = fmaxf(v1, 0.f); }
    float* op;
    if (SPLIT) {
      op = (co == 0 ? out : out2) + (size_t)n * HWp + oy * 80 + ox;
    } else {
      op = out + ((size_t)n * COUT + co) * HWp + oy * 80 + ox;
    }
    op[0]  = v0;
    op[80] = v1;
  }
}

// ---------------- h = transpose(conv4) + PE ; big-LN partial stats ----------

__global__ __launch_bounds__(256) void k_hstats(const float* __restrict__ enc,
                                                const float* __restrict__ pe_enc,
                                                float* __restrict__ hbuf,
                                                float* __restrict__ lnpart) {
  int b = blockIdx.y;
  int hw = blockIdx.x * 256 + threadIdx.x;
  const float* ep = enc + (size_t)b * Cc * HWp + hw;
  float v[32];
  float s = 0.f, ss = 0.f;
#pragma unroll
  for (int c = 0; c < 32; ++c) v[c] = ep[(size_t)c * HWp];
#pragma unroll
  for (int c = 0; c < 32; ++c) {
    v[c] += pe_enc[(size_t)hw * 32 + c];
    s += v[c];
    ss += v[c] * v[c];
  }
  float* hp = hbuf + ((size_t)b * HWp + hw) * 32;
#pragma unroll
  for (int c = 0; c < 32; ++c) hp[c] = v[c];
  __shared__ float r1[256], r2[256];
  r1[threadIdx.x] = s; r2[threadIdx.x] = ss;
  __syncthreads();
  for (int off = 128; off > 0; off >>= 1) {
    if (threadIdx.x < off) { r1[threadIdx.x] += r1[threadIdx.x + off]; r2[threadIdx.x] += r2[threadIdx.x + off]; }
    __syncthreads();
  }
  if (threadIdx.x == 0) {
    lnpart[(size_t)(b * 25 + blockIdx.x) * 2]     = r1[0];
    lnpart[(size_t)(b * 25 + blockIdx.x) * 2 + 1] = r2[0];
  }
}

__global__ void k_statsfin(const float* __restrict__ lnpart, float* __restrict__ meanr) {
  int b = threadIdx.x;
  if (b >= 32) return;
  float s = 0.f, ss = 0.f;
  for (int k = 0; k < 25; ++k) {
    s  += lnpart[(size_t)(b * 25 + k) * 2];
    ss += lnpart[(size_t)(b * 25 + k) * 2 + 1];
  }
  float m = s * (1.f / 204800.f);
  float var = ss * (1.f / 204800.f) - m * m;
  meanr[b * 2]     = m;
  meanr[b * 2 + 1] = rsqrtf(var + 1e-5f);
}

// ---------------- big-LN apply + MLP + per-pos LN + K/V ----------------------

__global__ __launch_bounds__(256) void k_lnmlpkv(
    const float* __restrict__ hbuf, const float* __restrict__ meanr,
    const float* __restrict__ g, const float* __restrict__ bb,
    const float* __restrict__ w1, const float* __restrict__ b1,
    const float* __restrict__ w2, const float* __restrict__ b2,
    const float* __restrict__ nig, const float* __restrict__ nib,
    const float* __restrict__ kw, const float* __restrict__ kb,
    const float* __restrict__ vw, const float* __restrict__ vb,
    float* __restrict__ keys, float* __restrict__ vals) {
  int b = blockIdx.y;
  int hw = blockIdx.x * 256 + threadIdx.x;
  float x[32], t0[32], t1[32];
  const float* hp = hbuf + ((size_t)b * HWp + hw) * 32;
  float m = meanr[b * 2], rs = meanr[b * 2 + 1];
#pragma unroll
  for (int c = 0; c < 32; ++c)
    x[c] = (hp[c] - m) * rs * g[(size_t)hw * 32 + c] + bb[(size_t)hw * 32 + c];
  matvec32(w1, b1, x, t0, true);
  matvec32(w2, b2, t0, t1, false);
  ln32v(t1, nig, nib, x);  // x := xn
  matvec32(kw, kb, x, t0, false);
  float* kp = keys + ((size_t)b * HWp + hw) * 32;
#pragma unroll
  for (int c = 0; c < 32; ++c) kp[c] = t0[c];
  matvec32(vw, vb, x, t0, false);
  float* vp = vals + ((size_t)b * HWp + hw) * 32;
#pragma unroll
  for (int c = 0; c < 32; ++c) vp[c] = t0[c];
}

// ---------------- slots init -------------------------------------------------

__global__ void k_slots_init(const float* __restrict__ mu, const float* __restrict__ sig,
                             const float* __restrict__ noise, float* __restrict__ slots) {
  int i = blockIdx.x * 256 + threadIdx.x;
  if (i >= 288 * 32) return;
  int c = i & 31;
  slots[i] = mu[c] + sig[c] * noise[i];
}

// ---------------- q = LN(slots) @ q_w^T + q_b --------------------------------

__global__ void k_q(const float* __restrict__ slots, const float* __restrict__ nsg,
                    const float* __restrict__ nsb, const float* __restrict__ qw,
                    const float* __restrict__ qb, float* __restrict__ qbuf) {
  int r = blockIdx.x * 64 + threadIdx.x;
  if (r >= 288) return;
  float x[32], y[32];
#pragma unroll
  for (int c = 0; c < 32; ++c) x[c] = slots[(size_t)r * 32 + c];
  ln32v(x, nsg, nsb, y);
  matvec32(qw, qb, y, x, false);
#pragma unroll
  for (int c = 0; c < 32; ++c) qbuf[(size_t)r * 32 + c] = x[c];
}

// ---------------- dots + softmax-over-slots + per-slot block sums -----------

__global__ __launch_bounds__(256) void k_dots(const float* __restrict__ qbuf,
                                              const float* __restrict__ keys,
                                              float* __restrict__ attnt,
                                              float* __restrict__ apart) {
  int b = blockIdx.y;
  int j = blockIdx.x * 256 + threadIdx.x;
  __shared__ float qs[288];
  for (int e = threadIdx.x; e < 288; e += 256) qs[e] = qbuf[(size_t)b * 288 + e];
  __syncthreads();
  float k[32];
  const float* kp = keys + ((size_t)b * HWp + j) * 32;
#pragma unroll
  for (int c = 0; c < 32; ++c) k[c] = kp[c];
  float d[9];
#pragma unroll
  for (int i = 0; i < 9; ++i) {
    float a = 0.f;
#pragma unroll
    for (int c = 0; c < 32; ++c) a = fmaf(qs[i * 32 + c], k[c], a);
    d[i] = a * SCALEf;
  }
  float mx = d[0];
#pragma unroll
  for (int i = 1; i < 9; ++i) mx = fmaxf(mx, d[i]);
  float sum = 0.f;
#pragma unroll
  for (int i = 0; i < 9; ++i) { d[i] = __expf(d[i] - mx); sum += d[i]; }
  float inv = 1.f / sum;
  float a[9];
#pragma unroll
  for (int i = 0; i < 9; ++i) {
    a[i] = d[i] * inv + 1e-8f;
    attnt[((size_t)b * 9 + i) * HWp + j] = a[i];
  }
  int lane = threadIdx.x & 63, wid = threadIdx.x >> 6;
  __shared__ float wr[4 * 9];
#pragma unroll
  for (int i = 0; i < 9; ++i) {
    float v = a[i];
    for (int off = 32; off > 0; off >>= 1) v += __shfl_down(v, off);
    if (lane == 0) wr[wid * 9 + i] = v;
  }
  __syncthreads();
  if (threadIdx.x < 9) {
    float v = wr[threadIdx.x] + wr[9 + threadIdx.x] + wr[18 + threadIdx.x] + wr[27 + threadIdx.x];
    apart[(size_t)(b * 9 + threadIdx.x) * 25 + blockIdx.x] = v;
  }
}

// ---------------- upd = (values^T @ attnt) / rowsum --------------------------

__global__ __launch_bounds__(256) void k_upd(const float* __restrict__ vals,
                                             const float* __restrict__ attnt,
                                             const float* __restrict__ apart,
                                             float* __restrict__ rowsum,
                                             float* __restrict__ upd) {
  int b = blockIdx.y, i = blockIdx.x;
  __shared__ float rbuf[32];
  if (threadIdx.x < 32)
    rbuf[threadIdx.x] = (threadIdx.x < 25) ? apart[(size_t)(b * 9 + i) * 25 + threadIdx.x] : 0.f;
  __syncthreads();
  if (threadIdx.x == 0) {
    float s = 0.f;
    for (int k = 0; k < 25; ++k) s += rbuf[k];
    rbuf[0] = s;
    rowsum[b * 9 + i] = s;
  }
  __syncthreads();
  float rs = rbuf[0];
  int c = threadIdx.x & 31, gg = threadIdx.x >> 5;
  float acc = 0.f;
  const float* vp = vals + (size_t)b * HWp * 32;
  const float* ap = attnt + ((size_t)b * 9 + i) * HWp;
  for (int j = gg; j < HWp; j += 8) acc = fmaf(vp[(size_t)j * 32 + c], ap[j], acc);
  __shared__ float red[256];
  red[threadIdx.x] = acc;
  __syncthreads();
  if (threadIdx.x < 32) {
    float s = red[c];
    for (int g2 = 1; g2 < 8; ++g2) s += red[g2 * 32 + c];
    upd[(size_t)(b * 9 + i) * 32 + c] = s / rs;
  }
}

// ---------------- GRU + residual MLP ----------------------------------------

__global__ void k_gru_res(const float* __restrict__ upd, float* __restrict__ slots,
                          const float* __restrict__ wih, const float* __restrict__ whh,
                          const float* __restrict__ bih, const float* __restrict__ bhh,
                          const float* __restrict__ rlg, const float* __restrict__ rlb,
                          const float* __restrict__ rw1, const float* __restrict__ rb1,
                          const float* __restrict__ rw2, const float* __restrict__ rb2) {
  int r = blockIdx.x * 64 + threadIdx.x;
  if (r >= 288) return;
  float u[32], h[32];
#pragma unroll
  for (int c = 0; c < 32; ++c) { u[c] = upd[(size_t)r * 32 + c]; h[c] = slots[(size_t)r * 32 + c]; }
  float rr[32], zz[32];
#pragma unroll
  for (int o = 0; o < 32; ++o) {
    float xr = bih[o], hr = bhh[o];
#pragma unroll
    for (int c = 0; c < 32; ++c) { xr = fmaf(u[c], wih[o * 32 + c], xr); hr = fmaf(h[c], whh[o * 32 + c], hr); }
    rr[o] = 1.f / (1.f + __expf(-(xr + hr)));
  }
#pragma unroll
  for (int o = 0; o < 32; ++o) {
    float xz = bih[32 + o], hz = bhh[32 + o];
#pragma unroll
    for (int c = 0; c < 32; ++c) { xz = fmaf(u[c], wih[(32 + o) * 32 + c], xz); hz = fmaf(h[c], whh[(32 + o) * 32 + c], hz); }
    zz[o] = 1.f / (1.f + __expf(-(xz + hz)));
  }
  float sm[32];
#pragma unroll
  for (int o = 0; o < 32; ++o) {
    float xc = bih[64 + o], hc = bhh[64 + o];
#pragma unroll
    for (int c = 0; c < 32; ++c) { xc = fmaf(u[c], wih[(64 + o) * 32 + c], xc); hc = fmaf(h[c], whh[(64 + o) * 32 + c], hc); }
    float cand = tanhf(xc + rr[o] * hc);
    sm[o] = (1.f - zz[o]) * cand + zz[o] * h[o];
  }
  float t[32], t1[32];
  ln32v(sm, rlg, rlb, t);
  matvec32(rw1, rb1, t, t1, true);
  matvec32(rw2, rb2, t1, t, false);
#pragma unroll
  for (int c = 0; c < 32; ++c) slots[(size_t)r * 32 + c] = sm[c] + t[c];
}

// ---------------- attn + slots outputs --------------------------------------

__global__ void k_attn_out(const float* __restrict__ attnt, const float* __restrict__ rsum,
                           float* __restrict__ out) {
  size_t idx = (size_t)blockIdx.x * 256 + threadIdx.x;  // < 1843200
  out[O_ATTN + idx] = attnt[idx] / rsum[idx / HWp];
}

__global__ void k_slots_out(const float* __restrict__ slots, float* __restrict__ out) {
  int idx = blockIdx.x * 256 + threadIdx.x;
  if (idx < 9216) out[O_SLOTS + idx] = slots[idx];
}

// ---------------- decoder input ----------------------------------------------

__global__ __launch_bounds__(256) void k_d0(const float* __restrict__ slots,
                                            const float* __restrict__ pe_dec,
                                            float* __restrict__ dst, int n0) {
  int hw = blockIdx.x * 256 + threadIdx.x;
  int nl = blockIdx.y;
  const float* sp = slots + (size_t)(n0 + nl) * 32;
  float* dp = dst + (size_t)nl * Cc * HWp + hw;
#pragma unroll
  for (int c = 0; c < 32; ++c) dp[(size_t)c * HWp] = sp[c] + pe_dec[(size_t)c * HWp + hw];
}

// ---------------- final mask softmax / combine -------------------------------
// recon already in out[O_RECON]; raw mask logits staged in out[O_MASK].
// Each thread reads its 9 logits and overwrites them with softmax (no hazard).

__global__ __launch_bounds__(256) void k_final(float* __restrict__ out) {
  int b = blockIdx.y;
  int j = blockIdx.x * 256 + threadIdx.x;
  float r[9], ml[9];
#pragma unroll
  for (int s = 0; s < 9; ++s) {
    r[s]  = out[O_RECON + (size_t)(b * 9 + s) * HWp + j];
    ml[s] = out[O_MASK  + (size_t)(b * 9 + s) * HWp + j];
  }
  float mx = ml[0];
#pragma unroll
  for (int s = 1; s < 9; ++s) mx = fmaxf(mx, ml[s]);
  float sum = 0.f;
#pragma unroll
  for (int s = 0; s < 9; ++s) { ml[s] = __expf(ml[s] - mx); sum += ml[s]; }
  float inv = 1.f / sum;
  float comb = 0.f;
#pragma unroll
  for (int s = 0; s < 9; ++s) {
    float mk = ml[s] * inv;
    comb = fmaf(r[s], mk, comb);
    out[O_MASK + (size_t)(b * 9 + s) * HWp + j] = mk;
  }
  out[O_COMB + (size_t)b * HWp + j] = comb;
}

}  // namespace

// ---------------------------------------------------------------------------

extern "C" void kernel_launch(void* const* d_in, const int* in_sizes, int n_in,
                              void* d_out, int out_size, void* d_ws, size_t ws_size,
                              hipStream_t stream) {
  if (ws_size < W_TOTAL * sizeof(float)) return;  // diagnostic: fail cleanly, not core-dump

  const float* in_x       = (const float*)d_in[0];
  const float* slot_noise = (const float*)d_in[1];
  const float* enc_w1 = (const float*)d_in[2];   const float* enc_b1 = (const float*)d_in[3];
  const float* enc_w2 = (const float*)d_in[4];   const float* enc_b2 = (const float*)d_in[5];
  const float* enc_w3 = (const float*)d_in[6];   const float* enc_b3 = (const float*)d_in[7];
  const float* enc_w4 = (const float*)d_in[8];   const float* enc_b4 = (const float*)d_in[9];
  const float* pe_enc_w = (const float*)d_in[10]; const float* pe_enc_b = (const float*)d_in[11];
  const float* ln_enc_g = (const float*)d_in[12]; const float* ln_enc_b = (const float*)d_in[13];
  const float* mlp_w1 = (const float*)d_in[14];  const float* mlp_b1 = (const float*)d_in[15];
  const float* mlp_w2 = (const float*)d_in[16];  const float* mlp_b2 = (const float*)d_in[17];
  const float* slots_mu = (const float*)d_in[18]; const float* slots_sigma = (const float*)d_in[19];
  const float* ni_g = (const float*)d_in[20];    const float* ni_b = (const float*)d_in[21];
  const float* ns_g = (const float*)d_in[22];    const float* ns_b = (const float*)d_in[23];
  const float* q_w = (const float*)d_in[24];     const float* q_b = (const float*)d_in[25];
  const float* k_w = (const float*)d_in[26];     const float* k_b = (const float*)d_in[27];
  const float* v_w = (const float*)d_in[28];     const float* v_b = (const float*)d_in[29];
  const float* gru_wih = (const float*)d_in[30]; const float* gru_whh = (const float*)d_in[31];
  const float* gru_bih = (const float*)d_in[32]; const float* gru_bhh = (const float*)d_in[33];
  const float* res_ln_g = (const float*)d_in[34]; const float* res_ln_b = (const float*)d_in[35];
  const float* res_w1 = (const float*)d_in[36];  const float* res_b1 = (const float*)d_in[37];
  const float* res_w2 = (const float*)d_in[38];  const float* res_b2 = (const float*)d_in[39];
  const float* pe_dec_w = (const float*)d_in[40]; const float* pe_dec_b = (const float*)d_in[41];
  const float* dec_w1 = (const float*)d_in[42];  const float* dec_b1 = (const float*)d_in[43];
  const float* dec_w2 = (const float*)d_in[44];  const float* dec_b2 = (const float*)d_in[45];
  const float* dec_w3 = (const float*)d_in[46];  const float* dec_b3 = (const float*)d_in[47];
  const float* dec_w4 = (const float*)d_in[48];  const float* dec_b4 = (const float*)d_in[49];

  float* ws  = (float*)d_ws;
  float* out = (float*)d_out;

  // PE maps (shared by encoder-add and decoder-broadcast)
  k_pe_maps<<<dim3(25), 256, 0, stream>>>(pe_enc_w, pe_enc_b, pe_dec_w, pe_dec_b,
                                          ws + W_PEENC, ws + W_PEDEC);

  // ---------------- encoder (ping-pong A/B) ----------------
  k_conv<1, 32, 5, 2, false, true, false><<<dim3(25, Bb), 128, 0, stream>>>(in_x, enc_w1, enc_b1, ws + W_A, nullptr);
  k_conv<32, 32, 5, 2, false, true, false><<<dim3(25, Bb), 128, 0, stream>>>(ws + W_A, enc_w2, enc_b2, ws + W_B, nullptr);
  k_conv<32, 32, 5, 2, false, true, false><<<dim3(25, Bb), 128, 0, stream>>>(ws + W_B, enc_w3, enc_b3, ws + W_A, nullptr);
  k_conv<32, 32, 5, 2, false, true, false><<<dim3(25, Bb), 128, 0, stream>>>(ws + W_A, enc_w4, enc_b4, ws + W_B, nullptr);

  // h = transpose(conv4 in B) + PE -> A ; per-batch LN stats
  k_hstats<<<dim3(25, Bb), 256, 0, stream>>>(ws + W_B, ws + W_PEENC, ws + W_A, ws + W_LNPART);
  k_statsfin<<<dim3(1), 64, 0, stream>>>(ws + W_LNPART, ws + W_MEANR);
  k_lnmlpkv<<<dim3(25, Bb), 256, 0, stream>>>(ws + W_A, ws + W_MEANR, ln_enc_g, ln_enc_b,
                                              mlp_w1, mlp_b1, mlp_w2, mlp_b2,
                                              ni_g, ni_b, k_w, k_b, v_w, v_b,
                                              ws + W_KEYS, ws + W_VALS);

  // ---------------- slot attention ----------------
  k_slots_init<<<dim3(36), 256, 0, stream>>>(slots_mu, slots_sigma, slot_noise, ws + W_SLOTS);
  for (int it = 0; it < 3; ++it) {
    k_q<<<dim3(5), 64, 0, stream>>>(ws + W_SLOTS, ns_g, ns_b, q_w, q_b, ws + W_Q);
    k_dots<<<dim3(25, Bb), 256, 0, stream>>>(ws + W_Q, ws + W_KEYS, ws + W_ATTNT, ws + W_APART);
    k_upd<<<dim3(9, Bb), 256, 0, stream>>>(ws + W_VALS, ws + W_ATTNT, ws + W_APART,
                                           ws + W_RSUM, ws + W_UPD);
    k_gru_res<<<dim3(5), 64, 0, stream>>>(ws + W_UPD, ws + W_SLOTS, gru_wih, gru_whh,
                                          gru_bih, gru_bhh, res_ln_g, res_ln_b,
                                          res_w1, res_b1, res_w2, res_b2);
  }
  k_attn_out<<<dim3(7200), 256, 0, stream>>>(ws + W_ATTNT, ws + W_RSUM, out);
  k_slots_out<<<dim3(36), 256, 0, stream>>>(ws + W_SLOTS, out);

  // ---------------- decoder: 9 chunks of 32 images, reuse A/B ----------------
  for (int ch = 0; ch < 9; ++ch) {
    int n0 = ch * 32;
    k_d0<<<dim3(25, 32), 256, 0, stream>>>(ws + W_SLOTS, ws + W_PEDEC, ws + W_A, n0);
    k_conv<32, 32, 5, 2, true, true, false><<<dim3(25, 32), 128, 0, stream>>>(ws + W_A, dec_w1, dec_b1, ws + W_B, nullptr);
    k_conv<32, 32, 5, 2, true, true, false><<<dim3(25, 32), 128, 0, stream>>>(ws + W_B, dec_w2, dec_b2, ws + W_A, nullptr);
    k_conv<32, 32, 5, 2, true, true, false><<<dim3(25, 32), 128, 0, stream>>>(ws + W_A, dec_w3, dec_b3, ws + W_B, nullptr);
    k_conv<32, 2, 3, 1, true, false, true><<<dim3(25, 32), 128, 0, stream>>>(
        ws + W_B, dec_w4, dec_b4, out + O_RECON + (size_t)n0 * HWp, out + O_MASK + (size_t)n0 * HWp);
  }

  k_final<<<dim3(25, Bb), 256, 0, stream>>>(out);
}

// Round 3
// 1570.090 us; speedup vs baseline: 6.3922x; 6.3922x over previous
//
#include <hip/hip_runtime.h>
#include <cstddef>
#include <cstdint>

// ---------------------------------------------------------------------------
// STSN forward, v3: bf16-MFMA convs + algebraic decoder-conv1 elimination.
// B=32, H=W=80, C=32, S=9, ITERS=3
// ---------------------------------------------------------------------------

namespace {

constexpr int Bb  = 32;
constexpr int HWp = 6400;   // 80*80
constexpr float SCALEf = 0.17677669529663687f;  // 32^-0.5

// output section offsets (floats)
constexpr size_t O_COMB  = 0;          // (32,1,80,80)
constexpr size_t O_RECON = 204800;     // (32,9,1,80,80)
constexpr size_t O_MASK  = 2048000;
constexpr size_t O_SLOTS = 3891200;
constexpr size_t O_ATTN  = 3900416;

// workspace layout (float offsets) — total 116.5 MB
constexpr size_t W_PEENC = 0;                 // 204800   [hw][c] fp32
constexpr size_t W_PEDEC = 204800;            // 204800   [c][hw] fp32
constexpr size_t W_BASE  = 409600;            // 204800 region, used as bf16 [c][hw]
constexpr size_t W_TC    = 614400;            // 25600  (25 cls x 32ci x 32co)
constexpr size_t W_TS    = 640000;            // 230400 (288 img x 25 cls x 32co)
constexpr size_t W_WP    = 870400;            // 76800 floats = 153600 bf16 packed weights
constexpr size_t W_LNPART= 947200;            // 1600
constexpr size_t W_MEANR = 948800;            // 64
constexpr size_t W_Q     = 948864;            // 9216
constexpr size_t W_SLOTS = 958080;            // 9216
constexpr size_t W_APART = 967296;            // 7200
constexpr size_t W_RSUM  = 974496;            // 288
constexpr size_t W_UPD   = 974784;            // 9216
constexpr size_t W_UP2   = 984000;            // 73728 (32b x 8jc x 9 x 32)
constexpr size_t W_A     = 1057728;           // 6553600 fp32 (enc ping; dec bf16 pool start)
constexpr size_t W_B     = 7611328;           // 6553600 fp32 (enc pong)
constexpr size_t W_KEYS  = 14164928;          // 6553600
constexpr size_t W_VALS  = 20718528;          // 6553600
constexpr size_t W_ATTNT = 27272128;          // 1843200
constexpr size_t W_TOTAL = 29115328;          // floats = 116.5 MB
// Decoder bf16 pool aliases [W_A, W_TOTAL): 112.2 MB >= 2 x 39.3 MB (96-img chunks).

typedef __attribute__((ext_vector_type(8))) short short8;   // 8 bf16 = 16B
typedef __attribute__((ext_vector_type(4))) float f32x4;

__device__ __forceinline__ ushort f2bf(float f) {
  uint u = __builtin_bit_cast(uint, f);
  uint r = (u + 0x7fffu + ((u >> 16) & 1u)) >> 16;   // RNE
  return (ushort)r;
}
__device__ __forceinline__ float bf2f(ushort b) {
  uint u = ((uint)b) << 16;
  return __builtin_bit_cast(float, u);
}

__device__ __forceinline__ void ln32v(const float* x, const float* __restrict__ g,
                                      const float* __restrict__ b, float* y) {
  float m = 0.f;
#pragma unroll
  for (int c = 0; c < 32; ++c) m += x[c];
  m *= (1.f / 32.f);
  float v = 0.f;
#pragma unroll
  for (int c = 0; c < 32; ++c) { float d = x[c] - m; v += d * d; }
  v *= (1.f / 32.f);
  float rs = rsqrtf(v + 1e-5f);
#pragma unroll
  for (int c = 0; c < 32; ++c) y[c] = (x[c] - m) * rs * g[c] + b[c];
}

__device__ __forceinline__ void matvec32(const float* __restrict__ W,
                                         const float* __restrict__ bias,
                                         const float* x, float* y, bool relu) {
#pragma unroll
  for (int o = 0; o < 32; ++o) {
    float a = bias[o];
#pragma unroll
    for (int c = 0; c < 32; ++c) a = fmaf(x[c], W[o * 32 + c], a);
    y[o] = relu ? fmaxf(a, 0.f) : a;
  }
}

// ---------------- positional-embedding maps ---------------------------------

__global__ void k_pe_maps(const float* __restrict__ pew_e, const float* __restrict__ peb_e,
                          const float* __restrict__ pew_d, const float* __restrict__ peb_d,
                          float* __restrict__ pe_enc, float* __restrict__ pe_dec) {
  int hw = blockIdx.x * 256 + threadIdx.x;
  if (hw >= HWp) return;
  int y = hw / 80, x = hw % 80;
  float g0 = y * (1.f / 79.f), g1 = x * (1.f / 79.f);
  float g2 = 1.f - g0, g3 = 1.f - g1;
#pragma unroll
  for (int c = 0; c < 32; ++c) {
    pe_enc[(size_t)hw * 32 + c] = peb_e[c] + g0 * pew_e[c * 4] + g1 * pew_e[c * 4 + 1] +
                                  g2 * pew_e[c * 4 + 2] + g3 * pew_e[c * 4 + 3];
    pe_dec[(size_t)c * HWp + hw] = peb_d[c] + g0 * pew_d[c * 4] + g1 * pew_d[c * 4 + 1] +
                                   g2 * pew_d[c * 4 + 2] + g3 * pew_d[c * 4 + 3];
  }
}

// ---------------- weight packing to MFMA A-fragment layout -------------------
// dst[tap][grp][lane][j]: A[m=grp*16+(lane&15)][k=(lane>>4)*8+j] for tap (ky,kx)

__global__ void k_pack(const float* __restrict__ w, ushort* __restrict__ dst, int trans) {
  int tap = blockIdx.x;                       // 0..24
  int grp = threadIdx.x >> 6, lane = threadIdx.x & 63;
  int ky = tap / 5, kx = tap % 5;
  int m = grp * 16 + (lane & 15);
  int kb = (lane >> 4) * 8;
  ushort* o = dst + ((size_t)(tap * 2 + grp) * 64 + lane) * 8;
#pragma unroll
  for (int j = 0; j < 8; ++j) {
    int k = kb + j;
    float v = trans ? w[(size_t)k * 800 + m * 25 + (4 - ky) * 5 + (4 - kx)]
                    : w[(size_t)m * 800 + k * 25 + ky * 5 + kx];
    o[j] = f2bf(v);
  }
}

// ---------------- Tc: boundary-class tap-sum matrices for decoder conv1 -----

__global__ void k_prep_tc(const float* __restrict__ w, float* __restrict__ tc) {
  const int rep[5] = {0, 1, 40, 78, 79};
  int cls = blockIdx.x;                       // 0..24
  int yc = cls / 5, xc = cls % 5;
  int ci = threadIdx.x >> 5, co = threadIdx.x & 31;
  int yr = rep[yc], xr = rep[xc];
  float s = 0.f;
#pragma unroll
  for (int ky = 0; ky < 5; ++ky) {
    if ((unsigned)(yr + ky - 2) >= 80u) continue;
#pragma unroll
    for (int kx = 0; kx < 5; ++kx) {
      if ((unsigned)(xr + kx - 2) >= 80u) continue;
      s += w[(size_t)ci * 800 + co * 25 + (4 - ky) * 5 + (4 - kx)];
    }
  }
  tc[(size_t)cls * 1024 + ci * 32 + co] = s;
}

// ---------------- Ts[img][cls][o] = Tc[cls][:,o] . slot[img] -----------------

__global__ void k_ts(const float* __restrict__ tc, const float* __restrict__ slots,
                     float* __restrict__ ts) {
  int idx = blockIdx.x * 256 + threadIdx.x;
  if (idx >= 288 * 800) return;
  int img = idx / 800, rem = idx % 800;
  int cls = rem >> 5, o = rem & 31;
  float s = 0.f;
#pragma unroll
  for (int ci = 0; ci < 32; ++ci)
    s += tc[(size_t)cls * 1024 + ci * 32 + o] * slots[(size_t)img * 32 + ci];
  ts[idx] = s;
}

// ---------------- MFMA conv: CIN=COUT=32, K=5, PAD=2 -------------------------
// Block 256 thr (4 waves), grid (10 rowtiles, nImg). Wave w: out rows rt*8+2w,+1.
// LDS: rows rt*8-2..rt*8+9 as [r][x 0..83][ci] bf16, 16B units swizzled by
// u' = u ^ ((x>>1)&3)  (<=2-way bank conflicts).

template <bool IN_BF16, bool OUT_BF16, bool RELU>
__global__ __launch_bounds__(256, 2) void k_conv_mfma(
    const void* __restrict__ in_, const ushort* __restrict__ wp,
    const float* __restrict__ bias, void* __restrict__ out_) {
  __shared__ int4 sm[4032];  // 12 * 84 * 4 units of 16B
  const int n = blockIdx.y, rt = blockIdx.x;
  const int t = threadIdx.x;

  // ---- stage ----
  for (int i = t; i < 4032; i += 256) {
    int x = i % 84, ru = i / 84;
    int r = ru >> 2, u = ru & 3;
    int gy = rt * 8 + r - 2, gx = x - 2;
    uint p0 = 0, p1 = 0, p2 = 0, p3 = 0;
    if ((unsigned)gy < 80u && (unsigned)gx < 80u) {
      size_t base = ((size_t)n * 32 + u * 8) * HWp + gy * 80 + gx;
      ushort bb[8];
#pragma unroll
      for (int j = 0; j < 8; ++j) {
        if (IN_BF16) bb[j] = ((const ushort*)in_)[base + (size_t)j * HWp];
        else         bb[j] = f2bf(((const float*)in_)[base + (size_t)j * HWp]);
      }
      p0 = (uint)bb[0] | ((uint)bb[1] << 16);
      p1 = (uint)bb[2] | ((uint)bb[3] << 16);
      p2 = (uint)bb[4] | ((uint)bb[5] << 16);
      p3 = (uint)bb[6] | ((uint)bb[7] << 16);
    }
    int up = u ^ ((x >> 1) & 3);
    int4 pk; pk.x = (int)p0; pk.y = (int)p1; pk.z = (int)p2; pk.w = (int)p3;
    sm[(r * 84 + x) * 4 + up] = pk;
  }
  __syncthreads();

  const int wv = t >> 6, lane = t & 63;
  const int l15 = lane & 15, lg = lane >> 4;
  const short8* smS = (const short8*)sm;

  f32x4 acc[2][5][2];
#pragma unroll
  for (int a = 0; a < 2; ++a)
#pragma unroll
    for (int b = 0; b < 5; ++b)
#pragma unroll
      for (int c = 0; c < 2; ++c) acc[a][b][c] = f32x4{0.f, 0.f, 0.f, 0.f};

  for (int dy = 0; dy < 5; ++dy) {
    for (int dx = 0; dx < 5; ++dx) {
      int tap = dy * 5 + dx;
      short8 A0 = *(const short8*)(wp + ((size_t)(tap * 2 + 0) * 64 + lane) * 8);
      short8 A1 = *(const short8*)(wp + ((size_t)(tap * 2 + 1) * 64 + lane) * 8);
#pragma unroll
      for (int ri = 0; ri < 2; ++ri) {
        int rbase = (wv * 2 + ri + dy) * 336;
#pragma unroll
        for (int xg = 0; xg < 5; ++xg) {
          int xs = xg * 16 + l15 + dx;
          short8 Bv = smS[rbase + xs * 4 + (lg ^ ((xs >> 1) & 3))];
          acc[ri][xg][0] = __builtin_amdgcn_mfma_f32_16x16x32_bf16(A0, Bv, acc[ri][xg][0], 0, 0, 0);
          acc[ri][xg][1] = __builtin_amdgcn_mfma_f32_16x16x32_bf16(A1, Bv, acc[ri][xg][1], 0, 0, 0);
        }
      }
    }
  }

  // ---- epilogue: D row m = lg*4+q (co), col n = l15 (px) ----
  float bv[2][4];
#pragma unroll
  for (int cg = 0; cg < 2; ++cg)
#pragma unroll
    for (int q = 0; q < 4; ++q) bv[cg][q] = bias[cg * 16 + lg * 4 + q];
  int y0 = rt * 8 + wv * 2;
#pragma unroll
  for (int ri = 0; ri < 2; ++ri) {
#pragma unroll
    for (int xg = 0; xg < 5; ++xg) {
#pragma unroll
      for (int cg = 0; cg < 2; ++cg) {
        f32x4 v = acc[ri][xg][cg];
#pragma unroll
        for (int q = 0; q < 4; ++q) {
          int co = cg * 16 + lg * 4 + q;
          float o = v[q] + bv[cg][q];
          if (RELU) o = fmaxf(o, 0.f);
          size_t idx = ((size_t)n * 32 + co) * HWp + (y0 + ri) * 80 + (xg * 16 + l15);
          if (OUT_BF16) ((ushort*)out_)[idx] = f2bf(o);
          else          ((float*)out_)[idx] = o;
        }
      }
    }
  }
}

// ---------------- encoder conv1 (1->32, 5x5, relu) ---------------------------

__global__ __launch_bounds__(256) void k_conv1(const float* __restrict__ in,
                                               const float* __restrict__ w,
                                               const float* __restrict__ b,
                                               float* __restrict__ out) {
  int hw = blockIdx.x * 256 + threadIdx.x;
  int n = blockIdx.y;
  int y = hw / 80, x = hw % 80;
  float xv[25];
#pragma unroll
  for (int ky = 0; ky < 5; ++ky)
#pragma unroll
    for (int kx = 0; kx < 5; ++kx) {
      int iy = y + ky - 2, ix = x + kx - 2;
      xv[ky * 5 + kx] = ((unsigned)iy < 80u && (unsigned)ix < 80u)
                            ? in[(size_t)n * HWp + iy * 80 + ix] : 0.f;
    }
#pragma unroll
  for (int co = 0; co < 32; ++co) {
    float a = b[co];
#pragma unroll
    for (int tp = 0; tp < 25; ++tp) a = fmaf(xv[tp], w[co * 25 + tp], a);
    out[((size_t)n * 32 + co) * HWp + hw] = fmaxf(a, 0.f);
  }
}

// ---------------- decoder conv1 output (algebraic) ---------------------------
// X1[o] = relu(base_bf16[o][hw] + Ts[img][cls(hw)][o])

__global__ __launch_bounds__(256) void k_dec1_write(const ushort* __restrict__ base,
                                                    const float* __restrict__ ts,
                                                    ushort* __restrict__ x1, int n0) {
  int hw = blockIdx.x * 256 + threadIdx.x;
  int nl = blockIdx.y;
  int y = hw / 80, x = hw % 80;
  int yc = y < 2 ? y : (y > 77 ? y - 75 : 2);
  int xc = x < 2 ? x : (x > 77 ? x - 75 : 2);
  const float* tp = ts + ((size_t)(n0 + nl) * 25 + (yc * 5 + xc)) * 32;
#pragma unroll
  for (int o = 0; o < 32; ++o) {
    float v = fmaxf(bf2f(base[(size_t)o * HWp + hw]) + tp[o], 0.f);
    x1[((size_t)nl * 32 + o) * HWp + hw] = f2bf(v);
  }
}

// ---------------- decoder conv4 (32->2, 3x3, trans, split out) ---------------

__global__ __launch_bounds__(256) void k_conv4(const ushort* __restrict__ in,
                                               const float* __restrict__ w,
                                               const float* __restrict__ b,
                                               float* __restrict__ outR,
                                               float* __restrict__ outM, int n0) {
  int hw = blockIdx.x * 256 + threadIdx.x;
  int nl = blockIdx.y;
  int y = hw / 80, x = hw % 80;
  float a0 = b[0], a1 = b[1];
  const ushort* ip = in + (size_t)nl * 32 * HWp;
  for (int ci = 0; ci < 32; ++ci) {
#pragma unroll
    for (int ky = 0; ky < 3; ++ky) {
#pragma unroll
      for (int kx = 0; kx < 3; ++kx) {
        int iy = y + ky - 1, ix = x + kx - 1;
        if ((unsigned)iy < 80u && (unsigned)ix < 80u) {
          float v = bf2f(ip[(size_t)ci * HWp + iy * 80 + ix]);
          a0 = fmaf(v, w[(size_t)ci * 18 + 0 + (2 - ky) * 3 + (2 - kx)], a0);
          a1 = fmaf(v, w[(size_t)ci * 18 + 9 + (2 - ky) * 3 + (2 - kx)], a1);
        }
      }
    }
  }
  outR[(size_t)(n0 + nl) * HWp + hw] = a0;
  outM[(size_t)(n0 + nl) * HWp + hw] = a1;
}

// ---------------- h + PE, big-LN stats ---------------------------------------

__global__ __launch_bounds__(256) void k_hstats(const float* __restrict__ enc,
                                                const float* __restrict__ pe_enc,
                                                float* __restrict__ hbuf,
                                                float* __restrict__ lnpart) {
  int b = blockIdx.y;
  int hw = blockIdx.x * 256 + threadIdx.x;
  const float* ep = enc + (size_t)b * 32 * HWp + hw;
  float v[32];
  float s = 0.f, ss = 0.f;
#pragma unroll
  for (int c = 0; c < 32; ++c) v[c] = ep[(size_t)c * HWp];
#pragma unroll
  for (int c = 0; c < 32; ++c) {
    v[c] += pe_enc[(size_t)hw * 32 + c];
    s += v[c]; ss += v[c] * v[c];
  }
  float* hp = hbuf + ((size_t)b * HWp + hw) * 32;
#pragma unroll
  for (int c = 0; c < 32; ++c) hp[c] = v[c];
  __shared__ float r1[256], r2[256];
  r1[threadIdx.x] = s; r2[threadIdx.x] = ss;
  __syncthreads();
  for (int off = 128; off > 0; off >>= 1) {
    if (threadIdx.x < off) { r1[threadIdx.x] += r1[threadIdx.x + off]; r2[threadIdx.x] += r2[threadIdx.x + off]; }
    __syncthreads();
  }
  if (threadIdx.x == 0) {
    lnpart[(size_t)(b * 25 + blockIdx.x) * 2] = r1[0];
    lnpart[(size_t)(b * 25 + blockIdx.x) * 2 + 1] = r2[0];
  }
}

__global__ void k_statsfin(const float* __restrict__ lnpart, float* __restrict__ meanr) {
  int b = threadIdx.x;
  if (b >= 32) return;
  float s = 0.f, ss = 0.f;
  for (int k = 0; k < 25; ++k) {
    s += lnpart[(size_t)(b * 25 + k) * 2];
    ss += lnpart[(size_t)(b * 25 + k) * 2 + 1];
  }
  float m = s * (1.f / 204800.f);
  float var = ss * (1.f / 204800.f) - m * m;
  meanr[b * 2] = m;
  meanr[b * 2 + 1] = rsqrtf(var + 1e-5f);
}

__global__ __launch_bounds__(256) void k_lnmlpkv(
    const float* __restrict__ hbuf, const float* __restrict__ meanr,
    const float* __restrict__ g, const float* __restrict__ bb,
    const float* __restrict__ w1, const float* __restrict__ b1,
    const float* __restrict__ w2, const float* __restrict__ b2,
    const float* __restrict__ nig, const float* __restrict__ nib,
    const float* __restrict__ kw, const float* __restrict__ kb,
    const float* __restrict__ vw, const float* __restrict__ vb,
    float* __restrict__ keys, float* __restrict__ vals) {
  int b = blockIdx.y;
  int hw = blockIdx.x * 256 + threadIdx.x;
  float x[32], t0[32], t1[32];
  const float* hp = hbuf + ((size_t)b * HWp + hw) * 32;
  float m = meanr[b * 2], rs = meanr[b * 2 + 1];
#pragma unroll
  for (int c = 0; c < 32; ++c)
    x[c] = (hp[c] - m) * rs * g[(size_t)hw * 32 + c] + bb[(size_t)hw * 32 + c];
  matvec32(w1, b1, x, t0, true);
  matvec32(w2, b2, t0, t1, false);
  ln32v(t1, nig, nib, x);
  matvec32(kw, kb, x, t0, false);
  float* kp = keys + ((size_t)b * HWp + hw) * 32;
#pragma unroll
  for (int c = 0; c < 32; ++c) kp[c] = t0[c];
  matvec32(vw, vb, x, t0, false);
  float* vp = vals + ((size_t)b * HWp + hw) * 32;
#pragma unroll
  for (int c = 0; c < 32; ++c) vp[c] = t0[c];
}

// ---------------- slot attention -------------------------------------------

__global__ void k_slots_init(const float* __restrict__ mu, const float* __restrict__ sig,
                             const float* __restrict__ noise, float* __restrict__ slots) {
  int i = blockIdx.x * 256 + threadIdx.x;
  if (i >= 288 * 32) return;
  int c = i & 31;
  slots[i] = mu[c] + sig[c] * noise[i];
}

__global__ void k_q(const float* __restrict__ slots, const float* __restrict__ nsg,
                    const float* __restrict__ nsb, const float* __restrict__ qw,
                    const float* __restrict__ qb, float* __restrict__ qbuf) {
  int r = blockIdx.x * 64 + threadIdx.x;
  if (r >= 288) return;
  float x[32], y[32];
#pragma unroll
  for (int c = 0; c < 32; ++c) x[c] = slots[(size_t)r * 32 + c];
  ln32v(x, nsg, nsb, y);
  matvec32(qw, qb, y, x, false);
#pragma unroll
  for (int c = 0; c < 32; ++c) qbuf[(size_t)r * 32 + c] = x[c];
}

__global__ __launch_bounds__(256) void k_dots(const float* __restrict__ qbuf,
                                              const float* __restrict__ keys,
                                              float* __restrict__ attnt,
                                              float* __restrict__ apart) {
  int b = blockIdx.y;
  int j = blockIdx.x * 256 + threadIdx.x;
  __shared__ float qs[288];
  for (int e = threadIdx.x; e < 288; e += 256) qs[e] = qbuf[(size_t)b * 288 + e];
  __syncthreads();
  float k[32];
  const float* kp = keys + ((size_t)b * HWp + j) * 32;
#pragma unroll
  for (int c = 0; c < 32; ++c) k[c] = kp[c];
  float d[9];
#pragma unroll
  for (int i = 0; i < 9; ++i) {
    float a = 0.f;
#pragma unroll
    for (int c = 0; c < 32; ++c) a = fmaf(qs[i * 32 + c], k[c], a);
    d[i] = a * SCALEf;
  }
  float mx = d[0];
#pragma unroll
  for (int i = 1; i < 9; ++i) mx = fmaxf(mx, d[i]);
  float sum = 0.f;
#pragma unroll
  for (int i = 0; i < 9; ++i) { d[i] = __expf(d[i] - mx); sum += d[i]; }
  float inv = 1.f / sum;
  float a[9];
#pragma unroll
  for (int i = 0; i < 9; ++i) {
    a[i] = d[i] * inv + 1e-8f;
    attnt[((size_t)b * 9 + i) * HWp + j] = a[i];
  }
  int lane = threadIdx.x & 63, wid = threadIdx.x >> 6;
  __shared__ float wr[4 * 9];
#pragma unroll
  for (int i = 0; i < 9; ++i) {
    float v = a[i];
    for (int off = 32; off > 0; off >>= 1) v += __shfl_down(v, off);
    if (lane == 0) wr[wid * 9 + i] = v;
  }
  __syncthreads();
  if (threadIdx.x < 9) {
    float v = wr[threadIdx.x] + wr[9 + threadIdx.x] + wr[18 + threadIdx.x] + wr[27 + threadIdx.x];
    apart[(size_t)(b * 9 + threadIdx.x) * 25 + blockIdx.x] = v;
  }
}

// upd partials: block (jc, b) reads V once for all 9 slots
__global__ __launch_bounds__(256) void k_upd2(const float* __restrict__ vals,
                                              const float* __restrict__ attnt,
                                              float* __restrict__ up2) {
  int jc = blockIdx.x, b = blockIdx.y;
  int c = threadIdx.x & 31, g = threadIdx.x >> 5;
  float a9[9];
#pragma unroll
  for (int i = 0; i < 9; ++i) a9[i] = 0.f;
  const float* vp = vals + (size_t)b * HWp * 32;
  const float* ap = attnt + (size_t)b * 9 * HWp;
  int j0 = jc * 800;
  for (int j = j0 + g; j < j0 + 800; j += 8) {
    float v = vp[(size_t)j * 32 + c];
#pragma unroll
    for (int i = 0; i < 9; ++i) a9[i] = fmaf(v, ap[(size_t)i * HWp + j], a9[i]);
  }
  __shared__ float red[9][8][32];
#pragma unroll
  for (int i = 0; i < 9; ++i) red[i][g][c] = a9[i];
  __syncthreads();
  for (int i = threadIdx.x >> 5; i < 9; i += 8) {
    float s = 0.f;
#pragma unroll
    for (int g2 = 0; g2 < 8; ++g2) s += red[i][g2][c];
    up2[(((size_t)b * 8 + jc) * 9 + i) * 32 + c] = s;
  }
}

__global__ void k_updfin(const float* __restrict__ up2, const float* __restrict__ apart,
                         float* __restrict__ rowsum, float* __restrict__ upd) {
  int i = blockIdx.x, b = blockIdx.y;
  int c = threadIdx.x;
  if (c >= 32) return;
  float rs = 0.f;
  for (int k = 0; k < 25; ++k) rs += apart[(size_t)(b * 9 + i) * 25 + k];
  if (c == 0) rowsum[b * 9 + i] = rs;
  float s = 0.f;
  for (int jc = 0; jc < 8; ++jc) s += up2[(((size_t)b * 8 + jc) * 9 + i) * 32 + c];
  upd[(size_t)(b * 9 + i) * 32 + c] = s / rs;
}

__global__ void k_gru_res(const float* __restrict__ upd, float* __restrict__ slots,
                          const float* __restrict__ wih, const float* __restrict__ whh,
                          const float* __restrict__ bih, const float* __restrict__ bhh,
                          const float* __restrict__ rlg, const float* __restrict__ rlb,
                          const float* __restrict__ rw1, const float* __restrict__ rb1,
                          const float* __restrict__ rw2, const float* __restrict__ rb2) {
  int r = blockIdx.x * 64 + threadIdx.x;
  if (r >= 288) return;
  float u[32], h[32];
#pragma unroll
  for (int c = 0; c < 32; ++c) { u[c] = upd[(size_t)r * 32 + c]; h[c] = slots[(size_t)r * 32 + c]; }
  float rr[32], zz[32];
#pragma unroll
  for (int o = 0; o < 32; ++o) {
    float xr = bih[o], hr = bhh[o];
#pragma unroll
    for (int c = 0; c < 32; ++c) { xr = fmaf(u[c], wih[o * 32 + c], xr); hr = fmaf(h[c], whh[o * 32 + c], hr); }
    rr[o] = 1.f / (1.f + __expf(-(xr + hr)));
  }
#pragma unroll
  for (int o = 0; o < 32; ++o) {
    float xz = bih[32 + o], hz = bhh[32 + o];
#pragma unroll
    for (int c = 0; c < 32; ++c) { xz = fmaf(u[c], wih[(32 + o) * 32 + c], xz); hz = fmaf(h[c], whh[(32 + o) * 32 + c], hz); }
    zz[o] = 1.f / (1.f + __expf(-(xz + hz)));
  }
  float sm[32];
#pragma unroll
  for (int o = 0; o < 32; ++o) {
    float xc = bih[64 + o], hc = bhh[64 + o];
#pragma unroll
    for (int c = 0; c < 32; ++c) { xc = fmaf(u[c], wih[(64 + o) * 32 + c], xc); hc = fmaf(h[c], whh[(64 + o) * 32 + c], hc); }
    float cand = tanhf(xc + rr[o] * hc);
    sm[o] = (1.f - zz[o]) * cand + zz[o] * h[o];
  }
  float tt[32], t1[32];
  ln32v(sm, rlg, rlb, tt);
  matvec32(rw1, rb1, tt, t1, true);
  matvec32(rw2, rb2, t1, tt, false);
#pragma unroll
  for (int c = 0; c < 32; ++c) slots[(size_t)r * 32 + c] = sm[c] + tt[c];
}

// ---------------- outputs ----------------------------------------------------

__global__ void k_attn_out(const float* __restrict__ attnt, const float* __restrict__ rsum,
                           float* __restrict__ out) {
  size_t idx = (size_t)blockIdx.x * 256 + threadIdx.x;
  out[O_ATTN + idx] = attnt[idx] / rsum[idx / HWp];
}

__global__ void k_slots_out(const float* __restrict__ slots, float* __restrict__ out) {
  int idx = blockIdx.x * 256 + threadIdx.x;
  if (idx < 9216) out[O_SLOTS + idx] = slots[idx];
}

__global__ __launch_bounds__(256) void k_final(float* __restrict__ out) {
  int b = blockIdx.y;
  int j = blockIdx.x * 256 + threadIdx.x;
  float r[9], ml[9];
#pragma unroll
  for (int s = 0; s < 9; ++s) {
    r[s]  = out[O_RECON + (size_t)(b * 9 + s) * HWp + j];
    ml[s] = out[O_MASK  + (size_t)(b * 9 + s) * HWp + j];
  }
  float mx = ml[0];
#pragma unroll
  for (int s = 1; s < 9; ++s) mx = fmaxf(mx, ml[s]);
  float sum = 0.f;
#pragma unroll
  for (int s = 0; s < 9; ++s) { ml[s] = __expf(ml[s] - mx); sum += ml[s]; }
  float inv = 1.f / sum;
  float comb = 0.f;
#pragma unroll
  for (int s = 0; s < 9; ++s) {
    float mk = ml[s] * inv;
    comb = fmaf(r[s], mk, comb);
    out[O_MASK + (size_t)(b * 9 + s) * HWp + j] = mk;
  }
  out[O_COMB + (size_t)b * HWp + j] = comb;
}

}  // namespace

// ---------------------------------------------------------------------------

extern "C" void kernel_launch(void* const* d_in, const int* in_sizes, int n_in,
                              void* d_out, int out_size, void* d_ws, size_t ws_size,
                              hipStream_t stream) {
  if (ws_size < W_TOTAL * sizeof(float)) return;  // clean fail, not core dump

  const float* in_x       = (const float*)d_in[0];
  const float* slot_noise = (const float*)d_in[1];
  const float* enc_w1 = (const float*)d_in[2];   const float* enc_b1 = (const float*)d_in[3];
  const float* enc_w2 = (const float*)d_in[4];   const float* enc_b2 = (const float*)d_in[5];
  const float* enc_w3 = (const float*)d_in[6];   const float* enc_b3 = (const float*)d_in[7];
  const float* enc_w4 = (const float*)d_in[8];   const float* enc_b4 = (const float*)d_in[9];
  const float* pe_enc_w = (const float*)d_in[10]; const float* pe_enc_b = (const float*)d_in[11];
  const float* ln_enc_g = (const float*)d_in[12]; const float* ln_enc_b = (const float*)d_in[13];
  const float* mlp_w1 = (const float*)d_in[14];  const float* mlp_b1 = (const float*)d_in[15];
  const float* mlp_w2 = (const float*)d_in[16];  const float* mlp_b2 = (const float*)d_in[17];
  const float* slots_mu = (const float*)d_in[18]; const float* slots_sigma = (const float*)d_in[19];
  const float* ni_g = (const float*)d_in[20];    const float* ni_b = (const float*)d_in[21];
  const float* ns_g = (const float*)d_in[22];    const float* ns_b = (const float*)d_in[23];
  const float* q_w = (const float*)d_in[24];     const float* q_b = (const float*)d_in[25];
  const float* k_w = (const float*)d_in[26];     const float* k_b = (const float*)d_in[27];
  const float* v_w = (const float*)d_in[28];     const float* v_b = (const float*)d_in[29];
  const float* gru_wih = (const float*)d_in[30]; const float* gru_whh = (const float*)d_in[31];
  const float* gru_bih = (const float*)d_in[32]; const float* gru_bhh = (const float*)d_in[33];
  const float* res_ln_g = (const float*)d_in[34]; const float* res_ln_b = (const float*)d_in[35];
  const float* res_w1 = (const float*)d_in[36];  const float* res_b1 = (const float*)d_in[37];
  const float* res_w2 = (const float*)d_in[38];  const float* res_b2 = (const float*)d_in[39];
  const float* pe_dec_w = (const float*)d_in[40]; const float* pe_dec_b = (const float*)d_in[41];
  const float* dec_w1 = (const float*)d_in[42];  const float* dec_b1 = (const float*)d_in[43];
  const float* dec_w2 = (const float*)d_in[44];  const float* dec_b2 = (const float*)d_in[45];
  const float* dec_w3 = (const float*)d_in[46];  const float* dec_b3 = (const float*)d_in[47];
  const float* dec_w4 = (const float*)d_in[48];  const float* dec_b4 = (const float*)d_in[49];

  float* ws  = (float*)d_ws;
  float* out = (float*)d_out;
  ushort* wp = (ushort*)(ws + W_WP);

  k_pe_maps<<<dim3(25), 256, 0, stream>>>(pe_enc_w, pe_enc_b, pe_dec_w, pe_dec_b,
                                          ws + W_PEENC, ws + W_PEDEC);

  // pack conv weights: 0=enc2 1=enc3 2=enc4 (normal), 3=dec1 4=dec2 5=dec3 (trans)
  const size_t WPSTR = 25 * 2 * 64 * 8;  // ushorts per conv
  k_pack<<<dim3(25), 128, 0, stream>>>(enc_w2, wp + 0 * WPSTR, 0);
  k_pack<<<dim3(25), 128, 0, stream>>>(enc_w3, wp + 1 * WPSTR, 0);
  k_pack<<<dim3(25), 128, 0, stream>>>(enc_w4, wp + 2 * WPSTR, 0);
  k_pack<<<dim3(25), 128, 0, stream>>>(dec_w1, wp + 3 * WPSTR, 1);
  k_pack<<<dim3(25), 128, 0, stream>>>(dec_w2, wp + 4 * WPSTR, 1);
  k_pack<<<dim3(25), 128, 0, stream>>>(dec_w3, wp + 5 * WPSTR, 1);
  k_prep_tc<<<dim3(25), 1024, 0, stream>>>(dec_w1, ws + W_TC);

  // base = convT1(pe_dec) + bias   (1 image, bf16 out, no relu)
  k_conv_mfma<false, true, false><<<dim3(10, 1), 256, 0, stream>>>(
      ws + W_PEDEC, wp + 3 * WPSTR, dec_b1, ws + W_BASE);

  // ---------------- encoder ----------------
  k_conv1<<<dim3(25, Bb), 256, 0, stream>>>(in_x, enc_w1, enc_b1, ws + W_A);
  k_conv_mfma<false, false, true><<<dim3(10, Bb), 256, 0, stream>>>(ws + W_A, wp + 0 * WPSTR, enc_b2, ws + W_B);
  k_conv_mfma<false, false, true><<<dim3(10, Bb), 256, 0, stream>>>(ws + W_B, wp + 1 * WPSTR, enc_b3, ws + W_A);
  k_conv_mfma<false, false, true><<<dim3(10, Bb), 256, 0, stream>>>(ws + W_A, wp + 2 * WPSTR, enc_b4, ws + W_B);

  k_hstats<<<dim3(25, Bb), 256, 0, stream>>>(ws + W_B, ws + W_PEENC, ws + W_A, ws + W_LNPART);
  k_statsfin<<<dim3(1), 64, 0, stream>>>(ws + W_LNPART, ws + W_MEANR);
  k_lnmlpkv<<<dim3(25, Bb), 256, 0, stream>>>(ws + W_A, ws + W_MEANR, ln_enc_g, ln_enc_b,
                                              mlp_w1, mlp_b1, mlp_w2, mlp_b2,
                                              ni_g, ni_b, k_w, k_b, v_w, v_b,
                                              ws + W_KEYS, ws + W_VALS);

  // ---------------- slot attention ----------------
  k_slots_init<<<dim3(36), 256, 0, stream>>>(slots_mu, slots_sigma, slot_noise, ws + W_SLOTS);
  for (int it = 0; it < 3; ++it) {
    k_q<<<dim3(5), 64, 0, stream>>>(ws + W_SLOTS, ns_g, ns_b, q_w, q_b, ws + W_Q);
    k_dots<<<dim3(25, Bb), 256, 0, stream>>>(ws + W_Q, ws + W_KEYS, ws + W_ATTNT, ws + W_APART);
    k_upd2<<<dim3(8, Bb), 256, 0, stream>>>(ws + W_VALS, ws + W_ATTNT, ws + W_UP2);
    k_updfin<<<dim3(9, Bb), 32, 0, stream>>>(ws + W_UP2, ws + W_APART, ws + W_RSUM, ws + W_UPD);
    k_gru_res<<<dim3(5), 64, 0, stream>>>(ws + W_UPD, ws + W_SLOTS, gru_wih, gru_whh,
                                          gru_bih, gru_bhh, res_ln_g, res_ln_b,
                                          res_w1, res_b1, res_w2, res_b2);
  }
  k_attn_out<<<dim3(7200), 256, 0, stream>>>(ws + W_ATTNT, ws + W_RSUM, out);
  k_slots_out<<<dim3(36), 256, 0, stream>>>(ws + W_SLOTS, out);

  // Ts for all 288 images (uses final slots)
  k_ts<<<dim3(900), 256, 0, stream>>>(ws + W_TC, ws + W_SLOTS, ws + W_TS);

  // ---------------- decoder: 3 chunks of 96 images, bf16 pool over W_A.. ----
  ushort* X1 = (ushort*)(ws + W_A);
  ushort* X2 = X1 + (size_t)96 * 32 * HWp;
  for (int ch = 0; ch < 3; ++ch) {
    int n0 = ch * 96;
    k_dec1_write<<<dim3(25, 96), 256, 0, stream>>>((ushort*)(ws + W_BASE), ws + W_TS, X1, n0);
    k_conv_mfma<true, true, true><<<dim3(10, 96), 256, 0, stream>>>(X1, wp + 4 * WPSTR, dec_b2, X2);
    k_conv_mfma<true, true, true><<<dim3(10, 96), 256, 0, stream>>>(X2, wp + 5 * WPSTR, dec_b3, X1);
    k_conv4<<<dim3(25, 96), 256, 0, stream>>>(X1, dec_w4, dec_b4,
                                              out + O_RECON, out + O_MASK, n0);
  }

  k_final<<<dim3(25, Bb), 256, 0, stream>>>(out);
}

// Round 4
// 1161.984 us; speedup vs baseline: 8.6373x; 1.3512x over previous
//
#include <hip/hip_runtime.h>
#include <cstddef>
#include <cstdint>

// ---------------------------------------------------------------------------
// STSN forward, v4: v3 + parallelized slot-attention chain (gru/q/updfin
// fused into wide (row,channel) kernels; 9216 threads instead of 288).
// B=32, H=W=80, C=32, S=9, ITERS=3
// ---------------------------------------------------------------------------

namespace {

constexpr int Bb  = 32;
constexpr int HWp = 6400;   // 80*80
constexpr float SCALEf = 0.17677669529663687f;  // 32^-0.5

// output section offsets (floats)
constexpr size_t O_COMB  = 0;          // (32,1,80,80)
constexpr size_t O_RECON = 204800;     // (32,9,1,80,80)
constexpr size_t O_MASK  = 2048000;
constexpr size_t O_SLOTS = 3891200;
constexpr size_t O_ATTN  = 3900416;

// workspace layout (float offsets) — total 116.5 MB
constexpr size_t W_PEENC = 0;                 // 204800   [hw][c] fp32
constexpr size_t W_PEDEC = 204800;            // 204800   [c][hw] fp32
constexpr size_t W_BASE  = 409600;            // 204800 region, used as bf16 [c][hw]
constexpr size_t W_TC    = 614400;            // 25600  (25 cls x 32ci x 32co)
constexpr size_t W_TS    = 640000;            // 230400 (288 img x 25 cls x 32co)
constexpr size_t W_WP    = 870400;            // 76800 floats = 153600 bf16 packed weights
constexpr size_t W_LNPART= 947200;            // 1600
constexpr size_t W_MEANR = 948800;            // 64
constexpr size_t W_Q     = 948864;            // 9216
constexpr size_t W_SLOTS = 958080;            // 9216
constexpr size_t W_APART = 967296;            // 7200
constexpr size_t W_RSUM  = 974496;            // 288
constexpr size_t W_UPD   = 974784;            // 9216 (unused, kept for layout stability)
constexpr size_t W_UP2   = 984000;            // 73728 (32b x 8jc x 9 x 32)
constexpr size_t W_A     = 1057728;           // 6553600 fp32 (enc ping; dec bf16 pool start)
constexpr size_t W_B     = 7611328;           // 6553600 fp32 (enc pong)
constexpr size_t W_KEYS  = 14164928;          // 6553600
constexpr size_t W_VALS  = 20718528;          // 6553600
constexpr size_t W_ATTNT = 27272128;          // 1843200
constexpr size_t W_TOTAL = 29115328;          // floats = 116.5 MB

typedef __attribute__((ext_vector_type(8))) short short8;   // 8 bf16 = 16B
typedef __attribute__((ext_vector_type(4))) float f32x4;

__device__ __forceinline__ ushort f2bf(float f) {
  uint u = __builtin_bit_cast(uint, f);
  uint r = (u + 0x7fffu + ((u >> 16) & 1u)) >> 16;   // RNE
  return (ushort)r;
}
__device__ __forceinline__ float bf2f(ushort b) {
  uint u = ((uint)b) << 16;
  return __builtin_bit_cast(float, u);
}

__device__ __forceinline__ void ln32v(const float* x, const float* __restrict__ g,
                                      const float* __restrict__ b, float* y) {
  float m = 0.f;
#pragma unroll
  for (int c = 0; c < 32; ++c) m += x[c];
  m *= (1.f / 32.f);
  float v = 0.f;
#pragma unroll
  for (int c = 0; c < 32; ++c) { float d = x[c] - m; v += d * d; }
  v *= (1.f / 32.f);
  float rs = rsqrtf(v + 1e-5f);
#pragma unroll
  for (int c = 0; c < 32; ++c) y[c] = (x[c] - m) * rs * g[c] + b[c];
}

__device__ __forceinline__ void matvec32(const float* __restrict__ W,
                                         const float* __restrict__ bias,
                                         const float* x, float* y, bool relu) {
#pragma unroll
  for (int o = 0; o < 32; ++o) {
    float a = bias[o];
#pragma unroll
    for (int c = 0; c < 32; ++c) a = fmaf(x[c], W[o * 32 + c], a);
    y[o] = relu ? fmaxf(a, 0.f) : a;
  }
}

// per-lane LN across a 32-lane group (lane o = laneid&31 holds element o)
__device__ __forceinline__ float lane_ln(float v, int o, const float* __restrict__ g,
                                         const float* __restrict__ b) {
  float s = v;
#pragma unroll
  for (int m = 16; m >= 1; m >>= 1) s += __shfl_xor(s, m);
  float mean = s * (1.f / 32.f);
  float d = v - mean;
  float q = d * d;
#pragma unroll
  for (int m = 16; m >= 1; m >>= 1) q += __shfl_xor(q, m);
  float rstd = rsqrtf(q * (1.f / 32.f) + 1e-5f);
  return d * rstd * g[o] + b[o];
}

// ---------------- positional-embedding maps ---------------------------------

__global__ void k_pe_maps(const float* __restrict__ pew_e, const float* __restrict__ peb_e,
                          const float* __restrict__ pew_d, const float* __restrict__ peb_d,
                          float* __restrict__ pe_enc, float* __restrict__ pe_dec) {
  int hw = blockIdx.x * 256 + threadIdx.x;
  if (hw >= HWp) return;
  int y = hw / 80, x = hw % 80;
  float g0 = y * (1.f / 79.f), g1 = x * (1.f / 79.f);
  float g2 = 1.f - g0, g3 = 1.f - g1;
#pragma unroll
  for (int c = 0; c < 32; ++c) {
    pe_enc[(size_t)hw * 32 + c] = peb_e[c] + g0 * pew_e[c * 4] + g1 * pew_e[c * 4 + 1] +
                                  g2 * pew_e[c * 4 + 2] + g3 * pew_e[c * 4 + 3];
    pe_dec[(size_t)c * HWp + hw] = peb_d[c] + g0 * pew_d[c * 4] + g1 * pew_d[c * 4 + 1] +
                                   g2 * pew_d[c * 4 + 2] + g3 * pew_d[c * 4 + 3];
  }
}

// ---------------- weight packing to MFMA A-fragment layout -------------------

__global__ void k_pack(const float* __restrict__ w, ushort* __restrict__ dst, int trans) {
  int tap = blockIdx.x;                       // 0..24
  int grp = threadIdx.x >> 6, lane = threadIdx.x & 63;
  int ky = tap / 5, kx = tap % 5;
  int m = grp * 16 + (lane & 15);
  int kb = (lane >> 4) * 8;
  ushort* o = dst + ((size_t)(tap * 2 + grp) * 64 + lane) * 8;
#pragma unroll
  for (int j = 0; j < 8; ++j) {
    int k = kb + j;
    float v = trans ? w[(size_t)k * 800 + m * 25 + (4 - ky) * 5 + (4 - kx)]
                    : w[(size_t)m * 800 + k * 25 + ky * 5 + kx];
    o[j] = f2bf(v);
  }
}

// ---------------- Tc: boundary-class tap-sum matrices for decoder conv1 -----

__global__ void k_prep_tc(const float* __restrict__ w, float* __restrict__ tc) {
  const int rep[5] = {0, 1, 40, 78, 79};
  int cls = blockIdx.x;                       // 0..24
  int yc = cls / 5, xc = cls % 5;
  int ci = threadIdx.x >> 5, co = threadIdx.x & 31;
  int yr = rep[yc], xr = rep[xc];
  float s = 0.f;
#pragma unroll
  for (int ky = 0; ky < 5; ++ky) {
    if ((unsigned)(yr + ky - 2) >= 80u) continue;
#pragma unroll
    for (int kx = 0; kx < 5; ++kx) {
      if ((unsigned)(xr + kx - 2) >= 80u) continue;
      s += w[(size_t)ci * 800 + co * 25 + (4 - ky) * 5 + (4 - kx)];
    }
  }
  tc[(size_t)cls * 1024 + ci * 32 + co] = s;
}

__global__ void k_ts(const float* __restrict__ tc, const float* __restrict__ slots,
                     float* __restrict__ ts) {
  int idx = blockIdx.x * 256 + threadIdx.x;
  if (idx >= 288 * 800) return;
  int img = idx / 800, rem = idx % 800;
  int cls = rem >> 5, o = rem & 31;
  float s = 0.f;
#pragma unroll
  for (int ci = 0; ci < 32; ++ci)
    s += tc[(size_t)cls * 1024 + ci * 32 + o] * slots[(size_t)img * 32 + ci];
  ts[idx] = s;
}

// ---------------- MFMA conv: CIN=COUT=32, K=5, PAD=2 -------------------------

template <bool IN_BF16, bool OUT_BF16, bool RELU>
__global__ __launch_bounds__(256, 2) void k_conv_mfma(
    const void* __restrict__ in_, const ushort* __restrict__ wp,
    const float* __restrict__ bias, void* __restrict__ out_) {
  __shared__ int4 sm[4032];  // 12 * 84 * 4 units of 16B
  const int n = blockIdx.y, rt = blockIdx.x;
  const int t = threadIdx.x;

  for (int i = t; i < 4032; i += 256) {
    int x = i % 84, ru = i / 84;
    int r = ru >> 2, u = ru & 3;
    int gy = rt * 8 + r - 2, gx = x - 2;
    uint p0 = 0, p1 = 0, p2 = 0, p3 = 0;
    if ((unsigned)gy < 80u && (unsigned)gx < 80u) {
      size_t base = ((size_t)n * 32 + u * 8) * HWp + gy * 80 + gx;
      ushort bb[8];
#pragma unroll
      for (int j = 0; j < 8; ++j) {
        if (IN_BF16) bb[j] = ((const ushort*)in_)[base + (size_t)j * HWp];
        else         bb[j] = f2bf(((const float*)in_)[base + (size_t)j * HWp]);
      }
      p0 = (uint)bb[0] | ((uint)bb[1] << 16);
      p1 = (uint)bb[2] | ((uint)bb[3] << 16);
      p2 = (uint)bb[4] | ((uint)bb[5] << 16);
      p3 = (uint)bb[6] | ((uint)bb[7] << 16);
    }
    int up = u ^ ((x >> 1) & 3);
    int4 pk; pk.x = (int)p0; pk.y = (int)p1; pk.z = (int)p2; pk.w = (int)p3;
    sm[(r * 84 + x) * 4 + up] = pk;
  }
  __syncthreads();

  const int wv = t >> 6, lane = t & 63;
  const int l15 = lane & 15, lg = lane >> 4;
  const short8* smS = (const short8*)sm;

  f32x4 acc[2][5][2];
#pragma unroll
  for (int a = 0; a < 2; ++a)
#pragma unroll
    for (int b = 0; b < 5; ++b)
#pragma unroll
      for (int c = 0; c < 2; ++c) acc[a][b][c] = f32x4{0.f, 0.f, 0.f, 0.f};

  for (int dy = 0; dy < 5; ++dy) {
    for (int dx = 0; dx < 5; ++dx) {
      int tap = dy * 5 + dx;
      short8 A0 = *(const short8*)(wp + ((size_t)(tap * 2 + 0) * 64 + lane) * 8);
      short8 A1 = *(const short8*)(wp + ((size_t)(tap * 2 + 1) * 64 + lane) * 8);
#pragma unroll
      for (int ri = 0; ri < 2; ++ri) {
        int rbase = (wv * 2 + ri + dy) * 336;
#pragma unroll
        for (int xg = 0; xg < 5; ++xg) {
          int xs = xg * 16 + l15 + dx;
          short8 Bv = smS[rbase + xs * 4 + (lg ^ ((xs >> 1) & 3))];
          acc[ri][xg][0] = __builtin_amdgcn_mfma_f32_16x16x32_bf16(A0, Bv, acc[ri][xg][0], 0, 0, 0);
          acc[ri][xg][1] = __builtin_amdgcn_mfma_f32_16x16x32_bf16(A1, Bv, acc[ri][xg][1], 0, 0, 0);
        }
      }
    }
  }

  float bv[2][4];
#pragma unroll
  for (int cg = 0; cg < 2; ++cg)
#pragma unroll
    for (int q = 0; q < 4; ++q) bv[cg][q] = bias[cg * 16 + lg * 4 + q];
  int y0 = rt * 8 + wv * 2;
#pragma unroll
  for (int ri = 0; ri < 2; ++ri) {
#pragma unroll
    for (int xg = 0; xg < 5; ++xg) {
#pragma unroll
      for (int cg = 0; cg < 2; ++cg) {
        f32x4 v = acc[ri][xg][cg];
#pragma unroll
        for (int q = 0; q < 4; ++q) {
          int co = cg * 16 + lg * 4 + q;
          float o = v[q] + bv[cg][q];
          if (RELU) o = fmaxf(o, 0.f);
          size_t idx = ((size_t)n * 32 + co) * HWp + (y0 + ri) * 80 + (xg * 16 + l15);
          if (OUT_BF16) ((ushort*)out_)[idx] = f2bf(o);
          else          ((float*)out_)[idx] = o;
        }
      }
    }
  }
}

// ---------------- encoder conv1 (1->32, 5x5, relu) ---------------------------

__global__ __launch_bounds__(256) void k_conv1(const float* __restrict__ in,
                                               const float* __restrict__ w,
                                               const float* __restrict__ b,
                                               float* __restrict__ out) {
  int hw = blockIdx.x * 256 + threadIdx.x;
  int n = blockIdx.y;
  int y = hw / 80, x = hw % 80;
  float xv[25];
#pragma unroll
  for (int ky = 0; ky < 5; ++ky)
#pragma unroll
    for (int kx = 0; kx < 5; ++kx) {
      int iy = y + ky - 2, ix = x + kx - 2;
      xv[ky * 5 + kx] = ((unsigned)iy < 80u && (unsigned)ix < 80u)
                            ? in[(size_t)n * HWp + iy * 80 + ix] : 0.f;
    }
#pragma unroll
  for (int co = 0; co < 32; ++co) {
    float a = b[co];
#pragma unroll
    for (int tp = 0; tp < 25; ++tp) a = fmaf(xv[tp], w[co * 25 + tp], a);
    out[((size_t)n * 32 + co) * HWp + hw] = fmaxf(a, 0.f);
  }
}

// ---------------- decoder conv1 output (algebraic) ---------------------------

__global__ __launch_bounds__(256) void k_dec1_write(const ushort* __restrict__ base,
                                                    const float* __restrict__ ts,
                                                    ushort* __restrict__ x1, int n0) {
  int hw = blockIdx.x * 256 + threadIdx.x;
  int nl = blockIdx.y;
  int y = hw / 80, x = hw % 80;
  int yc = y < 2 ? y : (y > 77 ? y - 75 : 2);
  int xc = x < 2 ? x : (x > 77 ? x - 75 : 2);
  const float* tp = ts + ((size_t)(n0 + nl) * 25 + (yc * 5 + xc)) * 32;
#pragma unroll
  for (int o = 0; o < 32; ++o) {
    float v = fmaxf(bf2f(base[(size_t)o * HWp + hw]) + tp[o], 0.f);
    x1[((size_t)nl * 32 + o) * HWp + hw] = f2bf(v);
  }
}

// ---------------- decoder conv4 (32->2, 3x3, trans, split out) ---------------

__global__ __launch_bounds__(256) void k_conv4(const ushort* __restrict__ in,
                                               const float* __restrict__ w,
                                               const float* __restrict__ b,
                                               float* __restrict__ outR,
                                               float* __restrict__ outM, int n0) {
  int hw = blockIdx.x * 256 + threadIdx.x;
  int nl = blockIdx.y;
  int y = hw / 80, x = hw % 80;
  float a0 = b[0], a1 = b[1];
  const ushort* ip = in + (size_t)nl * 32 * HWp;
  for (int ci = 0; ci < 32; ++ci) {
#pragma unroll
    for (int ky = 0; ky < 3; ++ky) {
#pragma unroll
      for (int kx = 0; kx < 3; ++kx) {
        int iy = y + ky - 1, ix = x + kx - 1;
        if ((unsigned)iy < 80u && (unsigned)ix < 80u) {
          float v = bf2f(ip[(size_t)ci * HWp + iy * 80 + ix]);
          a0 = fmaf(v, w[(size_t)ci * 18 + 0 + (2 - ky) * 3 + (2 - kx)], a0);
          a1 = fmaf(v, w[(size_t)ci * 18 + 9 + (2 - ky) * 3 + (2 - kx)], a1);
        }
      }
    }
  }
  outR[(size_t)(n0 + nl) * HWp + hw] = a0;
  outM[(size_t)(n0 + nl) * HWp + hw] = a1;
}

// ---------------- h + PE, big-LN stats ---------------------------------------

__global__ __launch_bounds__(256) void k_hstats(const float* __restrict__ enc,
                                                const float* __restrict__ pe_enc,
                                                float* __restrict__ hbuf,
                                                float* __restrict__ lnpart) {
  int b = blockIdx.y;
  int hw = blockIdx.x * 256 + threadIdx.x;
  const float* ep = enc + (size_t)b * 32 * HWp + hw;
  float v[32];
  float s = 0.f, ss = 0.f;
#pragma unroll
  for (int c = 0; c < 32; ++c) v[c] = ep[(size_t)c * HWp];
#pragma unroll
  for (int c = 0; c < 32; ++c) {
    v[c] += pe_enc[(size_t)hw * 32 + c];
    s += v[c]; ss += v[c] * v[c];
  }
  float* hp = hbuf + ((size_t)b * HWp + hw) * 32;
#pragma unroll
  for (int c = 0; c < 32; ++c) hp[c] = v[c];
  __shared__ float r1[256], r2[256];
  r1[threadIdx.x] = s; r2[threadIdx.x] = ss;
  __syncthreads();
  for (int off = 128; off > 0; off >>= 1) {
    if (threadIdx.x < off) { r1[threadIdx.x] += r1[threadIdx.x + off]; r2[threadIdx.x] += r2[threadIdx.x + off]; }
    __syncthreads();
  }
  if (threadIdx.x == 0) {
    lnpart[(size_t)(b * 25 + blockIdx.x) * 2] = r1[0];
    lnpart[(size_t)(b * 25 + blockIdx.x) * 2 + 1] = r2[0];
  }
}

__global__ void k_statsfin(const float* __restrict__ lnpart, float* __restrict__ meanr) {
  int b = threadIdx.x;
  if (b >= 32) return;
  float s = 0.f, ss = 0.f;
  for (int k = 0; k < 25; ++k) {
    s += lnpart[(size_t)(b * 25 + k) * 2];
    ss += lnpart[(size_t)(b * 25 + k) * 2 + 1];
  }
  float m = s * (1.f / 204800.f);
  float var = ss * (1.f / 204800.f) - m * m;
  meanr[b * 2] = m;
  meanr[b * 2 + 1] = rsqrtf(var + 1e-5f);
}

__global__ __launch_bounds__(256) void k_lnmlpkv(
    const float* __restrict__ hbuf, const float* __restrict__ meanr,
    const float* __restrict__ g, const float* __restrict__ bb,
    const float* __restrict__ w1, const float* __restrict__ b1,
    const float* __restrict__ w2, const float* __restrict__ b2,
    const float* __restrict__ nig, const float* __restrict__ nib,
    const float* __restrict__ kw, const float* __restrict__ kb,
    const float* __restrict__ vw, const float* __restrict__ vb,
    float* __restrict__ keys, float* __restrict__ vals) {
  int b = blockIdx.y;
  int hw = blockIdx.x * 256 + threadIdx.x;
  float x[32], t0[32], t1[32];
  const float* hp = hbuf + ((size_t)b * HWp + hw) * 32;
  float m = meanr[b * 2], rs = meanr[b * 2 + 1];
#pragma unroll
  for (int c = 0; c < 32; ++c)
    x[c] = (hp[c] - m) * rs * g[(size_t)hw * 32 + c] + bb[(size_t)hw * 32 + c];
  matvec32(w1, b1, x, t0, true);
  matvec32(w2, b2, t0, t1, false);
  ln32v(t1, nig, nib, x);
  matvec32(kw, kb, x, t0, false);
  float* kp = keys + ((size_t)b * HWp + hw) * 32;
#pragma unroll
  for (int c = 0; c < 32; ++c) kp[c] = t0[c];
  matvec32(vw, vb, x, t0, false);
  float* vp = vals + ((size_t)b * HWp + hw) * 32;
#pragma unroll
  for (int c = 0; c < 32; ++c) vp[c] = t0[c];
}

// ---------------- slot attention (wide kernels) ------------------------------
// thread (r,o): r = slot-row 0..287, o = channel 0..31. 36 blocks x 256.

__global__ __launch_bounds__(256) void k_init_q(
    const float* __restrict__ mu, const float* __restrict__ sig,
    const float* __restrict__ noise,
    const float* __restrict__ nsg, const float* __restrict__ nsb,
    const float* __restrict__ qw, const float* __restrict__ qb,
    float* __restrict__ slots, float* __restrict__ qbuf) {
  int rl = threadIdx.x >> 5, o = threadIdx.x & 31;
  int r = blockIdx.x * 8 + rl;
  float s = mu[o] + sig[o] * noise[(size_t)r * 32 + o];
  slots[(size_t)r * 32 + o] = s;
  float y = lane_ln(s, o, nsg, nsb);
  __shared__ float S[8][32];
  S[rl][o] = y;
  __syncthreads();
  float qv = qb[o];
#pragma unroll
  for (int c = 0; c < 32; ++c) qv = fmaf(S[rl][c], qw[o * 32 + c], qv);
  qbuf[(size_t)r * 32 + o] = qv;
}

// fused: rowsum + upd-finalize + GRU + res-MLP + next-iter q
__global__ __launch_bounds__(256) void k_gru_fused(
    const float* __restrict__ up2, const float* __restrict__ apart,
    float* __restrict__ slots, float* __restrict__ rowsum, float* __restrict__ qbuf,
    const float* __restrict__ wih, const float* __restrict__ whh,
    const float* __restrict__ bih, const float* __restrict__ bhh,
    const float* __restrict__ rlg, const float* __restrict__ rlb,
    const float* __restrict__ rw1, const float* __restrict__ rb1,
    const float* __restrict__ rw2, const float* __restrict__ rb2,
    const float* __restrict__ nsg, const float* __restrict__ nsb,
    const float* __restrict__ qw, const float* __restrict__ qb) {
  int rl = threadIdx.x >> 5, o = threadIdx.x & 31;
  int r = blockIdx.x * 8 + rl;            // 0..287
  int b = r / 9, i = r - b * 9;

  float rs = 0.f;
#pragma unroll
  for (int k = 0; k < 25; ++k) rs += apart[(size_t)(b * 9 + i) * 25 + k];
  if (o == 0) rowsum[r] = rs;

  float uo = 0.f;
#pragma unroll
  for (int jc = 0; jc < 8; ++jc) uo += up2[(((size_t)b * 8 + jc) * 9 + i) * 32 + o];
  uo /= rs;
  float ho = slots[(size_t)r * 32 + o];

  __shared__ float Us[8][32], Hs[8][32];
  Us[rl][o] = uo; Hs[rl][o] = ho;
  __syncthreads();

  float xr = bih[o], xz = bih[32 + o], xc = bih[64 + o];
  float hr = bhh[o], hz = bhh[32 + o], hc = bhh[64 + o];
#pragma unroll
  for (int c = 0; c < 32; ++c) {
    float u = Us[rl][c], h = Hs[rl][c];
    xr = fmaf(u, wih[o * 32 + c], xr);          hr = fmaf(h, whh[o * 32 + c], hr);
    xz = fmaf(u, wih[(32 + o) * 32 + c], xz);   hz = fmaf(h, whh[(32 + o) * 32 + c], hz);
    xc = fmaf(u, wih[(64 + o) * 32 + c], xc);   hc = fmaf(h, whh[(64 + o) * 32 + c], hc);
  }
  float rr = 1.f / (1.f + __expf(-(xr + hr)));
  float zz = 1.f / (1.f + __expf(-(xz + hz)));
  float cand = tanhf(xc + rr * hc);
  float sm = (1.f - zz) * cand + zz * ho;

  // residual MLP
  float y = lane_ln(sm, o, rlg, rlb);
  __syncthreads();
  Us[rl][o] = y;
  __syncthreads();
  float t1 = rb1[o];
#pragma unroll
  for (int c = 0; c < 32; ++c) t1 = fmaf(Us[rl][c], rw1[o * 32 + c], t1);
  t1 = fmaxf(t1, 0.f);
  Hs[rl][o] = t1;
  __syncthreads();
  float res = rb2[o];
#pragma unroll
  for (int c = 0; c < 32; ++c) res = fmaf(Hs[rl][c], rw2[o * 32 + c], res);
  float ns = sm + res;
  slots[(size_t)r * 32 + o] = ns;

  // q for next iteration
  float y2 = lane_ln(ns, o, nsg, nsb);
  __syncthreads();
  Us[rl][o] = y2;
  __syncthreads();
  float qv = qb[o];
#pragma unroll
  for (int c = 0; c < 32; ++c) qv = fmaf(Us[rl][c], qw[o * 32 + c], qv);
  qbuf[(size_t)r * 32 + o] = qv;
}

__global__ __launch_bounds__(256) void k_dots(const float* __restrict__ qbuf,
                                              const float* __restrict__ keys,
                                              float* __restrict__ attnt,
                                              float* __restrict__ apart) {
  int b = blockIdx.y;
  int j = blockIdx.x * 256 + threadIdx.x;
  __shared__ float qs[288];
  for (int e = threadIdx.x; e < 288; e += 256) qs[e] = qbuf[(size_t)b * 288 + e];
  __syncthreads();
  float k[32];
  const float* kp = keys + ((size_t)b * HWp + j) * 32;
#pragma unroll
  for (int c = 0; c < 32; ++c) k[c] = kp[c];
  float d[9];
#pragma unroll
  for (int i = 0; i < 9; ++i) {
    float a = 0.f;
#pragma unroll
    for (int c = 0; c < 32; ++c) a = fmaf(qs[i * 32 + c], k[c], a);
    d[i] = a * SCALEf;
  }
  float mx = d[0];
#pragma unroll
  for (int i = 1; i < 9; ++i) mx = fmaxf(mx, d[i]);
  float sum = 0.f;
#pragma unroll
  for (int i = 0; i < 9; ++i) { d[i] = __expf(d[i] - mx); sum += d[i]; }
  float inv = 1.f / sum;
  float a[9];
#pragma unroll
  for (int i = 0; i < 9; ++i) {
    a[i] = d[i] * inv + 1e-8f;
    attnt[((size_t)b * 9 + i) * HWp + j] = a[i];
  }
  int lane = threadIdx.x & 63, wid = threadIdx.x >> 6;
  __shared__ float wr[4 * 9];
#pragma unroll
  for (int i = 0; i < 9; ++i) {
    float v = a[i];
    for (int off = 32; off > 0; off >>= 1) v += __shfl_down(v, off);
    if (lane == 0) wr[wid * 9 + i] = v;
  }
  __syncthreads();
  if (threadIdx.x < 9) {
    float v = wr[threadIdx.x] + wr[9 + threadIdx.x] + wr[18 + threadIdx.x] + wr[27 + threadIdx.x];
    apart[(size_t)(b * 9 + threadIdx.x) * 25 + blockIdx.x] = v;
  }
}

__global__ __launch_bounds__(256) void k_upd2(const float* __restrict__ vals,
                                              const float* __restrict__ attnt,
                                              float* __restrict__ up2) {
  int jc = blockIdx.x, b = blockIdx.y;
  int c = threadIdx.x & 31, g = threadIdx.x >> 5;
  float a9[9];
#pragma unroll
  for (int i = 0; i < 9; ++i) a9[i] = 0.f;
  const float* vp = vals + (size_t)b * HWp * 32;
  const float* ap = attnt + (size_t)b * 9 * HWp;
  int j0 = jc * 800;
  for (int j = j0 + g; j < j0 + 800; j += 8) {
    float v = vp[(size_t)j * 32 + c];
#pragma unroll
    for (int i = 0; i < 9; ++i) a9[i] = fmaf(v, ap[(size_t)i * HWp + j], a9[i]);
  }
  __shared__ float red[9][8][32];
#pragma unroll
  for (int i = 0; i < 9; ++i) red[i][g][c] = a9[i];
  __syncthreads();
  for (int i = threadIdx.x >> 5; i < 9; i += 8) {
    float s = 0.f;
#pragma unroll
    for (int g2 = 0; g2 < 8; ++g2) s += red[i][g2][c];
    up2[(((size_t)b * 8 + jc) * 9 + i) * 32 + c] = s;
  }
}

// ---------------- outputs ----------------------------------------------------

__global__ void k_attn_out(const float* __restrict__ attnt, const float* __restrict__ rsum,
                           float* __restrict__ out) {
  size_t idx = (size_t)blockIdx.x * 256 + threadIdx.x;
  out[O_ATTN + idx] = attnt[idx] / rsum[idx / HWp];
}

__global__ void k_slots_out(const float* __restrict__ slots, float* __restrict__ out) {
  int idx = blockIdx.x * 256 + threadIdx.x;
  if (idx < 9216) out[O_SLOTS + idx] = slots[idx];
}

__global__ __launch_bounds__(256) void k_final(float* __restrict__ out) {
  int b = blockIdx.y;
  int j = blockIdx.x * 256 + threadIdx.x;
  float r[9], ml[9];
#pragma unroll
  for (int s = 0; s < 9; ++s) {
    r[s]  = out[O_RECON + (size_t)(b * 9 + s) * HWp + j];
    ml[s] = out[O_MASK  + (size_t)(b * 9 + s) * HWp + j];
  }
  float mx = ml[0];
#pragma unroll
  for (int s = 1; s < 9; ++s) mx = fmaxf(mx, ml[s]);
  float sum = 0.f;
#pragma unroll
  for (int s = 0; s < 9; ++s) { ml[s] = __expf(ml[s] - mx); sum += ml[s]; }
  float inv = 1.f / sum;
  float comb = 0.f;
#pragma unroll
  for (int s = 0; s < 9; ++s) {
    float mk = ml[s] * inv;
    comb = fmaf(r[s], mk, comb);
    out[O_MASK + (size_t)(b * 9 + s) * HWp + j] = mk;
  }
  out[O_COMB + (size_t)b * HWp + j] = comb;
}

}  // namespace

// ---------------------------------------------------------------------------

extern "C" void kernel_launch(void* const* d_in, const int* in_sizes, int n_in,
                              void* d_out, int out_size, void* d_ws, size_t ws_size,
                              hipStream_t stream) {
  if (ws_size < W_TOTAL * sizeof(float)) return;  // clean fail, not core dump

  const float* in_x       = (const float*)d_in[0];
  const float* slot_noise = (const float*)d_in[1];
  const float* enc_w1 = (const float*)d_in[2];   const float* enc_b1 = (const float*)d_in[3];
  const float* enc_w2 = (const float*)d_in[4];   const float* enc_b2 = (const float*)d_in[5];
  const float* enc_w3 = (const float*)d_in[6];   const float* enc_b3 = (const float*)d_in[7];
  const float* enc_w4 = (const float*)d_in[8];   const float* enc_b4 = (const float*)d_in[9];
  const float* pe_enc_w = (const float*)d_in[10]; const float* pe_enc_b = (const float*)d_in[11];
  const float* ln_enc_g = (const float*)d_in[12]; const float* ln_enc_b = (const float*)d_in[13];
  const float* mlp_w1 = (const float*)d_in[14];  const float* mlp_b1 = (const float*)d_in[15];
  const float* mlp_w2 = (const float*)d_in[16];  const float* mlp_b2 = (const float*)d_in[17];
  const float* slots_mu = (const float*)d_in[18]; const float* slots_sigma = (const float*)d_in[19];
  const float* ni_g = (const float*)d_in[20];    const float* ni_b = (const float*)d_in[21];
  const float* ns_g = (const float*)d_in[22];    const float* ns_b = (const float*)d_in[23];
  const float* q_w = (const float*)d_in[24];     const float* q_b = (const float*)d_in[25];
  const float* k_w = (const float*)d_in[26];     const float* k_b = (const float*)d_in[27];
  const float* v_w = (const float*)d_in[28];     const float* v_b = (const float*)d_in[29];
  const float* gru_wih = (const float*)d_in[30]; const float* gru_whh = (const float*)d_in[31];
  const float* gru_bih = (const float*)d_in[32]; const float* gru_bhh = (const float*)d_in[33];
  const float* res_ln_g = (const float*)d_in[34]; const float* res_ln_b = (const float*)d_in[35];
  const float* res_w1 = (const float*)d_in[36];  const float* res_b1 = (const float*)d_in[37];
  const float* res_w2 = (const float*)d_in[38];  const float* res_b2 = (const float*)d_in[39];
  const float* pe_dec_w = (const float*)d_in[40]; const float* pe_dec_b = (const float*)d_in[41];
  const float* dec_w1 = (const float*)d_in[42];  const float* dec_b1 = (const float*)d_in[43];
  const float* dec_w2 = (const float*)d_in[44];  const float* dec_b2 = (const float*)d_in[45];
  const float* dec_w3 = (const float*)d_in[46];  const float* dec_b3 = (const float*)d_in[47];
  const float* dec_w4 = (const float*)d_in[48];  const float* dec_b4 = (const float*)d_in[49];

  float* ws  = (float*)d_ws;
  float* out = (float*)d_out;
  ushort* wp = (ushort*)(ws + W_WP);

  k_pe_maps<<<dim3(25), 256, 0, stream>>>(pe_enc_w, pe_enc_b, pe_dec_w, pe_dec_b,
                                          ws + W_PEENC, ws + W_PEDEC);

  // pack conv weights: 0=enc2 1=enc3 2=enc4 (normal), 3=dec1 4=dec2 5=dec3 (trans)
  const size_t WPSTR = 25 * 2 * 64 * 8;  // ushorts per conv
  k_pack<<<dim3(25), 128, 0, stream>>>(enc_w2, wp + 0 * WPSTR, 0);
  k_pack<<<dim3(25), 128, 0, stream>>>(enc_w3, wp + 1 * WPSTR, 0);
  k_pack<<<dim3(25), 128, 0, stream>>>(enc_w4, wp + 2 * WPSTR, 0);
  k_pack<<<dim3(25), 128, 0, stream>>>(dec_w1, wp + 3 * WPSTR, 1);
  k_pack<<<dim3(25), 128, 0, stream>>>(dec_w2, wp + 4 * WPSTR, 1);
  k_pack<<<dim3(25), 128, 0, stream>>>(dec_w3, wp + 5 * WPSTR, 1);
  k_prep_tc<<<dim3(25), 1024, 0, stream>>>(dec_w1, ws + W_TC);

  // base = convT1(pe_dec) + bias   (1 image, bf16 out, no relu)
  k_conv_mfma<false, true, false><<<dim3(10, 1), 256, 0, stream>>>(
      ws + W_PEDEC, wp + 3 * WPSTR, dec_b1, ws + W_BASE);

  // ---------------- encoder ----------------
  k_conv1<<<dim3(25, Bb), 256, 0, stream>>>(in_x, enc_w1, enc_b1, ws + W_A);
  k_conv_mfma<false, false, true><<<dim3(10, Bb), 256, 0, stream>>>(ws + W_A, wp + 0 * WPSTR, enc_b2, ws + W_B);
  k_conv_mfma<false, false, true><<<dim3(10, Bb), 256, 0, stream>>>(ws + W_B, wp + 1 * WPSTR, enc_b3, ws + W_A);
  k_conv_mfma<false, false, true><<<dim3(10, Bb), 256, 0, stream>>>(ws + W_A, wp + 2 * WPSTR, enc_b4, ws + W_B);

  k_hstats<<<dim3(25, Bb), 256, 0, stream>>>(ws + W_B, ws + W_PEENC, ws + W_A, ws + W_LNPART);
  k_statsfin<<<dim3(1), 64, 0, stream>>>(ws + W_LNPART, ws + W_MEANR);
  k_lnmlpkv<<<dim3(25, Bb), 256, 0, stream>>>(ws + W_A, ws + W_MEANR, ln_enc_g, ln_enc_b,
                                              mlp_w1, mlp_b1, mlp_w2, mlp_b2,
                                              ni_g, ni_b, k_w, k_b, v_w, v_b,
                                              ws + W_KEYS, ws + W_VALS);

  // ---------------- slot attention (wide kernels) ----------------
  k_init_q<<<dim3(36), 256, 0, stream>>>(slots_mu, slots_sigma, slot_noise,
                                         ns_g, ns_b, q_w, q_b, ws + W_SLOTS, ws + W_Q);
  for (int it = 0; it < 3; ++it) {
    k_dots<<<dim3(25, Bb), 256, 0, stream>>>(ws + W_Q, ws + W_KEYS, ws + W_ATTNT, ws + W_APART);
    k_upd2<<<dim3(8, Bb), 256, 0, stream>>>(ws + W_VALS, ws + W_ATTNT, ws + W_UP2);
    k_gru_fused<<<dim3(36), 256, 0, stream>>>(ws + W_UP2, ws + W_APART,
                                              ws + W_SLOTS, ws + W_RSUM, ws + W_Q,
                                              gru_wih, gru_whh, gru_bih, gru_bhh,
                                              res_ln_g, res_ln_b, res_w1, res_b1,
                                              res_w2, res_b2, ns_g, ns_b, q_w, q_b);
  }
  k_attn_out<<<dim3(7200), 256, 0, stream>>>(ws + W_ATTNT, ws + W_RSUM, out);
  k_slots_out<<<dim3(36), 256, 0, stream>>>(ws + W_SLOTS, out);

  // Ts for all 288 images (uses final slots)
  k_ts<<<dim3(900), 256, 0, stream>>>(ws + W_TC, ws + W_SLOTS, ws + W_TS);

  // ---------------- decoder: 3 chunks of 96 images, bf16 pool over W_A.. ----
  ushort* X1 = (ushort*)(ws + W_A);
  ushort* X2 = X1 + (size_t)96 * 32 * HWp;
  for (int ch = 0; ch < 3; ++ch) {
    int n0 = ch * 96;
    k_dec1_write<<<dim3(25, 96), 256, 0, stream>>>((ushort*)(ws + W_BASE), ws + W_TS, X1, n0);
    k_conv_mfma<true, true, true><<<dim3(10, 96), 256, 0, stream>>>(X1, wp + 4 * WPSTR, dec_b2, X2);
    k_conv_mfma<true, true, true><<<dim3(10, 96), 256, 0, stream>>>(X2, wp + 5 * WPSTR, dec_b3, X1);
    k_conv4<<<dim3(25, 96), 256, 0, stream>>>(X1, dec_w4, dec_b4,
                                              out + O_RECON, out + O_MASK, n0);
  }

  k_final<<<dim3(25, Bb), 256, 0, stream>>>(out);
}

// Round 5
// 794.768 us; speedup vs baseline: 12.6281x; 1.4620x over previous
//
#include <hip/hip_runtime.h>
#include <cstddef>
#include <cstdint>

// ---------------------------------------------------------------------------
// STSN forward, v5: channel-last bf16 activations everywhere; dec1 fused into
// dec2 staging; vectorized conv4.  B=32, H=W=80, C=32, S=9, ITERS=3
// ---------------------------------------------------------------------------

namespace {

constexpr int Bb  = 32;
constexpr int HWp = 6400;   // 80*80
constexpr float SCALEf = 0.17677669529663687f;  // 32^-0.5

// output section offsets (floats)
constexpr size_t O_COMB  = 0;
constexpr size_t O_RECON = 204800;
constexpr size_t O_MASK  = 2048000;
constexpr size_t O_SLOTS = 3891200;
constexpr size_t O_ATTN  = 3900416;

// workspace layout (float offsets) — total 116.5 MB
constexpr size_t W_PEENC = 0;                 // 204800   [hw][c] fp32
constexpr size_t W_PEDEC = 204800;            // 204800   [c][hw] fp32
constexpr size_t W_BASE  = 409600;            // bf16 [hw][c] (uses 102400 floats)
constexpr size_t W_TC    = 614400;            // 25600
constexpr size_t W_TS    = 640000;            // 230400 (288 x 25 x 32) fp32
constexpr size_t W_WP    = 870400;            // packed bf16 weights
constexpr size_t W_LNPART= 947200;            // 1600
constexpr size_t W_MEANR = 948800;            // 64
constexpr size_t W_Q     = 948864;            // 9216
constexpr size_t W_SLOTS = 958080;            // 9216
constexpr size_t W_APART = 967296;            // 7200
constexpr size_t W_RSUM  = 974496;            // 288
constexpr size_t W_UPD   = 974784;            // 9216 (spare)
constexpr size_t W_UP2   = 984000;            // 73728
constexpr size_t W_A     = 1057728;           // 6553600 (h fp32 / enc bf16 / dec pool)
constexpr size_t W_B     = 7611328;           // 6553600
constexpr size_t W_KEYS  = 14164928;          // 6553600
constexpr size_t W_VALS  = 20718528;          // 6553600
constexpr size_t W_ATTNT = 27272128;          // 1843200
constexpr size_t W_TOTAL = 29115328;          // floats = 116.5 MB

typedef __attribute__((ext_vector_type(8))) short short8;   // 8 bf16 = 16B
typedef __attribute__((ext_vector_type(4))) float f32x4;

__device__ __forceinline__ ushort f2bf(float f) {
  uint u = __builtin_bit_cast(uint, f);
  uint r = (u + 0x7fffu + ((u >> 16) & 1u)) >> 16;   // RNE
  return (ushort)r;
}
__device__ __forceinline__ float bf2f(ushort b) {
  uint u = ((uint)b) << 16;
  return __builtin_bit_cast(float, u);
}
// unpack one 32-bit word (2 bf16) -> 2 floats
__device__ __forceinline__ void unpk2(uint w, float& a, float& b) {
  a = __builtin_bit_cast(float, w << 16);
  b = __builtin_bit_cast(float, w & 0xffff0000u);
}

__device__ __forceinline__ void ln32v(const float* x, const float* __restrict__ g,
                                      const float* __restrict__ b, float* y) {
  float m = 0.f;
#pragma unroll
  for (int c = 0; c < 32; ++c) m += x[c];
  m *= (1.f / 32.f);
  float v = 0.f;
#pragma unroll
  for (int c = 0; c < 32; ++c) { float d = x[c] - m; v += d * d; }
  v *= (1.f / 32.f);
  float rs = rsqrtf(v + 1e-5f);
#pragma unroll
  for (int c = 0; c < 32; ++c) y[c] = (x[c] - m) * rs * g[c] + b[c];
}

__device__ __forceinline__ void matvec32(const float* __restrict__ W,
                                         const float* __restrict__ bias,
                                         const float* x, float* y, bool relu) {
#pragma unroll
  for (int o = 0; o < 32; ++o) {
    float a = bias[o];
#pragma unroll
    for (int c = 0; c < 32; ++c) a = fmaf(x[c], W[o * 32 + c], a);
    y[o] = relu ? fmaxf(a, 0.f) : a;
  }
}

__device__ __forceinline__ float lane_ln(float v, int o, const float* __restrict__ g,
                                         const float* __restrict__ b) {
  float s = v;
#pragma unroll
  for (int m = 16; m >= 1; m >>= 1) s += __shfl_xor(s, m);
  float mean = s * (1.f / 32.f);
  float d = v - mean;
  float q = d * d;
#pragma unroll
  for (int m = 16; m >= 1; m >>= 1) q += __shfl_xor(q, m);
  float rstd = rsqrtf(q * (1.f / 32.f) + 1e-5f);
  return d * rstd * g[o] + b[o];
}

// ---------------- positional-embedding maps ---------------------------------

__global__ void k_pe_maps(const float* __restrict__ pew_e, const float* __restrict__ peb_e,
                          const float* __restrict__ pew_d, const float* __restrict__ peb_d,
                          float* __restrict__ pe_enc, float* __restrict__ pe_dec) {
  int hw = blockIdx.x * 256 + threadIdx.x;
  if (hw >= HWp) return;
  int y = hw / 80, x = hw % 80;
  float g0 = y * (1.f / 79.f), g1 = x * (1.f / 79.f);
  float g2 = 1.f - g0, g3 = 1.f - g1;
#pragma unroll
  for (int c = 0; c < 32; ++c) {
    pe_enc[(size_t)hw * 32 + c] = peb_e[c] + g0 * pew_e[c * 4] + g1 * pew_e[c * 4 + 1] +
                                  g2 * pew_e[c * 4 + 2] + g3 * pew_e[c * 4 + 3];
    pe_dec[(size_t)c * HWp + hw] = peb_d[c] + g0 * pew_d[c * 4] + g1 * pew_d[c * 4 + 1] +
                                   g2 * pew_d[c * 4 + 2] + g3 * pew_d[c * 4 + 3];
  }
}

// ---------------- weight packing to MFMA A-fragment layout -------------------

__global__ void k_pack(const float* __restrict__ w, ushort* __restrict__ dst, int trans) {
  int tap = blockIdx.x;                       // 0..24
  int grp = threadIdx.x >> 6, lane = threadIdx.x & 63;
  int ky = tap / 5, kx = tap % 5;
  int m = grp * 16 + (lane & 15);
  int kb = (lane >> 4) * 8;
  ushort* o = dst + ((size_t)(tap * 2 + grp) * 64 + lane) * 8;
#pragma unroll
  for (int j = 0; j < 8; ++j) {
    int k = kb + j;
    float v = trans ? w[(size_t)k * 800 + m * 25 + (4 - ky) * 5 + (4 - kx)]
                    : w[(size_t)m * 800 + k * 25 + ky * 5 + kx];
    o[j] = f2bf(v);
  }
}

// ---------------- Tc / Ts for algebraic decoder conv1 ------------------------

__global__ void k_prep_tc(const float* __restrict__ w, float* __restrict__ tc) {
  const int rep[5] = {0, 1, 40, 78, 79};
  int cls = blockIdx.x;
  int yc = cls / 5, xc = cls % 5;
  int ci = threadIdx.x >> 5, co = threadIdx.x & 31;
  int yr = rep[yc], xr = rep[xc];
  float s = 0.f;
#pragma unroll
  for (int ky = 0; ky < 5; ++ky) {
    if ((unsigned)(yr + ky - 2) >= 80u) continue;
#pragma unroll
    for (int kx = 0; kx < 5; ++kx) {
      if ((unsigned)(xr + kx - 2) >= 80u) continue;
      s += w[(size_t)ci * 800 + co * 25 + (4 - ky) * 5 + (4 - kx)];
    }
  }
  tc[(size_t)cls * 1024 + ci * 32 + co] = s;
}

__global__ void k_ts(const float* __restrict__ tc, const float* __restrict__ slots,
                     float* __restrict__ ts) {
  int idx = blockIdx.x * 256 + threadIdx.x;
  if (idx >= 288 * 800) return;
  int img = idx / 800, rem = idx % 800;
  int cls = rem >> 5, o = rem & 31;
  float s = 0.f;
#pragma unroll
  for (int ci = 0; ci < 32; ++ci)
    s += tc[(size_t)cls * 1024 + ci * 32 + o] * slots[(size_t)img * 32 + ci];
  ts[idx] = s;
}

// ---------------- MFMA conv (32->32, 5x5, pad 2) -----------------------------
// MODE 0: input fp32 channel-major [c][hw] (PE-dec base computation, 1 img)
// MODE 1: input bf16 channel-last  [img][hw][c]
// MODE 2: input = relu(base[hw][c] + ts[n0+img][cls(hw)][c])  (fused dec1)
// Output: always bf16 channel-last. LDS 16B units swizzled u^=((x>>1)&3).

template <int MODE, bool RELU>
__global__ __launch_bounds__(256, 2) void k_conv_mfma(
    const void* __restrict__ in_, const ushort* __restrict__ wp,
    const float* __restrict__ bias, ushort* __restrict__ out_,
    const float* __restrict__ ts, int n0) {
  __shared__ int4 sm[4032];  // 12 rows * 84 x * 4 units
  const int n = blockIdx.y, rt = blockIdx.x;
  const int t = threadIdx.x;

  for (int i = t; i < 4032; i += 256) {
    int x = i % 84, ru = i / 84;
    int r = ru >> 2, u = ru & 3;
    int gy = rt * 8 + r - 2, gx = x - 2;
    int4 pk = {0, 0, 0, 0};
    if ((unsigned)gy < 80u && (unsigned)gx < 80u) {
      int hw = gy * 80 + gx;
      if constexpr (MODE == 0) {
        const float* fp = (const float*)in_;
        ushort bb[8];
#pragma unroll
        for (int j = 0; j < 8; ++j)
          bb[j] = f2bf(fp[(size_t)(u * 8 + j) * HWp + hw]);
        pk.x = (int)((uint)bb[0] | ((uint)bb[1] << 16));
        pk.y = (int)((uint)bb[2] | ((uint)bb[3] << 16));
        pk.z = (int)((uint)bb[4] | ((uint)bb[5] << 16));
        pk.w = (int)((uint)bb[6] | ((uint)bb[7] << 16));
      } else if constexpr (MODE == 1) {
        pk = *(const int4*)((const ushort*)in_ + ((size_t)n * HWp + hw) * 32 + u * 8);
      } else {  // MODE 2: fused dec1
        int4 bp = *(const int4*)((const ushort*)in_ + (size_t)hw * 32 + u * 8);
        int yc = gy < 2 ? gy : (gy > 77 ? gy - 75 : 2);
        int xc = gx < 2 ? gx : (gx > 77 ? gx - 75 : 2);
        const float* tp = ts + ((size_t)(n0 + n) * 25 + (yc * 5 + xc)) * 32 + u * 8;
        float t0, t1;
        uint* pw = (uint*)&pk;
        const uint* bw = (const uint*)&bp;
#pragma unroll
        for (int h = 0; h < 4; ++h) {
          unpk2(bw[h], t0, t1);
          float f0 = fmaxf(t0 + tp[2 * h], 0.f);
          float f1 = fmaxf(t1 + tp[2 * h + 1], 0.f);
          pw[h] = (uint)f2bf(f0) | ((uint)f2bf(f1) << 16);
        }
      }
    }
    int up = u ^ ((x >> 1) & 3);
    sm[(r * 84 + x) * 4 + up] = pk;
  }
  __syncthreads();

  const int wv = t >> 6, lane = t & 63;
  const int l15 = lane & 15, lg = lane >> 4;
  const short8* smS = (const short8*)sm;

  f32x4 acc[2][5][2];
#pragma unroll
  for (int a = 0; a < 2; ++a)
#pragma unroll
    for (int b = 0; b < 5; ++b)
#pragma unroll
      for (int c = 0; c < 2; ++c) acc[a][b][c] = f32x4{0.f, 0.f, 0.f, 0.f};

  for (int dy = 0; dy < 5; ++dy) {
    for (int dx = 0; dx < 5; ++dx) {
      int tap = dy * 5 + dx;
      short8 A0 = *(const short8*)(wp + ((size_t)(tap * 2 + 0) * 64 + lane) * 8);
      short8 A1 = *(const short8*)(wp + ((size_t)(tap * 2 + 1) * 64 + lane) * 8);
#pragma unroll
      for (int ri = 0; ri < 2; ++ri) {
        int rbase = (wv * 2 + ri + dy) * 336;
#pragma unroll
        for (int xg = 0; xg < 5; ++xg) {
          int xs = xg * 16 + l15 + dx;
          short8 Bv = smS[rbase + xs * 4 + (lg ^ ((xs >> 1) & 3))];
          acc[ri][xg][0] = __builtin_amdgcn_mfma_f32_16x16x32_bf16(A0, Bv, acc[ri][xg][0], 0, 0, 0);
          acc[ri][xg][1] = __builtin_amdgcn_mfma_f32_16x16x32_bf16(A1, Bv, acc[ri][xg][1], 0, 0, 0);
        }
      }
    }
  }

  // epilogue: channel-last bf16; lane writes 4 consecutive co as 8B
  float bv[2][4];
#pragma unroll
  for (int cg = 0; cg < 2; ++cg)
#pragma unroll
    for (int q = 0; q < 4; ++q) bv[cg][q] = bias[cg * 16 + lg * 4 + q];
  int y0 = rt * 8 + wv * 2;
#pragma unroll
  for (int ri = 0; ri < 2; ++ri) {
#pragma unroll
    for (int xg = 0; xg < 5; ++xg) {
      size_t px = (size_t)n * HWp + (y0 + ri) * 80 + (xg * 16 + l15);
#pragma unroll
      for (int cg = 0; cg < 2; ++cg) {
        f32x4 v = acc[ri][xg][cg];
        float o0 = v[0] + bv[cg][0], o1 = v[1] + bv[cg][1];
        float o2 = v[2] + bv[cg][2], o3 = v[3] + bv[cg][3];
        if (RELU) {
          o0 = fmaxf(o0, 0.f); o1 = fmaxf(o1, 0.f);
          o2 = fmaxf(o2, 0.f); o3 = fmaxf(o3, 0.f);
        }
        uint2 pk;
        pk.x = (uint)f2bf(o0) | ((uint)f2bf(o1) << 16);
        pk.y = (uint)f2bf(o2) | ((uint)f2bf(o3) << 16);
        *(uint2*)(out_ + px * 32 + cg * 16 + lg * 4) = pk;
      }
    }
  }
}

// ---------------- encoder conv1 (1->32, 5x5, relu) -> bf16 channel-last ------

__global__ __launch_bounds__(256) void k_conv1(const float* __restrict__ in,
                                               const float* __restrict__ w,
                                               const float* __restrict__ b,
                                               ushort* __restrict__ out) {
  int hw = blockIdx.x * 256 + threadIdx.x;
  int n = blockIdx.y;
  int y = hw / 80, x = hw % 80;
  float xv[25];
#pragma unroll
  for (int ky = 0; ky < 5; ++ky)
#pragma unroll
    for (int kx = 0; kx < 5; ++kx) {
      int iy = y + ky - 2, ix = x + kx - 2;
      xv[ky * 5 + kx] = ((unsigned)iy < 80u && (unsigned)ix < 80u)
                            ? in[(size_t)n * HWp + iy * 80 + ix] : 0.f;
    }
  float a[32];
#pragma unroll
  for (int co = 0; co < 32; ++co) {
    float s = b[co];
#pragma unroll
    for (int tp = 0; tp < 25; ++tp) s = fmaf(xv[tp], w[co * 25 + tp], s);
    a[co] = fmaxf(s, 0.f);
  }
  ushort* op = out + ((size_t)n * HWp + hw) * 32;
#pragma unroll
  for (int g = 0; g < 4; ++g) {
    uint4 pk;
    pk.x = (uint)f2bf(a[g * 8 + 0]) | ((uint)f2bf(a[g * 8 + 1]) << 16);
    pk.y = (uint)f2bf(a[g * 8 + 2]) | ((uint)f2bf(a[g * 8 + 3]) << 16);
    pk.z = (uint)f2bf(a[g * 8 + 4]) | ((uint)f2bf(a[g * 8 + 5]) << 16);
    pk.w = (uint)f2bf(a[g * 8 + 6]) | ((uint)f2bf(a[g * 8 + 7]) << 16);
    *(uint4*)(op + g * 8) = pk;
  }
}

// ---------------- decoder conv4 (32->2, 3x3, trans) --------------------------
// input bf16 channel-last; weights pre-flipped in LDS.

__global__ __launch_bounds__(256) void k_conv4(const ushort* __restrict__ in,
                                               const float* __restrict__ w,
                                               const float* __restrict__ b,
                                               float* __restrict__ outR,
                                               float* __restrict__ outM, int n0) {
  __shared__ float sw[2 * 288];  // [co][tap][ci]
  for (int e = threadIdx.x; e < 576; e += 256) {
    int co = e / 288, rem = e % 288;
    int tap = rem / 32, ci = rem % 32;
    sw[e] = w[(size_t)(ci * 2 + co) * 9 + 8 - tap];
  }
  __syncthreads();
  int hw = blockIdx.x * 256 + threadIdx.x;
  int nl = blockIdx.y;
  int y = hw / 80, x = hw % 80;
  float a0 = b[0], a1 = b[1];
  const ushort* ip = in + (size_t)nl * HWp * 32;
#pragma unroll
  for (int ky = 0; ky < 3; ++ky) {
#pragma unroll
    for (int kx = 0; kx < 3; ++kx) {
      int iy = y + ky - 1, ix = x + kx - 1;
      if ((unsigned)iy >= 80u || (unsigned)ix >= 80u) continue;
      int tap = ky * 3 + kx;
      const int4* p = (const int4*)(ip + (size_t)(iy * 80 + ix) * 32);
      const float* w0 = sw + tap * 32;
      const float* w1 = sw + 288 + tap * 32;
#pragma unroll
      for (int u = 0; u < 4; ++u) {
        int4 ch = p[u];
        const uint* cw = (const uint*)&ch;
#pragma unroll
        for (int h = 0; h < 4; ++h) {
          float v0, v1;
          unpk2(cw[h], v0, v1);
          int ci = u * 8 + h * 2;
          a0 = fmaf(v0, w0[ci], a0);     a1 = fmaf(v0, w1[ci], a1);
          a0 = fmaf(v1, w0[ci + 1], a0); a1 = fmaf(v1, w1[ci + 1], a1);
        }
      }
    }
  }
  outR[(size_t)(n0 + nl) * HWp + hw] = a0;
  outM[(size_t)(n0 + nl) * HWp + hw] = a1;
}

// ---------------- h = enc4 + PE (bf16 chlast in), stats ----------------------

__global__ __launch_bounds__(256) void k_hstats(const ushort* __restrict__ enc,
                                                const float* __restrict__ pe_enc,
                                                float* __restrict__ hbuf,
                                                float* __restrict__ lnpart) {
  int b = blockIdx.y;
  int hw = blockIdx.x * 256 + threadIdx.x;
  const int4* ep = (const int4*)(enc + ((size_t)b * HWp + hw) * 32);
  float v[32];
#pragma unroll
  for (int u = 0; u < 4; ++u) {
    int4 ch = ep[u];
    const uint* cw = (const uint*)&ch;
#pragma unroll
    for (int h = 0; h < 4; ++h) unpk2(cw[h], v[u * 8 + h * 2], v[u * 8 + h * 2 + 1]);
  }
  float s = 0.f, ss = 0.f;
#pragma unroll
  for (int c = 0; c < 32; ++c) {
    v[c] += pe_enc[(size_t)hw * 32 + c];
    s += v[c]; ss += v[c] * v[c];
  }
  float* hp = hbuf + ((size_t)b * HWp + hw) * 32;
#pragma unroll
  for (int c = 0; c < 32; ++c) hp[c] = v[c];
  __shared__ float r1[256], r2[256];
  r1[threadIdx.x] = s; r2[threadIdx.x] = ss;
  __syncthreads();
  for (int off = 128; off > 0; off >>= 1) {
    if (threadIdx.x < off) { r1[threadIdx.x] += r1[threadIdx.x + off]; r2[threadIdx.x] += r2[threadIdx.x + off]; }
    __syncthreads();
  }
  if (threadIdx.x == 0) {
    lnpart[(size_t)(b * 25 + blockIdx.x) * 2] = r1[0];
    lnpart[(size_t)(b * 25 + blockIdx.x) * 2 + 1] = r2[0];
  }
}

__global__ void k_statsfin(const float* __restrict__ lnpart, float* __restrict__ meanr) {
  int b = threadIdx.x;
  if (b >= 32) return;
  float s = 0.f, ss = 0.f;
  for (int k = 0; k < 25; ++k) {
    s += lnpart[(size_t)(b * 25 + k) * 2];
    ss += lnpart[(size_t)(b * 25 + k) * 2 + 1];
  }
  float m = s * (1.f / 204800.f);
  float var = ss * (1.f / 204800.f) - m * m;
  meanr[b * 2] = m;
  meanr[b * 2 + 1] = rsqrtf(var + 1e-5f);
}

__global__ __launch_bounds__(256) void k_lnmlpkv(
    const float* __restrict__ hbuf, const float* __restrict__ meanr,
    const float* __restrict__ g, const float* __restrict__ bb,
    const float* __restrict__ w1, const float* __restrict__ b1,
    const float* __restrict__ w2, const float* __restrict__ b2,
    const float* __restrict__ nig, const float* __restrict__ nib,
    const float* __restrict__ kw, const float* __restrict__ kb,
    const float* __restrict__ vw, const float* __restrict__ vb,
    float* __restrict__ keys, float* __restrict__ vals) {
  int b = blockIdx.y;
  int hw = blockIdx.x * 256 + threadIdx.x;
  float x[32], t0[32], t1[32];
  const float* hp = hbuf + ((size_t)b * HWp + hw) * 32;
  float m = meanr[b * 2], rs = meanr[b * 2 + 1];
#pragma unroll
  for (int c = 0; c < 32; ++c)
    x[c] = (hp[c] - m) * rs * g[(size_t)hw * 32 + c] + bb[(size_t)hw * 32 + c];
  matvec32(w1, b1, x, t0, true);
  matvec32(w2, b2, t0, t1, false);
  ln32v(t1, nig, nib, x);
  matvec32(kw, kb, x, t0, false);
  float* kp = keys + ((size_t)b * HWp + hw) * 32;
#pragma unroll
  for (int c = 0; c < 32; ++c) kp[c] = t0[c];
  matvec32(vw, vb, x, t0, false);
  float* vp = vals + ((size_t)b * HWp + hw) * 32;
#pragma unroll
  for (int c = 0; c < 32; ++c) vp[c] = t0[c];
}

// ---------------- slot attention (wide kernels) ------------------------------

__global__ __launch_bounds__(256) void k_init_q(
    const float* __restrict__ mu, const float* __restrict__ sig,
    const float* __restrict__ noise,
    const float* __restrict__ nsg, const float* __restrict__ nsb,
    const float* __restrict__ qw, const float* __restrict__ qb,
    float* __restrict__ slots, float* __restrict__ qbuf) {
  int rl = threadIdx.x >> 5, o = threadIdx.x & 31;
  int r = blockIdx.x * 8 + rl;
  float s = mu[o] + sig[o] * noise[(size_t)r * 32 + o];
  slots[(size_t)r * 32 + o] = s;
  float y = lane_ln(s, o, nsg, nsb);
  __shared__ float S[8][32];
  S[rl][o] = y;
  __syncthreads();
  float qv = qb[o];
#pragma unroll
  for (int c = 0; c < 32; ++c) qv = fmaf(S[rl][c], qw[o * 32 + c], qv);
  qbuf[(size_t)r * 32 + o] = qv;
}

__global__ __launch_bounds__(256) void k_gru_fused(
    const float* __restrict__ up2, const float* __restrict__ apart,
    float* __restrict__ slots, float* __restrict__ rowsum, float* __restrict__ qbuf,
    const float* __restrict__ wih, const float* __restrict__ whh,
    const float* __restrict__ bih, const float* __restrict__ bhh,
    const float* __restrict__ rlg, const float* __restrict__ rlb,
    const float* __restrict__ rw1, const float* __restrict__ rb1,
    const float* __restrict__ rw2, const float* __restrict__ rb2,
    const float* __restrict__ nsg, const float* __restrict__ nsb,
    const float* __restrict__ qw, const float* __restrict__ qb) {
  int rl = threadIdx.x >> 5, o = threadIdx.x & 31;
  int r = blockIdx.x * 8 + rl;
  int b = r / 9, i = r - b * 9;

  float rs = 0.f;
#pragma unroll
  for (int k = 0; k < 25; ++k) rs += apart[(size_t)(b * 9 + i) * 25 + k];
  if (o == 0) rowsum[r] = rs;

  float uo = 0.f;
#pragma unroll
  for (int jc = 0; jc < 8; ++jc) uo += up2[(((size_t)b * 8 + jc) * 9 + i) * 32 + o];
  uo /= rs;
  float ho = slots[(size_t)r * 32 + o];

  __shared__ float Us[8][32], Hs[8][32];
  Us[rl][o] = uo; Hs[rl][o] = ho;
  __syncthreads();

  float xr = bih[o], xz = bih[32 + o], xc = bih[64 + o];
  float hr = bhh[o], hz = bhh[32 + o], hc = bhh[64 + o];
#pragma unroll
  for (int c = 0; c < 32; ++c) {
    float u = Us[rl][c], h = Hs[rl][c];
    xr = fmaf(u, wih[o * 32 + c], xr);          hr = fmaf(h, whh[o * 32 + c], hr);
    xz = fmaf(u, wih[(32 + o) * 32 + c], xz);   hz = fmaf(h, whh[(32 + o) * 32 + c], hz);
    xc = fmaf(u, wih[(64 + o) * 32 + c], xc);   hc = fmaf(h, whh[(64 + o) * 32 + c], hc);
  }
  float rr = 1.f / (1.f + __expf(-(xr + hr)));
  float zz = 1.f / (1.f + __expf(-(xz + hz)));
  float cand = tanhf(xc + rr * hc);
  float sm = (1.f - zz) * cand + zz * ho;

  float y = lane_ln(sm, o, rlg, rlb);
  __syncthreads();
  Us[rl][o] = y;
  __syncthreads();
  float t1 = rb1[o];
#pragma unroll
  for (int c = 0; c < 32; ++c) t1 = fmaf(Us[rl][c], rw1[o * 32 + c], t1);
  t1 = fmaxf(t1, 0.f);
  Hs[rl][o] = t1;
  __syncthreads();
  float res = rb2[o];
#pragma unroll
  for (int c = 0; c < 32; ++c) res = fmaf(Hs[rl][c], rw2[o * 32 + c], res);
  float ns = sm + res;
  slots[(size_t)r * 32 + o] = ns;

  float y2 = lane_ln(ns, o, nsg, nsb);
  __syncthreads();
  Us[rl][o] = y2;
  __syncthreads();
  float qv = qb[o];
#pragma unroll
  for (int c = 0; c < 32; ++c) qv = fmaf(Us[rl][c], qw[o * 32 + c], qv);
  qbuf[(size_t)r * 32 + o] = qv;
}

__global__ __launch_bounds__(256) void k_dots(const float* __restrict__ qbuf,
                                              const float* __restrict__ keys,
                                              float* __restrict__ attnt,
                                              float* __restrict__ apart) {
  int b = blockIdx.y;
  int j = blockIdx.x * 256 + threadIdx.x;
  __shared__ float qs[288];
  for (int e = threadIdx.x; e < 288; e += 256) qs[e] = qbuf[(size_t)b * 288 + e];
  __syncthreads();
  float k[32];
  const float* kp = keys + ((size_t)b * HWp + j) * 32;
#pragma unroll
  for (int c = 0; c < 32; ++c) k[c] = kp[c];
  float d[9];
#pragma unroll
  for (int i = 0; i < 9; ++i) {
    float a = 0.f;
#pragma unroll
    for (int c = 0; c < 32; ++c) a = fmaf(qs[i * 32 + c], k[c], a);
    d[i] = a * SCALEf;
  }
  float mx = d[0];
#pragma unroll
  for (int i = 1; i < 9; ++i) mx = fmaxf(mx, d[i]);
  float sum = 0.f;
#pragma unroll
  for (int i = 0; i < 9; ++i) { d[i] = __expf(d[i] - mx); sum += d[i]; }
  float inv = 1.f / sum;
  float a[9];
#pragma unroll
  for (int i = 0; i < 9; ++i) {
    a[i] = d[i] * inv + 1e-8f;
    attnt[((size_t)b * 9 + i) * HWp + j] = a[i];
  }
  int lane = threadIdx.x & 63, wid = threadIdx.x >> 6;
  __shared__ float wr[4 * 9];
#pragma unroll
  for (int i = 0; i < 9; ++i) {
    float v = a[i];
    for (int off = 32; off > 0; off >>= 1) v += __shfl_down(v, off);
    if (lane == 0) wr[wid * 9 + i] = v;
  }
  __syncthreads();
  if (threadIdx.x < 9) {
    float v = wr[threadIdx.x] + wr[9 + threadIdx.x] + wr[18 + threadIdx.x] + wr[27 + threadIdx.x];
    apart[(size_t)(b * 9 + threadIdx.x) * 25 + blockIdx.x] = v;
  }
}

__global__ __launch_bounds__(256) void k_upd2(const float* __restrict__ vals,
                                              const float* __restrict__ attnt,
                                              float* __restrict__ up2) {
  int jc = blockIdx.x, b = blockIdx.y;
  int c = threadIdx.x & 31, g = threadIdx.x >> 5;
  float a9[9];
#pragma unroll
  for (int i = 0; i < 9; ++i) a9[i] = 0.f;
  const float* vp = vals + (size_t)b * HWp * 32;
  const float* ap = attnt + (size_t)b * 9 * HWp;
  int j0 = jc * 800;
  for (int j = j0 + g; j < j0 + 800; j += 8) {
    float v = vp[(size_t)j * 32 + c];
#pragma unroll
    for (int i = 0; i < 9; ++i) a9[i] = fmaf(v, ap[(size_t)i * HWp + j], a9[i]);
  }
  __shared__ float red[9][8][32];
#pragma unroll
  for (int i = 0; i < 9; ++i) red[i][g][c] = a9[i];
  __syncthreads();
  for (int i = threadIdx.x >> 5; i < 9; i += 8) {
    float s = 0.f;
#pragma unroll
    for (int g2 = 0; g2 < 8; ++g2) s += red[i][g2][c];
    up2[(((size_t)b * 8 + jc) * 9 + i) * 32 + c] = s;
  }
}

// ---------------- outputs ----------------------------------------------------

__global__ void k_attn_out(const float* __restrict__ attnt, const float* __restrict__ rsum,
                           float* __restrict__ out) {
  size_t idx = (size_t)blockIdx.x * 256 + threadIdx.x;
  out[O_ATTN + idx] = attnt[idx] / rsum[idx / HWp];
}

__global__ void k_slots_out(const float* __restrict__ slots, float* __restrict__ out) {
  int idx = blockIdx.x * 256 + threadIdx.x;
  if (idx < 9216) out[O_SLOTS + idx] = slots[idx];
}

__global__ __launch_bounds__(256) void k_final(float* __restrict__ out) {
  int b = blockIdx.y;
  int j = blockIdx.x * 256 + threadIdx.x;
  float r[9], ml[9];
#pragma unroll
  for (int s = 0; s < 9; ++s) {
    r[s]  = out[O_RECON + (size_t)(b * 9 + s) * HWp + j];
    ml[s] = out[O_MASK  + (size_t)(b * 9 + s) * HWp + j];
  }
  float mx = ml[0];
#pragma unroll
  for (int s = 1; s < 9; ++s) mx = fmaxf(mx, ml[s]);
  float sum = 0.f;
#pragma unroll
  for (int s = 0; s < 9; ++s) { ml[s] = __expf(ml[s] - mx); sum += ml[s]; }
  float inv = 1.f / sum;
  float comb = 0.f;
#pragma unroll
  for (int s = 0; s < 9; ++s) {
    float mk = ml[s] * inv;
    comb = fmaf(r[s], mk, comb);
    out[O_MASK + (size_t)(b * 9 + s) * HWp + j] = mk;
  }
  out[O_COMB + (size_t)b * HWp + j] = comb;
}

}  // namespace

// ---------------------------------------------------------------------------

extern "C" void kernel_launch(void* const* d_in, const int* in_sizes, int n_in,
                              void* d_out, int out_size, void* d_ws, size_t ws_size,
                              hipStream_t stream) {
  if (ws_size < W_TOTAL * sizeof(float)) return;

  const float* in_x       = (const float*)d_in[0];
  const float* slot_noise = (const float*)d_in[1];
  const float* enc_w1 = (const float*)d_in[2];   const float* enc_b1 = (const float*)d_in[3];
  const float* enc_w2 = (const float*)d_in[4];   const float* enc_b2 = (const float*)d_in[5];
  const float* enc_w3 = (const float*)d_in[6];   const float* enc_b3 = (const float*)d_in[7];
  const float* enc_w4 = (const float*)d_in[8];   const float* enc_b4 = (const float*)d_in[9];
  const float* pe_enc_w = (const float*)d_in[10]; const float* pe_enc_b = (const float*)d_in[11];
  const float* ln_enc_g = (const float*)d_in[12]; const float* ln_enc_b = (const float*)d_in[13];
  const float* mlp_w1 = (const float*)d_in[14];  const float* mlp_b1 = (const float*)d_in[15];
  const float* mlp_w2 = (const float*)d_in[16];  const float* mlp_b2 = (const float*)d_in[17];
  const float* slots_mu = (const float*)d_in[18]; const float* slots_sigma = (const float*)d_in[19];
  const float* ni_g = (const float*)d_in[20];    const float* ni_b = (const float*)d_in[21];
  const float* ns_g = (const float*)d_in[22];    const float* ns_b = (const float*)d_in[23];
  const float* q_w = (const float*)d_in[24];     const float* q_b = (const float*)d_in[25];
  const float* k_w = (const float*)d_in[26];     const float* k_b = (const float*)d_in[27];
  const float* v_w = (const float*)d_in[28];     const float* v_b = (const float*)d_in[29];
  const float* gru_wih = (const float*)d_in[30]; const float* gru_whh = (const float*)d_in[31];
  const float* gru_bih = (const float*)d_in[32]; const float* gru_bhh = (const float*)d_in[33];
  const float* res_ln_g = (const float*)d_in[34]; const float* res_ln_b = (const float*)d_in[35];
  const float* res_w1 = (const float*)d_in[36];  const float* res_b1 = (const float*)d_in[37];
  const float* res_w2 = (const float*)d_in[38];  const float* res_b2 = (const float*)d_in[39];
  const float* pe_dec_w = (const float*)d_in[40]; const float* pe_dec_b = (const float*)d_in[41];
  const float* dec_w1 = (const float*)d_in[42];  const float* dec_b1 = (const float*)d_in[43];
  const float* dec_w2 = (const float*)d_in[44];  const float* dec_b2 = (const float*)d_in[45];
  const float* dec_w3 = (const float*)d_in[46];  const float* dec_b3 = (const float*)d_in[47];
  const float* dec_w4 = (const float*)d_in[48];  const float* dec_b4 = (const float*)d_in[49];

  float* ws  = (float*)d_ws;
  float* out = (float*)d_out;
  ushort* wp = (ushort*)(ws + W_WP);

  k_pe_maps<<<dim3(25), 256, 0, stream>>>(pe_enc_w, pe_enc_b, pe_dec_w, pe_dec_b,
                                          ws + W_PEENC, ws + W_PEDEC);

  const size_t WPSTR = 25 * 2 * 64 * 8;
  k_pack<<<dim3(25), 128, 0, stream>>>(enc_w2, wp + 0 * WPSTR, 0);
  k_pack<<<dim3(25), 128, 0, stream>>>(enc_w3, wp + 1 * WPSTR, 0);
  k_pack<<<dim3(25), 128, 0, stream>>>(enc_w4, wp + 2 * WPSTR, 0);
  k_pack<<<dim3(25), 128, 0, stream>>>(dec_w1, wp + 3 * WPSTR, 1);
  k_pack<<<dim3(25), 128, 0, stream>>>(dec_w2, wp + 4 * WPSTR, 1);
  k_pack<<<dim3(25), 128, 0, stream>>>(dec_w3, wp + 5 * WPSTR, 1);
  k_prep_tc<<<dim3(25), 1024, 0, stream>>>(dec_w1, ws + W_TC);

  ushort* base = (ushort*)(ws + W_BASE);

  // base = convT1(pe_dec) + bias (1 img; fp32 chan-major in, bf16 chlast out)
  k_conv_mfma<0, false><<<dim3(10, 1), 256, 0, stream>>>(
      ws + W_PEDEC, wp + 3 * WPSTR, dec_b1, base, nullptr, 0);

  // ---------------- encoder (bf16 channel-last chain) ----------------
  ushort* E1 = (ushort*)(ws + W_A);
  ushort* E2 = (ushort*)(ws + W_B);
  k_conv1<<<dim3(25, Bb), 256, 0, stream>>>(in_x, enc_w1, enc_b1, E1);
  k_conv_mfma<1, true><<<dim3(10, Bb), 256, 0, stream>>>(E1, wp + 0 * WPSTR, enc_b2, E2, nullptr, 0);
  k_conv_mfma<1, true><<<dim3(10, Bb), 256, 0, stream>>>(E2, wp + 1 * WPSTR, enc_b3, E1, nullptr, 0);
  k_conv_mfma<1, true><<<dim3(10, Bb), 256, 0, stream>>>(E1, wp + 2 * WPSTR, enc_b4, E2, nullptr, 0);

  // h = E2 + PE -> W_A (fp32 chlast); per-batch LN stats
  k_hstats<<<dim3(25, Bb), 256, 0, stream>>>(E2, ws + W_PEENC, ws + W_A, ws + W_LNPART);
  k_statsfin<<<dim3(1), 64, 0, stream>>>(ws + W_LNPART, ws + W_MEANR);
  k_lnmlpkv<<<dim3(25, Bb), 256, 0, stream>>>(ws + W_A, ws + W_MEANR, ln_enc_g, ln_enc_b,
                                              mlp_w1, mlp_b1, mlp_w2, mlp_b2,
                                              ni_g, ni_b, k_w, k_b, v_w, v_b,
                                              ws + W_KEYS, ws + W_VALS);

  // ---------------- slot attention ----------------
  k_init_q<<<dim3(36), 256, 0, stream>>>(slots_mu, slots_sigma, slot_noise,
                                         ns_g, ns_b, q_w, q_b, ws + W_SLOTS, ws + W_Q);
  for (int it = 0; it < 3; ++it) {
    k_dots<<<dim3(25, Bb), 256, 0, stream>>>(ws + W_Q, ws + W_KEYS, ws + W_ATTNT, ws + W_APART);
    k_upd2<<<dim3(8, Bb), 256, 0, stream>>>(ws + W_VALS, ws + W_ATTNT, ws + W_UP2);
    k_gru_fused<<<dim3(36), 256, 0, stream>>>(ws + W_UP2, ws + W_APART,
                                              ws + W_SLOTS, ws + W_RSUM, ws + W_Q,
                                              gru_wih, gru_whh, gru_bih, gru_bhh,
                                              res_ln_g, res_ln_b, res_w1, res_b1,
                                              res_w2, res_b2, ns_g, ns_b, q_w, q_b);
  }
  k_attn_out<<<dim3(7200), 256, 0, stream>>>(ws + W_ATTNT, ws + W_RSUM, out);
  k_slots_out<<<dim3(36), 256, 0, stream>>>(ws + W_SLOTS, out);

  // Ts for all 288 images (uses final slots)
  k_ts<<<dim3(900), 256, 0, stream>>>(ws + W_TC, ws + W_SLOTS, ws + W_TS);

  // ---------------- decoder: 3 chunks of 96, dec1 fused into dec2 stage -----
  ushort* XA = (ushort*)(ws + W_A);
  ushort* XB = XA + (size_t)96 * 32 * HWp;
  for (int ch = 0; ch < 3; ++ch) {
    int n0 = ch * 96;
    k_conv_mfma<2, true><<<dim3(10, 96), 256, 0, stream>>>(base, wp + 4 * WPSTR, dec_b2, XA,
                                                           ws + W_TS, n0);
    k_conv_mfma<1, true><<<dim3(10, 96), 256, 0, stream>>>(XA, wp + 5 * WPSTR, dec_b3, XB,
                                                           nullptr, 0);
    k_conv4<<<dim3(25, 96), 256, 0, stream>>>(XB, dec_w4, dec_b4,
                                              out + O_RECON, out + O_MASK, n0);
  }

  k_final<<<dim3(25, Bb), 256, 0, stream>>>(out);
}

// Round 6
// 696.914 us; speedup vs baseline: 14.4012x; 1.1404x over previous
//
#include <hip/hip_runtime.h>
#include <cstddef>
#include <cstdint>

// ---------------------------------------------------------------------------
// STSN forward, v6: v5 + bf16 keys/vals, no h buffer, fused dots+upd,
// attnt written only on last iteration, workspace aliasing.
// B=32, H=W=80, C=32, S=9, ITERS=3
// ---------------------------------------------------------------------------

namespace {

constexpr int Bb  = 32;
constexpr int HWp = 6400;
constexpr float SCALEf = 0.17677669529663687f;  // 32^-0.5

// output section offsets (floats)
constexpr size_t O_COMB  = 0;
constexpr size_t O_RECON = 204800;
constexpr size_t O_MASK  = 2048000;
constexpr size_t O_SLOTS = 3891200;
constexpr size_t O_ATTN  = 3900416;

// workspace layout (float offsets)
constexpr size_t W_PEENC = 0;                 // 204800 [hw][c] fp32
constexpr size_t W_PEDEC = 204800;            // 204800 [c][hw] fp32
constexpr size_t W_BASE  = 409600;            // 102400 (bf16 [hw][c], 204800 ushorts)
constexpr size_t W_TC    = 512000;            // 25600
constexpr size_t W_TS    = 537600;            // 230400
constexpr size_t W_WP    = 768000;            // 76800 (packed bf16 weights)
constexpr size_t W_LNPART= 844800;            // 1600
constexpr size_t W_MEANR = 846400;            // 64
constexpr size_t W_Q     = 846464;            // 9216
constexpr size_t W_SLOTS = 855680;            // 9216
constexpr size_t W_APART = 864896;            // 7200  (288 x 25)
constexpr size_t W_RSUM  = 872096;            // 288
constexpr size_t W_UP2   = 872384;            // 230400 (32b x 25jb x 9 x 32)
constexpr size_t W_KEYS  = 1102784;           // 3276800 (bf16 [b][hw][c])
constexpr size_t W_VALS  = 4379584;           // 3276800 (bf16)
constexpr size_t W_POOL  = 7656384;           // 21458944 floats available
constexpr size_t W_TOTAL = 29115328;          // 116.5 MB (verified fits)
// Pool aliasing (disjoint lifetimes):
//   E1 bf16 [0..3276800) ; E2 bf16 [3276800..6553600)   (encoder phase)
//   attnt fp32 [0..1843200)                             (attention phase)
//   XA bf16 [0..9830400) ; XB bf16 [9830400..19660800)  (decoder phase)

typedef __attribute__((ext_vector_type(8))) short short8;
typedef __attribute__((ext_vector_type(4))) float f32x4;

__device__ __forceinline__ ushort f2bf(float f) {
  uint u = __builtin_bit_cast(uint, f);
  uint r = (u + 0x7fffu + ((u >> 16) & 1u)) >> 16;   // RNE
  return (ushort)r;
}
__device__ __forceinline__ float bf2f(ushort b) {
  uint u = ((uint)b) << 16;
  return __builtin_bit_cast(float, u);
}
__device__ __forceinline__ void unpk2(uint w, float& a, float& b) {
  a = __builtin_bit_cast(float, w << 16);
  b = __builtin_bit_cast(float, w & 0xffff0000u);
}

__device__ __forceinline__ void ln32v(const float* x, const float* __restrict__ g,
                                      const float* __restrict__ b, float* y) {
  float m = 0.f;
#pragma unroll
  for (int c = 0; c < 32; ++c) m += x[c];
  m *= (1.f / 32.f);
  float v = 0.f;
#pragma unroll
  for (int c = 0; c < 32; ++c) { float d = x[c] - m; v += d * d; }
  v *= (1.f / 32.f);
  float rs = rsqrtf(v + 1e-5f);
#pragma unroll
  for (int c = 0; c < 32; ++c) y[c] = (x[c] - m) * rs * g[c] + b[c];
}

__device__ __forceinline__ void matvec32(const float* __restrict__ W,
                                         const float* __restrict__ bias,
                                         const float* x, float* y, bool relu) {
#pragma unroll
  for (int o = 0; o < 32; ++o) {
    float a = bias[o];
#pragma unroll
    for (int c = 0; c < 32; ++c) a = fmaf(x[c], W[o * 32 + c], a);
    y[o] = relu ? fmaxf(a, 0.f) : a;
  }
}

__device__ __forceinline__ float lane_ln(float v, int o, const float* __restrict__ g,
                                         const float* __restrict__ b) {
  float s = v;
#pragma unroll
  for (int m = 16; m >= 1; m >>= 1) s += __shfl_xor(s, m);
  float mean = s * (1.f / 32.f);
  float d = v - mean;
  float q = d * d;
#pragma unroll
  for (int m = 16; m >= 1; m >>= 1) q += __shfl_xor(q, m);
  float rstd = rsqrtf(q * (1.f / 32.f) + 1e-5f);
  return d * rstd * g[o] + b[o];
}

// ---------------- positional-embedding maps ---------------------------------

__global__ void k_pe_maps(const float* __restrict__ pew_e, const float* __restrict__ peb_e,
                          const float* __restrict__ pew_d, const float* __restrict__ peb_d,
                          float* __restrict__ pe_enc, float* __restrict__ pe_dec) {
  int hw = blockIdx.x * 256 + threadIdx.x;
  if (hw >= HWp) return;
  int y = hw / 80, x = hw % 80;
  float g0 = y * (1.f / 79.f), g1 = x * (1.f / 79.f);
  float g2 = 1.f - g0, g3 = 1.f - g1;
#pragma unroll
  for (int c = 0; c < 32; ++c) {
    pe_enc[(size_t)hw * 32 + c] = peb_e[c] + g0 * pew_e[c * 4] + g1 * pew_e[c * 4 + 1] +
                                  g2 * pew_e[c * 4 + 2] + g3 * pew_e[c * 4 + 3];
    pe_dec[(size_t)c * HWp + hw] = peb_d[c] + g0 * pew_d[c * 4] + g1 * pew_d[c * 4 + 1] +
                                   g2 * pew_d[c * 4 + 2] + g3 * pew_d[c * 4 + 3];
  }
}

// ---------------- weight packing to MFMA A-fragment layout -------------------

__global__ void k_pack(const float* __restrict__ w, ushort* __restrict__ dst, int trans) {
  int tap = blockIdx.x;
  int grp = threadIdx.x >> 6, lane = threadIdx.x & 63;
  int ky = tap / 5, kx = tap % 5;
  int m = grp * 16 + (lane & 15);
  int kb = (lane >> 4) * 8;
  ushort* o = dst + ((size_t)(tap * 2 + grp) * 64 + lane) * 8;
#pragma unroll
  for (int j = 0; j < 8; ++j) {
    int k = kb + j;
    float v = trans ? w[(size_t)k * 800 + m * 25 + (4 - ky) * 5 + (4 - kx)]
                    : w[(size_t)m * 800 + k * 25 + ky * 5 + kx];
    o[j] = f2bf(v);
  }
}

// ---------------- Tc / Ts for algebraic decoder conv1 ------------------------

__global__ void k_prep_tc(const float* __restrict__ w, float* __restrict__ tc) {
  const int rep[5] = {0, 1, 40, 78, 79};
  int cls = blockIdx.x;
  int yc = cls / 5, xc = cls % 5;
  int ci = threadIdx.x >> 5, co = threadIdx.x & 31;
  int yr = rep[yc], xr = rep[xc];
  float s = 0.f;
#pragma unroll
  for (int ky = 0; ky < 5; ++ky) {
    if ((unsigned)(yr + ky - 2) >= 80u) continue;
#pragma unroll
    for (int kx = 0; kx < 5; ++kx) {
      if ((unsigned)(xr + kx - 2) >= 80u) continue;
      s += w[(size_t)ci * 800 + co * 25 + (4 - ky) * 5 + (4 - kx)];
    }
  }
  tc[(size_t)cls * 1024 + ci * 32 + co] = s;
}

__global__ void k_ts(const float* __restrict__ tc, const float* __restrict__ slots,
                     float* __restrict__ ts) {
  int idx = blockIdx.x * 256 + threadIdx.x;
  if (idx >= 288 * 800) return;
  int img = idx / 800, rem = idx % 800;
  int cls = rem >> 5, o = rem & 31;
  float s = 0.f;
#pragma unroll
  for (int ci = 0; ci < 32; ++ci)
    s += tc[(size_t)cls * 1024 + ci * 32 + o] * slots[(size_t)img * 32 + ci];
  ts[idx] = s;
}

// ---------------- MFMA conv (32->32, 5x5, pad 2) -----------------------------
// MODE 0: fp32 channel-major input (base precompute). MODE 1: bf16 chlast.
// MODE 2: relu(base[hw][c] + ts[n0+img][cls(hw)][c]) fused dec1.

template <int MODE, bool RELU>
__global__ __launch_bounds__(256, 2) void k_conv_mfma(
    const void* __restrict__ in_, const ushort* __restrict__ wp,
    const float* __restrict__ bias, ushort* __restrict__ out_,
    const float* __restrict__ ts, int n0) {
  __shared__ int4 sm[4032];
  const int n = blockIdx.y, rt = blockIdx.x;
  const int t = threadIdx.x;

  for (int i = t; i < 4032; i += 256) {
    int x = i % 84, ru = i / 84;
    int r = ru >> 2, u = ru & 3;
    int gy = rt * 8 + r - 2, gx = x - 2;
    int4 pk = {0, 0, 0, 0};
    if ((unsigned)gy < 80u && (unsigned)gx < 80u) {
      int hw = gy * 80 + gx;
      if constexpr (MODE == 0) {
        const float* fp = (const float*)in_;
        ushort bb[8];
#pragma unroll
        for (int j = 0; j < 8; ++j)
          bb[j] = f2bf(fp[(size_t)(u * 8 + j) * HWp + hw]);
        pk.x = (int)((uint)bb[0] | ((uint)bb[1] << 16));
        pk.y = (int)((uint)bb[2] | ((uint)bb[3] << 16));
        pk.z = (int)((uint)bb[4] | ((uint)bb[5] << 16));
        pk.w = (int)((uint)bb[6] | ((uint)bb[7] << 16));
      } else if constexpr (MODE == 1) {
        pk = *(const int4*)((const ushort*)in_ + ((size_t)n * HWp + hw) * 32 + u * 8);
      } else {
        int4 bp = *(const int4*)((const ushort*)in_ + (size_t)hw * 32 + u * 8);
        int yc = gy < 2 ? gy : (gy > 77 ? gy - 75 : 2);
        int xc = gx < 2 ? gx : (gx > 77 ? gx - 75 : 2);
        const float* tp = ts + ((size_t)(n0 + n) * 25 + (yc * 5 + xc)) * 32 + u * 8;
        float t0, t1;
        uint* pw = (uint*)&pk;
        const uint* bw = (const uint*)&bp;
#pragma unroll
        for (int h = 0; h < 4; ++h) {
          unpk2(bw[h], t0, t1);
          float f0 = fmaxf(t0 + tp[2 * h], 0.f);
          float f1 = fmaxf(t1 + tp[2 * h + 1], 0.f);
          pw[h] = (uint)f2bf(f0) | ((uint)f2bf(f1) << 16);
        }
      }
    }
    int up = u ^ ((x >> 1) & 3);
    sm[(r * 84 + x) * 4 + up] = pk;
  }
  __syncthreads();

  const int wv = t >> 6, lane = t & 63;
  const int l15 = lane & 15, lg = lane >> 4;
  const short8* smS = (const short8*)sm;

  f32x4 acc[2][5][2];
#pragma unroll
  for (int a = 0; a < 2; ++a)
#pragma unroll
    for (int b = 0; b < 5; ++b)
#pragma unroll
      for (int c = 0; c < 2; ++c) acc[a][b][c] = f32x4{0.f, 0.f, 0.f, 0.f};

  for (int dy = 0; dy < 5; ++dy) {
    for (int dx = 0; dx < 5; ++dx) {
      int tap = dy * 5 + dx;
      short8 A0 = *(const short8*)(wp + ((size_t)(tap * 2 + 0) * 64 + lane) * 8);
      short8 A1 = *(const short8*)(wp + ((size_t)(tap * 2 + 1) * 64 + lane) * 8);
#pragma unroll
      for (int ri = 0; ri < 2; ++ri) {
        int rbase = (wv * 2 + ri + dy) * 336;
#pragma unroll
        for (int xg = 0; xg < 5; ++xg) {
          int xs = xg * 16 + l15 + dx;
          short8 Bv = smS[rbase + xs * 4 + (lg ^ ((xs >> 1) & 3))];
          acc[ri][xg][0] = __builtin_amdgcn_mfma_f32_16x16x32_bf16(A0, Bv, acc[ri][xg][0], 0, 0, 0);
          acc[ri][xg][1] = __builtin_amdgcn_mfma_f32_16x16x32_bf16(A1, Bv, acc[ri][xg][1], 0, 0, 0);
        }
      }
    }
  }

  float bv[2][4];
#pragma unroll
  for (int cg = 0; cg < 2; ++cg)
#pragma unroll
    for (int q = 0; q < 4; ++q) bv[cg][q] = bias[cg * 16 + lg * 4 + q];
  int y0 = rt * 8 + wv * 2;
#pragma unroll
  for (int ri = 0; ri < 2; ++ri) {
#pragma unroll
    for (int xg = 0; xg < 5; ++xg) {
      size_t px = (size_t)n * HWp + (y0 + ri) * 80 + (xg * 16 + l15);
#pragma unroll
      for (int cg = 0; cg < 2; ++cg) {
        f32x4 v = acc[ri][xg][cg];
        float o0 = v[0] + bv[cg][0], o1 = v[1] + bv[cg][1];
        float o2 = v[2] + bv[cg][2], o3 = v[3] + bv[cg][3];
        if (RELU) {
          o0 = fmaxf(o0, 0.f); o1 = fmaxf(o1, 0.f);
          o2 = fmaxf(o2, 0.f); o3 = fmaxf(o3, 0.f);
        }
        uint2 pk;
        pk.x = (uint)f2bf(o0) | ((uint)f2bf(o1) << 16);
        pk.y = (uint)f2bf(o2) | ((uint)f2bf(o3) << 16);
        *(uint2*)(out_ + px * 32 + cg * 16 + lg * 4) = pk;
      }
    }
  }
}

// ---------------- encoder conv1 ----------------------------------------------

__global__ __launch_bounds__(256) void k_conv1(const float* __restrict__ in,
                                               const float* __restrict__ w,
                                               const float* __restrict__ b,
                                               ushort* __restrict__ out) {
  int hw = blockIdx.x * 256 + threadIdx.x;
  int n = blockIdx.y;
  int y = hw / 80, x = hw % 80;
  float xv[25];
#pragma unroll
  for (int ky = 0; ky < 5; ++ky)
#pragma unroll
    for (int kx = 0; kx < 5; ++kx) {
      int iy = y + ky - 2, ix = x + kx - 2;
      xv[ky * 5 + kx] = ((unsigned)iy < 80u && (unsigned)ix < 80u)
                            ? in[(size_t)n * HWp + iy * 80 + ix] : 0.f;
    }
  float a[32];
#pragma unroll
  for (int co = 0; co < 32; ++co) {
    float s = b[co];
#pragma unroll
    for (int tp = 0; tp < 25; ++tp) s = fmaf(xv[tp], w[co * 25 + tp], s);
    a[co] = fmaxf(s, 0.f);
  }
  ushort* op = out + ((size_t)n * HWp + hw) * 32;
#pragma unroll
  for (int g = 0; g < 4; ++g) {
    uint4 pk;
    pk.x = (uint)f2bf(a[g * 8 + 0]) | ((uint)f2bf(a[g * 8 + 1]) << 16);
    pk.y = (uint)f2bf(a[g * 8 + 2]) | ((uint)f2bf(a[g * 8 + 3]) << 16);
    pk.z = (uint)f2bf(a[g * 8 + 4]) | ((uint)f2bf(a[g * 8 + 5]) << 16);
    pk.w = (uint)f2bf(a[g * 8 + 6]) | ((uint)f2bf(a[g * 8 + 7]) << 16);
    *(uint4*)(op + g * 8) = pk;
  }
}

// ---------------- decoder conv4 (32->2, 3x3, trans) --------------------------

__global__ __launch_bounds__(256) void k_conv4(const ushort* __restrict__ in,
                                               const float* __restrict__ w,
                                               const float* __restrict__ b,
                                               float* __restrict__ outR,
                                               float* __restrict__ outM, int n0) {
  __shared__ float sw[2 * 288];
  for (int e = threadIdx.x; e < 576; e += 256) {
    int co = e / 288, rem = e % 288;
    int tap = rem / 32, ci = rem % 32;
    sw[e] = w[(size_t)(ci * 2 + co) * 9 + 8 - tap];
  }
  __syncthreads();
  int hw = blockIdx.x * 256 + threadIdx.x;
  int nl = blockIdx.y;
  int y = hw / 80, x = hw % 80;
  float a0 = b[0], a1 = b[1];
  const ushort* ip = in + (size_t)nl * HWp * 32;
#pragma unroll
  for (int ky = 0; ky < 3; ++ky) {
#pragma unroll
    for (int kx = 0; kx < 3; ++kx) {
      int iy = y + ky - 1, ix = x + kx - 1;
      if ((unsigned)iy >= 80u || (unsigned)ix >= 80u) continue;
      int tap = ky * 3 + kx;
      const int4* p = (const int4*)(ip + (size_t)(iy * 80 + ix) * 32);
      const float* w0 = sw + tap * 32;
      const float* w1 = sw + 288 + tap * 32;
#pragma unroll
      for (int u = 0; u < 4; ++u) {
        int4 ch = p[u];
        const uint* cw = (const uint*)&ch;
#pragma unroll
        for (int h = 0; h < 4; ++h) {
          float v0, v1;
          unpk2(cw[h], v0, v1);
          int ci = u * 8 + h * 2;
          a0 = fmaf(v0, w0[ci], a0);     a1 = fmaf(v0, w1[ci], a1);
          a0 = fmaf(v1, w0[ci + 1], a0); a1 = fmaf(v1, w1[ci + 1], a1);
        }
      }
    }
  }
  outR[(size_t)(n0 + nl) * HWp + hw] = a0;
  outM[(size_t)(n0 + nl) * HWp + hw] = a1;
}

// ---------------- big-LN stats from E2+PE (no h store) -----------------------

__global__ __launch_bounds__(256) void k_hstats(const ushort* __restrict__ enc,
                                                const float* __restrict__ pe_enc,
                                                float* __restrict__ lnpart) {
  int b = blockIdx.y;
  int hw = blockIdx.x * 256 + threadIdx.x;
  const int4* ep = (const int4*)(enc + ((size_t)b * HWp + hw) * 32);
  float v[32];
#pragma unroll
  for (int u = 0; u < 4; ++u) {
    int4 ch = ep[u];
    const uint* cw = (const uint*)&ch;
#pragma unroll
    for (int h = 0; h < 4; ++h) unpk2(cw[h], v[u * 8 + h * 2], v[u * 8 + h * 2 + 1]);
  }
  float s = 0.f, ss = 0.f;
#pragma unroll
  for (int c = 0; c < 32; ++c) {
    v[c] += pe_enc[(size_t)hw * 32 + c];
    s += v[c]; ss += v[c] * v[c];
  }
  __shared__ float r1[256], r2[256];
  r1[threadIdx.x] = s; r2[threadIdx.x] = ss;
  __syncthreads();
  for (int off = 128; off > 0; off >>= 1) {
    if (threadIdx.x < off) { r1[threadIdx.x] += r1[threadIdx.x + off]; r2[threadIdx.x] += r2[threadIdx.x + off]; }
    __syncthreads();
  }
  if (threadIdx.x == 0) {
    lnpart[(size_t)(b * 25 + blockIdx.x) * 2] = r1[0];
    lnpart[(size_t)(b * 25 + blockIdx.x) * 2 + 1] = r2[0];
  }
}

__global__ void k_statsfin(const float* __restrict__ lnpart, float* __restrict__ meanr) {
  int b = threadIdx.x;
  if (b >= 32) return;
  float s = 0.f, ss = 0.f;
  for (int k = 0; k < 25; ++k) {
    s += lnpart[(size_t)(b * 25 + k) * 2];
    ss += lnpart[(size_t)(b * 25 + k) * 2 + 1];
  }
  float m = s * (1.f / 204800.f);
  float var = ss * (1.f / 204800.f) - m * m;
  meanr[b * 2] = m;
  meanr[b * 2 + 1] = rsqrtf(var + 1e-5f);
}

// ---------------- LN + MLP + per-pos LN + K/V (recomputes h from E2+PE) ------

__global__ __launch_bounds__(256) void k_lnmlpkv(
    const ushort* __restrict__ enc, const float* __restrict__ pe_enc,
    const float* __restrict__ meanr,
    const float* __restrict__ g, const float* __restrict__ bb,
    const float* __restrict__ w1, const float* __restrict__ b1,
    const float* __restrict__ w2, const float* __restrict__ b2,
    const float* __restrict__ nig, const float* __restrict__ nib,
    const float* __restrict__ kw, const float* __restrict__ kb,
    const float* __restrict__ vw, const float* __restrict__ vb,
    ushort* __restrict__ keys, ushort* __restrict__ vals) {
  int b = blockIdx.y;
  int hw = blockIdx.x * 256 + threadIdx.x;
  float x[32], t0[32], t1[32];
  const int4* ep = (const int4*)(enc + ((size_t)b * HWp + hw) * 32);
#pragma unroll
  for (int u = 0; u < 4; ++u) {
    int4 ch = ep[u];
    const uint* cw = (const uint*)&ch;
#pragma unroll
    for (int h = 0; h < 4; ++h) unpk2(cw[h], x[u * 8 + h * 2], x[u * 8 + h * 2 + 1]);
  }
  float m = meanr[b * 2], rs = meanr[b * 2 + 1];
#pragma unroll
  for (int c = 0; c < 32; ++c) {
    float h = x[c] + pe_enc[(size_t)hw * 32 + c];
    x[c] = (h - m) * rs * g[(size_t)hw * 32 + c] + bb[(size_t)hw * 32 + c];
  }
  matvec32(w1, b1, x, t0, true);
  matvec32(w2, b2, t0, t1, false);
  ln32v(t1, nig, nib, x);
  matvec32(kw, kb, x, t0, false);
  matvec32(vw, vb, x, t1, false);
  ushort* kp = keys + ((size_t)b * HWp + hw) * 32;
  ushort* vp = vals + ((size_t)b * HWp + hw) * 32;
#pragma unroll
  for (int gq = 0; gq < 4; ++gq) {
    uint4 pk, pv;
    pk.x = (uint)f2bf(t0[gq * 8 + 0]) | ((uint)f2bf(t0[gq * 8 + 1]) << 16);
    pk.y = (uint)f2bf(t0[gq * 8 + 2]) | ((uint)f2bf(t0[gq * 8 + 3]) << 16);
    pk.z = (uint)f2bf(t0[gq * 8 + 4]) | ((uint)f2bf(t0[gq * 8 + 5]) << 16);
    pk.w = (uint)f2bf(t0[gq * 8 + 6]) | ((uint)f2bf(t0[gq * 8 + 7]) << 16);
    pv.x = (uint)f2bf(t1[gq * 8 + 0]) | ((uint)f2bf(t1[gq * 8 + 1]) << 16);
    pv.y = (uint)f2bf(t1[gq * 8 + 2]) | ((uint)f2bf(t1[gq * 8 + 3]) << 16);
    pv.z = (uint)f2bf(t1[gq * 8 + 4]) | ((uint)f2bf(t1[gq * 8 + 5]) << 16);
    pv.w = (uint)f2bf(t1[gq * 8 + 6]) | ((uint)f2bf(t1[gq * 8 + 7]) << 16);
    *(uint4*)(kp + gq * 8) = pk;
    *(uint4*)(vp + gq * 8) = pv;
  }
}

// ---------------- slot attention -------------------------------------------

__global__ __launch_bounds__(256) void k_init_q(
    const float* __restrict__ mu, const float* __restrict__ sig,
    const float* __restrict__ noise,
    const float* __restrict__ nsg, const float* __restrict__ nsb,
    const float* __restrict__ qw, const float* __restrict__ qb,
    float* __restrict__ slots, float* __restrict__ qbuf) {
  int rl = threadIdx.x >> 5, o = threadIdx.x & 31;
  int r = blockIdx.x * 8 + rl;
  float s = mu[o] + sig[o] * noise[(size_t)r * 32 + o];
  slots[(size_t)r * 32 + o] = s;
  float y = lane_ln(s, o, nsg, nsb);
  __shared__ float S[8][32];
  S[rl][o] = y;
  __syncthreads();
  float qv = qb[o];
#pragma unroll
  for (int c = 0; c < 32; ++c) qv = fmaf(S[rl][c], qw[o * 32 + c], qv);
  qbuf[(size_t)r * 32 + o] = qv;
}

// fused dots + softmax + apart + V-weighted partial sums
template <bool LAST>
__global__ __launch_bounds__(256) void k_dots_upd(
    const float* __restrict__ qbuf, const ushort* __restrict__ keys,
    const ushort* __restrict__ vals, float* __restrict__ attnt,
    float* __restrict__ apart, float* __restrict__ up2) {
  int b = blockIdx.y, jb = blockIdx.x;
  int t = threadIdx.x;
  int j = jb * 256 + t;
  __shared__ float qs[288];
  __shared__ float aL[2304];   // [256][9] then aliased as [9][8][32]
  __shared__ float wr[36];
  for (int e = t; e < 288; e += 256) qs[e] = qbuf[(size_t)b * 288 + e];
  __syncthreads();
  float k[32];
  const int4* kp = (const int4*)(keys + ((size_t)b * HWp + j) * 32);
#pragma unroll
  for (int u = 0; u < 4; ++u) {
    int4 ch = kp[u];
    const uint* cw = (const uint*)&ch;
#pragma unroll
    for (int h = 0; h < 4; ++h) unpk2(cw[h], k[u * 8 + h * 2], k[u * 8 + h * 2 + 1]);
  }
  float d[9];
#pragma unroll
  for (int i = 0; i < 9; ++i) {
    float a = 0.f;
#pragma unroll
    for (int c = 0; c < 32; ++c) a = fmaf(qs[i * 32 + c], k[c], a);
    d[i] = a * SCALEf;
  }
  float mx = d[0];
#pragma unroll
  for (int i = 1; i < 9; ++i) mx = fmaxf(mx, d[i]);
  float sum = 0.f;
#pragma unroll
  for (int i = 0; i < 9; ++i) { d[i] = __expf(d[i] - mx); sum += d[i]; }
  float inv = 1.f / sum;
  float a9[9];
#pragma unroll
  for (int i = 0; i < 9; ++i) {
    a9[i] = d[i] * inv + 1e-8f;
    if (LAST) attnt[((size_t)b * 9 + i) * HWp + j] = a9[i];
    aL[t * 9 + i] = a9[i];
  }
  int lane = t & 63, wid = t >> 6;
#pragma unroll
  for (int i = 0; i < 9; ++i) {
    float v = a9[i];
    for (int off = 32; off > 0; off >>= 1) v += __shfl_down(v, off);
    if (lane == 0) wr[wid * 9 + i] = v;
  }
  __syncthreads();
  if (t < 9)
    apart[(size_t)(b * 9 + t) * 25 + jb] = wr[t] + wr[9 + t] + wr[18 + t] + wr[27 + t];
  // phase 2: acc[i][c] += vals[j][c] * a[i][j] over the block's 256 positions
  int c = t & 31, g = t >> 5;
  float acc[9];
#pragma unroll
  for (int i = 0; i < 9; ++i) acc[i] = 0.f;
  const ushort* vp = vals + ((size_t)b * HWp + jb * 256) * 32 + c;
  for (int jj = g; jj < 256; jj += 8) {
    float v = bf2f(vp[(size_t)jj * 32]);
#pragma unroll
    for (int i = 0; i < 9; ++i) acc[i] = fmaf(v, aL[jj * 9 + i], acc[i]);
  }
  __syncthreads();
#pragma unroll
  for (int i = 0; i < 9; ++i) aL[(i * 8 + g) * 32 + c] = acc[i];
  __syncthreads();
  for (int i = g; i < 9; i += 8) {
    float s = 0.f;
#pragma unroll
    for (int g2 = 0; g2 < 8; ++g2) s += aL[(i * 8 + g2) * 32 + c];
    up2[(((size_t)b * 25 + jb) * 9 + i) * 32 + c] = s;
  }
}

__global__ __launch_bounds__(256) void k_gru_fused(
    const float* __restrict__ up2, const float* __restrict__ apart,
    float* __restrict__ slots, float* __restrict__ rowsum, float* __restrict__ qbuf,
    const float* __restrict__ wih, const float* __restrict__ whh,
    const float* __restrict__ bih, const float* __restrict__ bhh,
    const float* __restrict__ rlg, const float* __restrict__ rlb,
    const float* __restrict__ rw1, const float* __restrict__ rb1,
    const float* __restrict__ rw2, const float* __restrict__ rb2,
    const float* __restrict__ nsg, const float* __restrict__ nsb,
    const float* __restrict__ qw, const float* __restrict__ qb) {
  int rl = threadIdx.x >> 5, o = threadIdx.x & 31;
  int r = blockIdx.x * 8 + rl;
  int b = r / 9, i = r - b * 9;

  float rs = 0.f;
#pragma unroll
  for (int k = 0; k < 25; ++k) rs += apart[(size_t)(b * 9 + i) * 25 + k];
  if (o == 0) rowsum[r] = rs;

  float uo = 0.f;
#pragma unroll
  for (int jc = 0; jc < 25; ++jc) uo += up2[(((size_t)b * 25 + jc) * 9 + i) * 32 + o];
  uo /= rs;
  float ho = slots[(size_t)r * 32 + o];

  __shared__ float Us[8][32], Hs[8][32];
  Us[rl][o] = uo; Hs[rl][o] = ho;
  __syncthreads();

  float xr = bih[o], xz = bih[32 + o], xc = bih[64 + o];
  float hr = bhh[o], hz = bhh[32 + o], hc = bhh[64 + o];
#pragma unroll
  for (int c = 0; c < 32; ++c) {
    float u = Us[rl][c], h = Hs[rl][c];
    xr = fmaf(u, wih[o * 32 + c], xr);          hr = fmaf(h, whh[o * 32 + c], hr);
    xz = fmaf(u, wih[(32 + o) * 32 + c], xz);   hz = fmaf(h, whh[(32 + o) * 32 + c], hz);
    xc = fmaf(u, wih[(64 + o) * 32 + c], xc);   hc = fmaf(h, whh[(64 + o) * 32 + c], hc);
  }
  float rr = 1.f / (1.f + __expf(-(xr + hr)));
  float zz = 1.f / (1.f + __expf(-(xz + hz)));
  float cand = tanhf(xc + rr * hc);
  float sm = (1.f - zz) * cand + zz * ho;

  float y = lane_ln(sm, o, rlg, rlb);
  __syncthreads();
  Us[rl][o] = y;
  __syncthreads();
  float t1 = rb1[o];
#pragma unroll
  for (int c = 0; c < 32; ++c) t1 = fmaf(Us[rl][c], rw1[o * 32 + c], t1);
  t1 = fmaxf(t1, 0.f);
  Hs[rl][o] = t1;
  __syncthreads();
  float res = rb2[o];
#pragma unroll
  for (int c = 0; c < 32; ++c) res = fmaf(Hs[rl][c], rw2[o * 32 + c], res);
  float ns = sm + res;
  slots[(size_t)r * 32 + o] = ns;

  float y2 = lane_ln(ns, o, nsg, nsb);
  __syncthreads();
  Us[rl][o] = y2;
  __syncthreads();
  float qv = qb[o];
#pragma unroll
  for (int c = 0; c < 32; ++c) qv = fmaf(Us[rl][c], qw[o * 32 + c], qv);
  qbuf[(size_t)r * 32 + o] = qv;
}

// ---------------- outputs ----------------------------------------------------

__global__ void k_attn_out(const float* __restrict__ attnt, const float* __restrict__ rsum,
                           float* __restrict__ out) {
  size_t idx = (size_t)blockIdx.x * 256 + threadIdx.x;
  out[O_ATTN + idx] = attnt[idx] / rsum[idx / HWp];
}

__global__ void k_slots_out(const float* __restrict__ slots, float* __restrict__ out) {
  int idx = blockIdx.x * 256 + threadIdx.x;
  if (idx < 9216) out[O_SLOTS + idx] = slots[idx];
}

__global__ __launch_bounds__(256) void k_final(float* __restrict__ out) {
  int b = blockIdx.y;
  int j = blockIdx.x * 256 + threadIdx.x;
  float r[9], ml[9];
#pragma unroll
  for (int s = 0; s < 9; ++s) {
    r[s]  = out[O_RECON + (size_t)(b * 9 + s) * HWp + j];
    ml[s] = out[O_MASK  + (size_t)(b * 9 + s) * HWp + j];
  }
  float mx = ml[0];
#pragma unroll
  for (int s = 1; s < 9; ++s) mx = fmaxf(mx, ml[s]);
  float sum = 0.f;
#pragma unroll
  for (int s = 0; s < 9; ++s) { ml[s] = __expf(ml[s] - mx); sum += ml[s]; }
  float inv = 1.f / sum;
  float comb = 0.f;
#pragma unroll
  for (int s = 0; s < 9; ++s) {
    float mk = ml[s] * inv;
    comb = fmaf(r[s], mk, comb);
    out[O_MASK + (size_t)(b * 9 + s) * HWp + j] = mk;
  }
  out[O_COMB + (size_t)b * HWp + j] = comb;
}

}  // namespace

// ---------------------------------------------------------------------------

extern "C" void kernel_launch(void* const* d_in, const int* in_sizes, int n_in,
                              void* d_out, int out_size, void* d_ws, size_t ws_size,
                              hipStream_t stream) {
  if (ws_size < W_TOTAL * sizeof(float)) return;

  const float* in_x       = (const float*)d_in[0];
  const float* slot_noise = (const float*)d_in[1];
  const float* enc_w1 = (const float*)d_in[2];   const float* enc_b1 = (const float*)d_in[3];
  const float* enc_w2 = (const float*)d_in[4];   const float* enc_b2 = (const float*)d_in[5];
  const float* enc_w3 = (const float*)d_in[6];   const float* enc_b3 = (const float*)d_in[7];
  const float* enc_w4 = (const float*)d_in[8];   const float* enc_b4 = (const float*)d_in[9];
  const float* pe_enc_w = (const float*)d_in[10]; const float* pe_enc_b = (const float*)d_in[11];
  const float* ln_enc_g = (const float*)d_in[12]; const float* ln_enc_b = (const float*)d_in[13];
  const float* mlp_w1 = (const float*)d_in[14];  const float* mlp_b1 = (const float*)d_in[15];
  const float* mlp_w2 = (const float*)d_in[16];  const float* mlp_b2 = (const float*)d_in[17];
  const float* slots_mu = (const float*)d_in[18]; const float* slots_sigma = (const float*)d_in[19];
  const float* ni_g = (const float*)d_in[20];    const float* ni_b = (const float*)d_in[21];
  const float* ns_g = (const float*)d_in[22];    const float* ns_b = (const float*)d_in[23];
  const float* q_w = (const float*)d_in[24];     const float* q_b = (const float*)d_in[25];
  const float* k_w = (const float*)d_in[26];     const float* k_b = (const float*)d_in[27];
  const float* v_w = (const float*)d_in[28];     const float* v_b = (const float*)d_in[29];
  const float* gru_wih = (const float*)d_in[30]; const float* gru_whh = (const float*)d_in[31];
  const float* gru_bih = (const float*)d_in[32]; const float* gru_bhh = (const float*)d_in[33];
  const float* res_ln_g = (const float*)d_in[34]; const float* res_ln_b = (const float*)d_in[35];
  const float* res_w1 = (const float*)d_in[36];  const float* res_b1 = (const float*)d_in[37];
  const float* res_w2 = (const float*)d_in[38];  const float* res_b2 = (const float*)d_in[39];
  const float* pe_dec_w = (const float*)d_in[40]; const float* pe_dec_b = (const float*)d_in[41];
  const float* dec_w1 = (const float*)d_in[42];  const float* dec_b1 = (const float*)d_in[43];
  const float* dec_w2 = (const float*)d_in[44];  const float* dec_b2 = (const float*)d_in[45];
  const float* dec_w3 = (const float*)d_in[46];  const float* dec_b3 = (const float*)d_in[47];
  const float* dec_w4 = (const float*)d_in[48];  const float* dec_b4 = (const float*)d_in[49];

  float* ws  = (float*)d_ws;
  float* out = (float*)d_out;
  ushort* wp = (ushort*)(ws + W_WP);

  k_pe_maps<<<dim3(25), 256, 0, stream>>>(pe_enc_w, pe_enc_b, pe_dec_w, pe_dec_b,
                                          ws + W_PEENC, ws + W_PEDEC);

  const size_t WPSTR = 25 * 2 * 64 * 8;
  k_pack<<<dim3(25), 128, 0, stream>>>(enc_w2, wp + 0 * WPSTR, 0);
  k_pack<<<dim3(25), 128, 0, stream>>>(enc_w3, wp + 1 * WPSTR, 0);
  k_pack<<<dim3(25), 128, 0, stream>>>(enc_w4, wp + 2 * WPSTR, 0);
  k_pack<<<dim3(25), 128, 0, stream>>>(dec_w1, wp + 3 * WPSTR, 1);
  k_pack<<<dim3(25), 128, 0, stream>>>(dec_w2, wp + 4 * WPSTR, 1);
  k_pack<<<dim3(25), 128, 0, stream>>>(dec_w3, wp + 5 * WPSTR, 1);
  k_prep_tc<<<dim3(25), 1024, 0, stream>>>(dec_w1, ws + W_TC);

  ushort* base  = (ushort*)(ws + W_BASE);
  ushort* keys  = (ushort*)(ws + W_KEYS);
  ushort* vals  = (ushort*)(ws + W_VALS);
  float*  attnt = ws + W_POOL;                       // aliases pool (E1/XA dead)
  ushort* E1    = (ushort*)(ws + W_POOL);
  ushort* E2    = (ushort*)(ws + W_POOL + 3276800);

  // base = convT1(pe_dec) + bias (1 img)
  k_conv_mfma<0, false><<<dim3(10, 1), 256, 0, stream>>>(
      ws + W_PEDEC, wp + 3 * WPSTR, dec_b1, base, nullptr, 0);

  // ---------------- encoder ----------------
  k_conv1<<<dim3(25, Bb), 256, 0, stream>>>(in_x, enc_w1, enc_b1, E1);
  k_conv_mfma<1, true><<<dim3(10, Bb), 256, 0, stream>>>(E1, wp + 0 * WPSTR, enc_b2, E2, nullptr, 0);
  k_conv_mfma<1, true><<<dim3(10, Bb), 256, 0, stream>>>(E2, wp + 1 * WPSTR, enc_b3, E1, nullptr, 0);
  k_conv_mfma<1, true><<<dim3(10, Bb), 256, 0, stream>>>(E1, wp + 2 * WPSTR, enc_b4, E2, nullptr, 0);

  k_hstats<<<dim3(25, Bb), 256, 0, stream>>>(E2, ws + W_PEENC, ws + W_LNPART);
  k_statsfin<<<dim3(1), 64, 0, stream>>>(ws + W_LNPART, ws + W_MEANR);
  k_lnmlpkv<<<dim3(25, Bb), 256, 0, stream>>>(E2, ws + W_PEENC, ws + W_MEANR,
                                              ln_enc_g, ln_enc_b,
                                              mlp_w1, mlp_b1, mlp_w2, mlp_b2,
                                              ni_g, ni_b, k_w, k_b, v_w, v_b,
                                              keys, vals);

  // ---------------- slot attention ----------------
  k_init_q<<<dim3(36), 256, 0, stream>>>(slots_mu, slots_sigma, slot_noise,
                                         ns_g, ns_b, q_w, q_b, ws + W_SLOTS, ws + W_Q);
  for (int it = 0; it < 3; ++it) {
    if (it == 2)
      k_dots_upd<true><<<dim3(25, Bb), 256, 0, stream>>>(ws + W_Q, keys, vals, attnt,
                                                         ws + W_APART, ws + W_UP2);
    else
      k_dots_upd<false><<<dim3(25, Bb), 256, 0, stream>>>(ws + W_Q, keys, vals, attnt,
                                                          ws + W_APART, ws + W_UP2);
    k_gru_fused<<<dim3(36), 256, 0, stream>>>(ws + W_UP2, ws + W_APART,
                                              ws + W_SLOTS, ws + W_RSUM, ws + W_Q,
                                              gru_wih, gru_whh, gru_bih, gru_bhh,
                                              res_ln_g, res_ln_b, res_w1, res_b1,
                                              res_w2, res_b2, ns_g, ns_b, q_w, q_b);
  }
  k_attn_out<<<dim3(7200), 256, 0, stream>>>(attnt, ws + W_RSUM, out);
  k_slots_out<<<dim3(36), 256, 0, stream>>>(ws + W_SLOTS, out);

  // Ts for all 288 images
  k_ts<<<dim3(900), 256, 0, stream>>>(ws + W_TC, ws + W_SLOTS, ws + W_TS);

  // ---------------- decoder: 3 chunks of 96 (pool reused; attnt dead) -------
  ushort* XA = (ushort*)(ws + W_POOL);
  ushort* XB = XA + (size_t)96 * 32 * HWp;
  for (int ch = 0; ch < 3; ++ch) {
    int n0 = ch * 96;
    k_conv_mfma<2, true><<<dim3(10, 96), 256, 0, stream>>>(base, wp + 4 * WPSTR, dec_b2, XA,
                                                           ws + W_TS, n0);
    k_conv_mfma<1, true><<<dim3(10, 96), 256, 0, stream>>>(XA, wp + 5 * WPSTR, dec_b3, XB,
                                                           nullptr, 0);
    k_conv4<<<dim3(25, 96), 256, 0, stream>>>(XB, dec_w4, dec_b4,
                                              out + O_RECON, out + O_MASK, n0);
  }

  k_final<<<dim3(25, Bb), 256, 0, stream>>>(out);
}

// Round 7
// 637.006 us; speedup vs baseline: 15.7555x; 1.0940x over previous
//
#include <hip/hip_runtime.h>
#include <cstddef>
#include <cstdint>

// ---------------------------------------------------------------------------
// STSN forward, v7: v6 + MFMA-based lnmlpkv (B-frags loaded directly from
// channel-last global; weights as prepacked A-frags; LDS-bounce relayout).
// B=32, H=W=80, C=32, S=9, ITERS=3
// ---------------------------------------------------------------------------

namespace {

constexpr int Bb  = 32;
constexpr int HWp = 6400;
constexpr float SCALEf = 0.17677669529663687f;  // 32^-0.5

// output section offsets (floats)
constexpr size_t O_COMB  = 0;
constexpr size_t O_RECON = 204800;
constexpr size_t O_MASK  = 2048000;
constexpr size_t O_SLOTS = 3891200;
constexpr size_t O_ATTN  = 3900416;

// workspace layout (float offsets)
constexpr size_t W_PEENC = 0;                 // 204800 [hw][c] fp32
constexpr size_t W_PEDEC = 204800;            // 204800 [c][hw] fp32
constexpr size_t W_BASE  = 409600;            // 102400 (bf16 [hw][c])
constexpr size_t W_TC    = 512000;            // 25600
constexpr size_t W_TS    = 537600;            // 230400
constexpr size_t W_WP    = 768000;            // 76800 (packed conv weights bf16)
constexpr size_t W_WPM   = 844800;            // 2048 (packed 32x32 matrices bf16)
constexpr size_t W_LNPART= 846848;            // 1600
constexpr size_t W_MEANR = 848448;            // 64
constexpr size_t W_Q     = 848512;            // 9216
constexpr size_t W_SLOTS = 857728;            // 9216
constexpr size_t W_APART = 866944;            // 7200
constexpr size_t W_RSUM  = 874144;            // 288
constexpr size_t W_UP2   = 874432;            // 230400
constexpr size_t W_KEYS  = 1104832;           // 3276800 (bf16 [b][hw][c])
constexpr size_t W_VALS  = 4381632;           // 3276800 (bf16)
constexpr size_t W_POOL  = 7658432;           // 21456896 floats available
constexpr size_t W_TOTAL = 29115328;          // 116.5 MB
// Pool aliasing: E1/E2 (encoder) | attnt (attention) | XA/XB (decoder)

typedef __attribute__((ext_vector_type(8))) short short8;
typedef __attribute__((ext_vector_type(4))) float f32x4;

__device__ __forceinline__ ushort f2bf(float f) {
  uint u = __builtin_bit_cast(uint, f);
  uint r = (u + 0x7fffu + ((u >> 16) & 1u)) >> 16;   // RNE
  return (ushort)r;
}
__device__ __forceinline__ float bf2f(ushort b) {
  uint u = ((uint)b) << 16;
  return __builtin_bit_cast(float, u);
}
__device__ __forceinline__ void unpk2(uint w, float& a, float& b) {
  a = __builtin_bit_cast(float, w << 16);
  b = __builtin_bit_cast(float, w & 0xffff0000u);
}

__device__ __forceinline__ void matvec32(const float* __restrict__ W,
                                         const float* __restrict__ bias,
                                         const float* x, float* y, bool relu) {
#pragma unroll
  for (int o = 0; o < 32; ++o) {
    float a = bias[o];
#pragma unroll
    for (int c = 0; c < 32; ++c) a = fmaf(x[c], W[o * 32 + c], a);
    y[o] = relu ? fmaxf(a, 0.f) : a;
  }
}

__device__ __forceinline__ float lane_ln(float v, int o, const float* __restrict__ g,
                                         const float* __restrict__ b) {
  float s = v;
#pragma unroll
  for (int m = 16; m >= 1; m >>= 1) s += __shfl_xor(s, m);
  float mean = s * (1.f / 32.f);
  float d = v - mean;
  float q = d * d;
#pragma unroll
  for (int m = 16; m >= 1; m >>= 1) q += __shfl_xor(q, m);
  float rstd = rsqrtf(q * (1.f / 32.f) + 1e-5f);
  return d * rstd * g[o] + b[o];
}

// ---------------- positional-embedding maps ---------------------------------

__global__ void k_pe_maps(const float* __restrict__ pew_e, const float* __restrict__ peb_e,
                          const float* __restrict__ pew_d, const float* __restrict__ peb_d,
                          float* __restrict__ pe_enc, float* __restrict__ pe_dec) {
  int hw = blockIdx.x * 256 + threadIdx.x;
  if (hw >= HWp) return;
  int y = hw / 80, x = hw % 80;
  float g0 = y * (1.f / 79.f), g1 = x * (1.f / 79.f);
  float g2 = 1.f - g0, g3 = 1.f - g1;
#pragma unroll
  for (int c = 0; c < 32; ++c) {
    pe_enc[(size_t)hw * 32 + c] = peb_e[c] + g0 * pew_e[c * 4] + g1 * pew_e[c * 4 + 1] +
                                  g2 * pew_e[c * 4 + 2] + g3 * pew_e[c * 4 + 3];
    pe_dec[(size_t)c * HWp + hw] = peb_d[c] + g0 * pew_d[c * 4] + g1 * pew_d[c * 4 + 1] +
                                   g2 * pew_d[c * 4 + 2] + g3 * pew_d[c * 4 + 3];
  }
}

// ---------------- weight packing -------------------------------------------

__global__ void k_pack(const float* __restrict__ w, ushort* __restrict__ dst, int trans) {
  int tap = blockIdx.x;
  int grp = threadIdx.x >> 6, lane = threadIdx.x & 63;
  int ky = tap / 5, kx = tap % 5;
  int m = grp * 16 + (lane & 15);
  int kb = (lane >> 4) * 8;
  ushort* o = dst + ((size_t)(tap * 2 + grp) * 64 + lane) * 8;
#pragma unroll
  for (int j = 0; j < 8; ++j) {
    int k = kb + j;
    float v = trans ? w[(size_t)k * 800 + m * 25 + (4 - ky) * 5 + (4 - kx)]
                    : w[(size_t)m * 800 + k * 25 + ky * 5 + kx];
    o[j] = f2bf(v);
  }
}

// pack a row-major [32][32] matrix (y = x @ W^T form, A[m=o][k=c]) into A-frags
__global__ void k_pack_mat(const float* __restrict__ w, ushort* __restrict__ dst) {
  int grp = threadIdx.x >> 6, lane = threadIdx.x & 63;   // 128 threads
  int m = grp * 16 + (lane & 15), kb = (lane >> 4) * 8;
  ushort* o = dst + ((size_t)(grp * 64 + lane)) * 8;
#pragma unroll
  for (int j = 0; j < 8; ++j) o[j] = f2bf(w[m * 32 + kb + j]);
}

// ---------------- Tc / Ts for algebraic decoder conv1 ------------------------

__global__ void k_prep_tc(const float* __restrict__ w, float* __restrict__ tc) {
  const int rep[5] = {0, 1, 40, 78, 79};
  int cls = blockIdx.x;
  int yc = cls / 5, xc = cls % 5;
  int ci = threadIdx.x >> 5, co = threadIdx.x & 31;
  int yr = rep[yc], xr = rep[xc];
  float s = 0.f;
#pragma unroll
  for (int ky = 0; ky < 5; ++ky) {
    if ((unsigned)(yr + ky - 2) >= 80u) continue;
#pragma unroll
    for (int kx = 0; kx < 5; ++kx) {
      if ((unsigned)(xr + kx - 2) >= 80u) continue;
      s += w[(size_t)ci * 800 + co * 25 + (4 - ky) * 5 + (4 - kx)];
    }
  }
  tc[(size_t)cls * 1024 + ci * 32 + co] = s;
}

__global__ void k_ts(const float* __restrict__ tc, const float* __restrict__ slots,
                     float* __restrict__ ts) {
  int idx = blockIdx.x * 256 + threadIdx.x;
  if (idx >= 288 * 800) return;
  int img = idx / 800, rem = idx % 800;
  int cls = rem >> 5, o = rem & 31;
  float s = 0.f;
#pragma unroll
  for (int ci = 0; ci < 32; ++ci)
    s += tc[(size_t)cls * 1024 + ci * 32 + o] * slots[(size_t)img * 32 + ci];
  ts[idx] = s;
}

// ---------------- MFMA conv (32->32, 5x5, pad 2) -----------------------------

template <int MODE, bool RELU>
__global__ __launch_bounds__(256, 2) void k_conv_mfma(
    const void* __restrict__ in_, const ushort* __restrict__ wp,
    const float* __restrict__ bias, ushort* __restrict__ out_,
    const float* __restrict__ ts, int n0) {
  __shared__ int4 sm[4032];
  const int n = blockIdx.y, rt = blockIdx.x;
  const int t = threadIdx.x;

  for (int i = t; i < 4032; i += 256) {
    int x = i % 84, ru = i / 84;
    int r = ru >> 2, u = ru & 3;
    int gy = rt * 8 + r - 2, gx = x - 2;
    int4 pk = {0, 0, 0, 0};
    if ((unsigned)gy < 80u && (unsigned)gx < 80u) {
      int hw = gy * 80 + gx;
      if constexpr (MODE == 0) {
        const float* fp = (const float*)in_;
        ushort bb[8];
#pragma unroll
        for (int j = 0; j < 8; ++j)
          bb[j] = f2bf(fp[(size_t)(u * 8 + j) * HWp + hw]);
        pk.x = (int)((uint)bb[0] | ((uint)bb[1] << 16));
        pk.y = (int)((uint)bb[2] | ((uint)bb[3] << 16));
        pk.z = (int)((uint)bb[4] | ((uint)bb[5] << 16));
        pk.w = (int)((uint)bb[6] | ((uint)bb[7] << 16));
      } else if constexpr (MODE == 1) {
        pk = *(const int4*)((const ushort*)in_ + ((size_t)n * HWp + hw) * 32 + u * 8);
      } else {
        int4 bp = *(const int4*)((const ushort*)in_ + (size_t)hw * 32 + u * 8);
        int yc = gy < 2 ? gy : (gy > 77 ? gy - 75 : 2);
        int xc = gx < 2 ? gx : (gx > 77 ? gx - 75 : 2);
        const float* tp = ts + ((size_t)(n0 + n) * 25 + (yc * 5 + xc)) * 32 + u * 8;
        float t0, t1;
        uint* pw = (uint*)&pk;
        const uint* bw = (const uint*)&bp;
#pragma unroll
        for (int h = 0; h < 4; ++h) {
          unpk2(bw[h], t0, t1);
          float f0 = fmaxf(t0 + tp[2 * h], 0.f);
          float f1 = fmaxf(t1 + tp[2 * h + 1], 0.f);
          pw[h] = (uint)f2bf(f0) | ((uint)f2bf(f1) << 16);
        }
      }
    }
    int up = u ^ ((x >> 1) & 3);
    sm[(r * 84 + x) * 4 + up] = pk;
  }
  __syncthreads();

  const int wv = t >> 6, lane = t & 63;
  const int l15 = lane & 15, lg = lane >> 4;
  const short8* smS = (const short8*)sm;

  f32x4 acc[2][5][2];
#pragma unroll
  for (int a = 0; a < 2; ++a)
#pragma unroll
    for (int b = 0; b < 5; ++b)
#pragma unroll
      for (int c = 0; c < 2; ++c) acc[a][b][c] = f32x4{0.f, 0.f, 0.f, 0.f};

  for (int dy = 0; dy < 5; ++dy) {
    for (int dx = 0; dx < 5; ++dx) {
      int tap = dy * 5 + dx;
      short8 A0 = *(const short8*)(wp + ((size_t)(tap * 2 + 0) * 64 + lane) * 8);
      short8 A1 = *(const short8*)(wp + ((size_t)(tap * 2 + 1) * 64 + lane) * 8);
#pragma unroll
      for (int ri = 0; ri < 2; ++ri) {
        int rbase = (wv * 2 + ri + dy) * 336;
#pragma unroll
        for (int xg = 0; xg < 5; ++xg) {
          int xs = xg * 16 + l15 + dx;
          short8 Bv = smS[rbase + xs * 4 + (lg ^ ((xs >> 1) & 3))];
          acc[ri][xg][0] = __builtin_amdgcn_mfma_f32_16x16x32_bf16(A0, Bv, acc[ri][xg][0], 0, 0, 0);
          acc[ri][xg][1] = __builtin_amdgcn_mfma_f32_16x16x32_bf16(A1, Bv, acc[ri][xg][1], 0, 0, 0);
        }
      }
    }
  }

  float bv[2][4];
#pragma unroll
  for (int cg = 0; cg < 2; ++cg)
#pragma unroll
    for (int q = 0; q < 4; ++q) bv[cg][q] = bias[cg * 16 + lg * 4 + q];
  int y0 = rt * 8 + wv * 2;
#pragma unroll
  for (int ri = 0; ri < 2; ++ri) {
#pragma unroll
    for (int xg = 0; xg < 5; ++xg) {
      size_t px = (size_t)n * HWp + (y0 + ri) * 80 + (xg * 16 + l15);
#pragma unroll
      for (int cg = 0; cg < 2; ++cg) {
        f32x4 v = acc[ri][xg][cg];
        float o0 = v[0] + bv[cg][0], o1 = v[1] + bv[cg][1];
        float o2 = v[2] + bv[cg][2], o3 = v[3] + bv[cg][3];
        if (RELU) {
          o0 = fmaxf(o0, 0.f); o1 = fmaxf(o1, 0.f);
          o2 = fmaxf(o2, 0.f); o3 = fmaxf(o3, 0.f);
        }
        uint2 pk;
        pk.x = (uint)f2bf(o0) | ((uint)f2bf(o1) << 16);
        pk.y = (uint)f2bf(o2) | ((uint)f2bf(o3) << 16);
        *(uint2*)(out_ + px * 32 + cg * 16 + lg * 4) = pk;
      }
    }
  }
}

// ---------------- encoder conv1 ----------------------------------------------

__global__ __launch_bounds__(256) void k_conv1(const float* __restrict__ in,
                                               const float* __restrict__ w,
                                               const float* __restrict__ b,
                                               ushort* __restrict__ out) {
  int hw = blockIdx.x * 256 + threadIdx.x;
  int n = blockIdx.y;
  int y = hw / 80, x = hw % 80;
  float xv[25];
#pragma unroll
  for (int ky = 0; ky < 5; ++ky)
#pragma unroll
    for (int kx = 0; kx < 5; ++kx) {
      int iy = y + ky - 2, ix = x + kx - 2;
      xv[ky * 5 + kx] = ((unsigned)iy < 80u && (unsigned)ix < 80u)
                            ? in[(size_t)n * HWp + iy * 80 + ix] : 0.f;
    }
  float a[32];
#pragma unroll
  for (int co = 0; co < 32; ++co) {
    float s = b[co];
#pragma unroll
    for (int tp = 0; tp < 25; ++tp) s = fmaf(xv[tp], w[co * 25 + tp], s);
    a[co] = fmaxf(s, 0.f);
  }
  ushort* op = out + ((size_t)n * HWp + hw) * 32;
#pragma unroll
  for (int g = 0; g < 4; ++g) {
    uint4 pk;
    pk.x = (uint)f2bf(a[g * 8 + 0]) | ((uint)f2bf(a[g * 8 + 1]) << 16);
    pk.y = (uint)f2bf(a[g * 8 + 2]) | ((uint)f2bf(a[g * 8 + 3]) << 16);
    pk.z = (uint)f2bf(a[g * 8 + 4]) | ((uint)f2bf(a[g * 8 + 5]) << 16);
    pk.w = (uint)f2bf(a[g * 8 + 6]) | ((uint)f2bf(a[g * 8 + 7]) << 16);
    *(uint4*)(op + g * 8) = pk;
  }
}

// ---------------- decoder conv4 (32->2, 3x3, trans) --------------------------

__global__ __launch_bounds__(256) void k_conv4(const ushort* __restrict__ in,
                                               const float* __restrict__ w,
                                               const float* __restrict__ b,
                                               float* __restrict__ outR,
                                               float* __restrict__ outM, int n0) {
  __shared__ float sw[2 * 288];
  for (int e = threadIdx.x; e < 576; e += 256) {
    int co = e / 288, rem = e % 288;
    int tap = rem / 32, ci = rem % 32;
    sw[e] = w[(size_t)(ci * 2 + co) * 9 + 8 - tap];
  }
  __syncthreads();
  int hw = blockIdx.x * 256 + threadIdx.x;
  int nl = blockIdx.y;
  int y = hw / 80, x = hw % 80;
  float a0 = b[0], a1 = b[1];
  const ushort* ip = in + (size_t)nl * HWp * 32;
#pragma unroll
  for (int ky = 0; ky < 3; ++ky) {
#pragma unroll
    for (int kx = 0; kx < 3; ++kx) {
      int iy = y + ky - 1, ix = x + kx - 1;
      if ((unsigned)iy >= 80u || (unsigned)ix >= 80u) continue;
      int tap = ky * 3 + kx;
      const int4* p = (const int4*)(ip + (size_t)(iy * 80 + ix) * 32);
      const float* w0 = sw + tap * 32;
      const float* w1 = sw + 288 + tap * 32;
#pragma unroll
      for (int u = 0; u < 4; ++u) {
        int4 ch = p[u];
        const uint* cw = (const uint*)&ch;
#pragma unroll
        for (int h = 0; h < 4; ++h) {
          float v0, v1;
          unpk2(cw[h], v0, v1);
          int ci = u * 8 + h * 2;
          a0 = fmaf(v0, w0[ci], a0);     a1 = fmaf(v0, w1[ci], a1);
          a0 = fmaf(v1, w0[ci + 1], a0); a1 = fmaf(v1, w1[ci + 1], a1);
        }
      }
    }
  }
  outR[(size_t)(n0 + nl) * HWp + hw] = a0;
  outM[(size_t)(n0 + nl) * HWp + hw] = a1;
}

// ---------------- big-LN stats from E2+PE ------------------------------------

__global__ __launch_bounds__(256) void k_hstats(const ushort* __restrict__ enc,
                                                const float* __restrict__ pe_enc,
                                                float* __restrict__ lnpart) {
  int b = blockIdx.y;
  int hw = blockIdx.x * 256 + threadIdx.x;
  const int4* ep = (const int4*)(enc + ((size_t)b * HWp + hw) * 32);
  float v[32];
#pragma unroll
  for (int u = 0; u < 4; ++u) {
    int4 ch = ep[u];
    const uint* cw = (const uint*)&ch;
#pragma unroll
    for (int h = 0; h < 4; ++h) unpk2(cw[h], v[u * 8 + h * 2], v[u * 8 + h * 2 + 1]);
  }
  float s = 0.f, ss = 0.f;
#pragma unroll
  for (int c = 0; c < 32; ++c) {
    v[c] += pe_enc[(size_t)hw * 32 + c];
    s += v[c]; ss += v[c] * v[c];
  }
  __shared__ float r1[256], r2[256];
  r1[threadIdx.x] = s; r2[threadIdx.x] = ss;
  __syncthreads();
  for (int off = 128; off > 0; off >>= 1) {
    if (threadIdx.x < off) { r1[threadIdx.x] += r1[threadIdx.x + off]; r2[threadIdx.x] += r2[threadIdx.x + off]; }
    __syncthreads();
  }
  if (threadIdx.x == 0) {
    lnpart[(size_t)(b * 25 + blockIdx.x) * 2] = r1[0];
    lnpart[(size_t)(b * 25 + blockIdx.x) * 2 + 1] = r2[0];
  }
}

__global__ void k_statsfin(const float* __restrict__ lnpart, float* __restrict__ meanr) {
  int b = threadIdx.x;
  if (b >= 32) return;
  float s = 0.f, ss = 0.f;
  for (int k = 0; k < 25; ++k) {
    s += lnpart[(size_t)(b * 25 + k) * 2];
    ss += lnpart[(size_t)(b * 25 + k) * 2 + 1];
  }
  float m = s * (1.f / 204800.f);
  float var = ss * (1.f / 204800.f) - m * m;
  meanr[b * 2] = m;
  meanr[b * 2 + 1] = rsqrtf(var + 1e-5f);
}

// ---------------- MFMA lnmlpkv ----------------------------------------------
// Per block: 256 positions of one batch image. 4 waves, each owns 64 positions
// (4 groups of 16). B-frags come straight from channel-last global memory;
// C->B relayout bounces through a wave-private swizzled LDS region.
// wm: 4 packed matrices (w1,w2,kw,vw), each [grp][lane][8] A-frags.

__global__ __launch_bounds__(256) void k_lnmlpkv_mfma(
    const ushort* __restrict__ enc, const float* __restrict__ pe,
    const float* __restrict__ meanr,
    const float* __restrict__ g, const float* __restrict__ bb,
    const ushort* __restrict__ wm,
    const float* __restrict__ b1, const float* __restrict__ b2,
    const float* __restrict__ nig, const float* __restrict__ nib,
    const float* __restrict__ kb, const float* __restrict__ vb,
    ushort* __restrict__ keys, ushort* __restrict__ vals) {
  __shared__ ushort ls[256 * 32];   // 16 KB bounce buffer
  const int b = blockIdx.y, jb = blockIdx.x;
  const int t = threadIdx.x, wv = t >> 6, lane = t & 63;
  const int l15 = lane & 15, lg = lane >> 4;
  const int skey = l15 & 3;

  // A-fragments for the 4 matrices (loaded once, 32 VGPRs)
  short8 A[4][2];
#pragma unroll
  for (int mt = 0; mt < 4; ++mt)
#pragma unroll
    for (int gr = 0; gr < 2; ++gr)
      A[mt][gr] = *(const short8*)(wm + ((size_t)(mt * 2 + gr) * 64 + lane) * 8);

  // per-lane bias/LN vectors (channels cg*16 + lg*4 + q)
  float4 b1v0 = *(const float4*)(b1 + lg * 4),  b1v1 = *(const float4*)(b1 + 16 + lg * 4);
  float4 b2v0 = *(const float4*)(b2 + lg * 4),  b2v1 = *(const float4*)(b2 + 16 + lg * 4);
  float4 ng0  = *(const float4*)(nig + lg * 4), ng1  = *(const float4*)(nig + 16 + lg * 4);
  float4 nb0  = *(const float4*)(nib + lg * 4), nb1  = *(const float4*)(nib + 16 + lg * 4);
  float4 kbv0 = *(const float4*)(kb + lg * 4),  kbv1 = *(const float4*)(kb + 16 + lg * 4);
  float4 vbv0 = *(const float4*)(vb + lg * 4),  vbv1 = *(const float4*)(vb + 16 + lg * 4);

  const float m_ = meanr[b * 2], rs_ = meanr[b * 2 + 1];

  // ---- stage 1: x = bigLN(enc + pe) -> B-frags (direct from global) ----
  short8 bx[4];
#pragma unroll
  for (int g2 = 0; g2 < 4; ++g2) {
    int pos = jb * 256 + wv * 64 + g2 * 16 + l15;
    int4 e = *(const int4*)(enc + ((size_t)b * HWp + pos) * 32 + lg * 8);
    float xv[8];
    const uint* ew = (const uint*)&e;
#pragma unroll
    for (int h = 0; h < 4; ++h) unpk2(ew[h], xv[2 * h], xv[2 * h + 1]);
    float4 p0 = *(const float4*)(pe + (size_t)pos * 32 + lg * 8);
    float4 p1 = *(const float4*)(pe + (size_t)pos * 32 + lg * 8 + 4);
    float4 g0 = *(const float4*)(g + (size_t)pos * 32 + lg * 8);
    float4 g1 = *(const float4*)(g + (size_t)pos * 32 + lg * 8 + 4);
    float4 q0 = *(const float4*)(bb + (size_t)pos * 32 + lg * 8);
    float4 q1 = *(const float4*)(bb + (size_t)pos * 32 + lg * 8 + 4);
    float pv[8] = {p0.x, p0.y, p0.z, p0.w, p1.x, p1.y, p1.z, p1.w};
    float gv[8] = {g0.x, g0.y, g0.z, g0.w, g1.x, g1.y, g1.z, g1.w};
    float qv[8] = {q0.x, q0.y, q0.z, q0.w, q1.x, q1.y, q1.z, q1.w};
    uint pk[4];
#pragma unroll
    for (int h = 0; h < 4; ++h) {
      float f0 = (xv[2 * h] + pv[2 * h] - m_) * rs_ * gv[2 * h] + qv[2 * h];
      float f1 = (xv[2 * h + 1] + pv[2 * h + 1] - m_) * rs_ * gv[2 * h + 1] + qv[2 * h + 1];
      pk[h] = (uint)f2bf(f0) | ((uint)f2bf(f1) << 16);
    }
    bx[g2] = __builtin_bit_cast(short8, *(int4*)pk);
  }

  // helper lambdas for the LDS bounce
  auto lds_write = [&](int posl, int cg, const f32x4& v) {
    int u = cg * 2 + (lg >> 1);
    int us = u ^ skey;
    uint2 pk;
    pk.x = (uint)f2bf(v[0]) | ((uint)f2bf(v[1]) << 16);
    pk.y = (uint)f2bf(v[2]) | ((uint)f2bf(v[3]) << 16);
    *(uint2*)(ls + (size_t)posl * 32 + us * 8 + (lg & 1) * 4) = pk;
  };

  // ---- stage 2: t0 = relu(x @ w1^T + b1) -> LDS ----
#pragma unroll
  for (int g2 = 0; g2 < 4; ++g2) {
    int posl = wv * 64 + g2 * 16 + l15;
    f32x4 a0 = __builtin_amdgcn_mfma_f32_16x16x32_bf16(A[0][0], bx[g2], f32x4{0, 0, 0, 0}, 0, 0, 0);
    f32x4 a1 = __builtin_amdgcn_mfma_f32_16x16x32_bf16(A[0][1], bx[g2], f32x4{0, 0, 0, 0}, 0, 0, 0);
    f32x4 r0, r1;
#pragma unroll
    for (int q = 0; q < 4; ++q) {
      r0[q] = fmaxf(a0[q] + (&b1v0.x)[q], 0.f);
      r1[q] = fmaxf(a1[q] + (&b1v1.x)[q], 0.f);
    }
    lds_write(posl, 0, r0);
    lds_write(posl, 1, r1);
  }
  __syncthreads();
  short8 t0f[4];
#pragma unroll
  for (int g2 = 0; g2 < 4; ++g2) {
    int posl = wv * 64 + g2 * 16 + l15;
    t0f[g2] = *(const short8*)(ls + (size_t)posl * 32 + (lg ^ skey) * 8);
  }
  __syncthreads();

  // ---- stage 3: t1 = t0 @ w2^T + b2 ; xn = LN(t1) -> LDS ----
#pragma unroll
  for (int g2 = 0; g2 < 4; ++g2) {
    int posl = wv * 64 + g2 * 16 + l15;
    f32x4 c0 = __builtin_amdgcn_mfma_f32_16x16x32_bf16(A[1][0], t0f[g2], f32x4{0, 0, 0, 0}, 0, 0, 0);
    f32x4 c1 = __builtin_amdgcn_mfma_f32_16x16x32_bf16(A[1][1], t0f[g2], f32x4{0, 0, 0, 0}, 0, 0, 0);
#pragma unroll
    for (int q = 0; q < 4; ++q) { c0[q] += (&b2v0.x)[q]; c1[q] += (&b2v1.x)[q]; }
    float s = 0.f;
#pragma unroll
    for (int q = 0; q < 4; ++q) s += c0[q] + c1[q];
    s += __shfl_xor(s, 16); s += __shfl_xor(s, 32);
    float mean = s * (1.f / 32.f);
    float var = 0.f;
#pragma unroll
    for (int q = 0; q < 4; ++q) {
      float d0 = c0[q] - mean, d1 = c1[q] - mean;
      var += d0 * d0 + d1 * d1;
    }
    var += __shfl_xor(var, 16); var += __shfl_xor(var, 32);
    float rstd = rsqrtf(var * (1.f / 32.f) + 1e-5f);
    f32x4 y0, y1;
#pragma unroll
    for (int q = 0; q < 4; ++q) {
      y0[q] = (c0[q] - mean) * rstd * (&ng0.x)[q] + (&nb0.x)[q];
      y1[q] = (c1[q] - mean) * rstd * (&ng1.x)[q] + (&nb1.x)[q];
    }
    lds_write(posl, 0, y0);
    lds_write(posl, 1, y1);
  }
  __syncthreads();
  short8 xnf[4];
#pragma unroll
  for (int g2 = 0; g2 < 4; ++g2) {
    int posl = wv * 64 + g2 * 16 + l15;
    xnf[g2] = *(const short8*)(ls + (size_t)posl * 32 + (lg ^ skey) * 8);
  }

  // ---- stage 4: keys = xn @ kw^T + kb ; vals = xn @ vw^T + vb ----
#pragma unroll
  for (int g2 = 0; g2 < 4; ++g2) {
    int pos = jb * 256 + wv * 64 + g2 * 16 + l15;
    size_t px = ((size_t)b * HWp + pos) * 32;
    f32x4 k0 = __builtin_amdgcn_mfma_f32_16x16x32_bf16(A[2][0], xnf[g2], f32x4{0, 0, 0, 0}, 0, 0, 0);
    f32x4 k1 = __builtin_amdgcn_mfma_f32_16x16x32_bf16(A[2][1], xnf[g2], f32x4{0, 0, 0, 0}, 0, 0, 0);
    f32x4 v0 = __builtin_amdgcn_mfma_f32_16x16x32_bf16(A[3][0], xnf[g2], f32x4{0, 0, 0, 0}, 0, 0, 0);
    f32x4 v1 = __builtin_amdgcn_mfma_f32_16x16x32_bf16(A[3][1], xnf[g2], f32x4{0, 0, 0, 0}, 0, 0, 0);
    uint2 pk;
    pk.x = (uint)f2bf(k0[0] + kbv0.x) | ((uint)f2bf(k0[1] + kbv0.y) << 16);
    pk.y = (uint)f2bf(k0[2] + kbv0.z) | ((uint)f2bf(k0[3] + kbv0.w) << 16);
    *(uint2*)(keys + px + lg * 4) = pk;
    pk.x = (uint)f2bf(k1[0] + kbv1.x) | ((uint)f2bf(k1[1] + kbv1.y) << 16);
    pk.y = (uint)f2bf(k1[2] + kbv1.z) | ((uint)f2bf(k1[3] + kbv1.w) << 16);
    *(uint2*)(keys + px + 16 + lg * 4) = pk;
    pk.x = (uint)f2bf(v0[0] + vbv0.x) | ((uint)f2bf(v0[1] + vbv0.y) << 16);
    pk.y = (uint)f2bf(v0[2] + vbv0.z) | ((uint)f2bf(v0[3] + vbv0.w) << 16);
    *(uint2*)(vals + px + lg * 4) = pk;
    pk.x = (uint)f2bf(v1[0] + vbv1.x) | ((uint)f2bf(v1[1] + vbv1.y) << 16);
    pk.y = (uint)f2bf(v1[2] + vbv1.z) | ((uint)f2bf(v1[3] + vbv1.w) << 16);
    *(uint2*)(vals + px + 16 + lg * 4) = pk;
  }
}

// ---------------- slot attention -------------------------------------------

__global__ __launch_bounds__(256) void k_init_q(
    const float* __restrict__ mu, const float* __restrict__ sig,
    const float* __restrict__ noise,
    const float* __restrict__ nsg, const float* __restrict__ nsb,
    const float* __restrict__ qw, const float* __restrict__ qb,
    float* __restrict__ slots, float* __restrict__ qbuf) {
  int rl = threadIdx.x >> 5, o = threadIdx.x & 31;
  int r = blockIdx.x * 8 + rl;
  float s = mu[o] + sig[o] * noise[(size_t)r * 32 + o];
  slots[(size_t)r * 32 + o] = s;
  float y = lane_ln(s, o, nsg, nsb);
  __shared__ float S[8][32];
  S[rl][o] = y;
  __syncthreads();
  float qv = qb[o];
#pragma unroll
  for (int c = 0; c < 32; ++c) qv = fmaf(S[rl][c], qw[o * 32 + c], qv);
  qbuf[(size_t)r * 32 + o] = qv;
}

template <bool LAST>
__global__ __launch_bounds__(256) void k_dots_upd(
    const float* __restrict__ qbuf, const ushort* __restrict__ keys,
    const ushort* __restrict__ vals, float* __restrict__ attnt,
    float* __restrict__ apart, float* __restrict__ up2) {
  int b = blockIdx.y, jb = blockIdx.x;
  int t = threadIdx.x;
  int j = jb * 256 + t;
  __shared__ float qs[288];
  __shared__ float aL[2304];
  __shared__ float wr[36];
  for (int e = t; e < 288; e += 256) qs[e] = qbuf[(size_t)b * 288 + e];
  __syncthreads();
  float k[32];
  const int4* kp = (const int4*)(keys + ((size_t)b * HWp + j) * 32);
#pragma unroll
  for (int u = 0; u < 4; ++u) {
    int4 ch = kp[u];
    const uint* cw = (const uint*)&ch;
#pragma unroll
    for (int h = 0; h < 4; ++h) unpk2(cw[h], k[u * 8 + h * 2], k[u * 8 + h * 2 + 1]);
  }
  float d[9];
#pragma unroll
  for (int i = 0; i < 9; ++i) {
    float a = 0.f;
#pragma unroll
    for (int c = 0; c < 32; ++c) a = fmaf(qs[i * 32 + c], k[c], a);
    d[i] = a * SCALEf;
  }
  float mx = d[0];
#pragma unroll
  for (int i = 1; i < 9; ++i) mx = fmaxf(mx, d[i]);
  float sum = 0.f;
#pragma unroll
  for (int i = 0; i < 9; ++i) { d[i] = __expf(d[i] - mx); sum += d[i]; }
  float inv = 1.f / sum;
  float a9[9];
#pragma unroll
  for (int i = 0; i < 9; ++i) {
    a9[i] = d[i] * inv + 1e-8f;
    if (LAST) attnt[((size_t)b * 9 + i) * HWp + j] = a9[i];
    aL[t * 9 + i] = a9[i];
  }
  int lane = t & 63, wid = t >> 6;
#pragma unroll
  for (int i = 0; i < 9; ++i) {
    float v = a9[i];
    for (int off = 32; off > 0; off >>= 1) v += __shfl_down(v, off);
    if (lane == 0) wr[wid * 9 + i] = v;
  }
  __syncthreads();
  if (t < 9)
    apart[(size_t)(b * 9 + t) * 25 + jb] = wr[t] + wr[9 + t] + wr[18 + t] + wr[27 + t];
  int c = t & 31, g = t >> 5;
  float acc[9];
#pragma unroll
  for (int i = 0; i < 9; ++i) acc[i] = 0.f;
  const ushort* vp = vals + ((size_t)b * HWp + jb * 256) * 32 + c;
  for (int jj = g; jj < 256; jj += 8) {
    float v = bf2f(vp[(size_t)jj * 32]);
#pragma unroll
    for (int i = 0; i < 9; ++i) acc[i] = fmaf(v, aL[jj * 9 + i], acc[i]);
  }
  __syncthreads();
#pragma unroll
  for (int i = 0; i < 9; ++i) aL[(i * 8 + g) * 32 + c] = acc[i];
  __syncthreads();
  for (int i = g; i < 9; i += 8) {
    float s = 0.f;
#pragma unroll
    for (int g2 = 0; g2 < 8; ++g2) s += aL[(i * 8 + g2) * 32 + c];
    up2[(((size_t)b * 25 + jb) * 9 + i) * 32 + c] = s;
  }
}

__global__ __launch_bounds__(256) void k_gru_fused(
    const float* __restrict__ up2, const float* __restrict__ apart,
    float* __restrict__ slots, float* __restrict__ rowsum, float* __restrict__ qbuf,
    const float* __restrict__ wih, const float* __restrict__ whh,
    const float* __restrict__ bih, const float* __restrict__ bhh,
    const float* __restrict__ rlg, const float* __restrict__ rlb,
    const float* __restrict__ rw1, const float* __restrict__ rb1,
    const float* __restrict__ rw2, const float* __restrict__ rb2,
    const float* __restrict__ nsg, const float* __restrict__ nsb,
    const float* __restrict__ qw, const float* __restrict__ qb) {
  int rl = threadIdx.x >> 5, o = threadIdx.x & 31;
  int r = blockIdx.x * 8 + rl;
  int b = r / 9, i = r - b * 9;

  float rs = 0.f;
#pragma unroll
  for (int k = 0; k < 25; ++k) rs += apart[(size_t)(b * 9 + i) * 25 + k];
  if (o == 0) rowsum[r] = rs;

  float uo = 0.f;
#pragma unroll
  for (int jc = 0; jc < 25; ++jc) uo += up2[(((size_t)b * 25 + jc) * 9 + i) * 32 + o];
  uo /= rs;
  float ho = slots[(size_t)r * 32 + o];

  __shared__ float Us[8][32], Hs[8][32];
  Us[rl][o] = uo; Hs[rl][o] = ho;
  __syncthreads();

  float xr = bih[o], xz = bih[32 + o], xc = bih[64 + o];
  float hr = bhh[o], hz = bhh[32 + o], hc = bhh[64 + o];
#pragma unroll
  for (int c = 0; c < 32; ++c) {
    float u = Us[rl][c], h = Hs[rl][c];
    xr = fmaf(u, wih[o * 32 + c], xr);          hr = fmaf(h, whh[o * 32 + c], hr);
    xz = fmaf(u, wih[(32 + o) * 32 + c], xz);   hz = fmaf(h, whh[(32 + o) * 32 + c], hz);
    xc = fmaf(u, wih[(64 + o) * 32 + c], xc);   hc = fmaf(h, whh[(64 + o) * 32 + c], hc);
  }
  float rr = 1.f / (1.f + __expf(-(xr + hr)));
  float zz = 1.f / (1.f + __expf(-(xz + hz)));
  float cand = tanhf(xc + rr * hc);
  float sm = (1.f - zz) * cand + zz * ho;

  float y = lane_ln(sm, o, rlg, rlb);
  __syncthreads();
  Us[rl][o] = y;
  __syncthreads();
  float t1 = rb1[o];
#pragma unroll
  for (int c = 0; c < 32; ++c) t1 = fmaf(Us[rl][c], rw1[o * 32 + c], t1);
  t1 = fmaxf(t1, 0.f);
  Hs[rl][o] = t1;
  __syncthreads();
  float res = rb2[o];
#pragma unroll
  for (int c = 0; c < 32; ++c) res = fmaf(Hs[rl][c], rw2[o * 32 + c], res);
  float ns = sm + res;
  slots[(size_t)r * 32 + o] = ns;

  float y2 = lane_ln(ns, o, nsg, nsb);
  __syncthreads();
  Us[rl][o] = y2;
  __syncthreads();
  float qv = qb[o];
#pragma unroll
  for (int c = 0; c < 32; ++c) qv = fmaf(Us[rl][c], qw[o * 32 + c], qv);
  qbuf[(size_t)r * 32 + o] = qv;
}

// ---------------- outputs ----------------------------------------------------

__global__ void k_attn_out(const float* __restrict__ attnt, const float* __restrict__ rsum,
                           float* __restrict__ out) {
  size_t idx = (size_t)blockIdx.x * 256 + threadIdx.x;
  out[O_ATTN + idx] = attnt[idx] / rsum[idx / HWp];
}

__global__ void k_slots_out(const float* __restrict__ slots, float* __restrict__ out) {
  int idx = blockIdx.x * 256 + threadIdx.x;
  if (idx < 9216) out[O_SLOTS + idx] = slots[idx];
}

__global__ __launch_bounds__(256) void k_final(float* __restrict__ out) {
  int b = blockIdx.y;
  int j = blockIdx.x * 256 + threadIdx.x;
  float r[9], ml[9];
#pragma unroll
  for (int s = 0; s < 9; ++s) {
    r[s]  = out[O_RECON + (size_t)(b * 9 + s) * HWp + j];
    ml[s] = out[O_MASK  + (size_t)(b * 9 + s) * HWp + j];
  }
  float mx = ml[0];
#pragma unroll
  for (int s = 1; s < 9; ++s) mx = fmaxf(mx, ml[s]);
  float sum = 0.f;
#pragma unroll
  for (int s = 0; s < 9; ++s) { ml[s] = __expf(ml[s] - mx); sum += ml[s]; }
  float inv = 1.f / sum;
  float comb = 0.f;
#pragma unroll
  for (int s = 0; s < 9; ++s) {
    float mk = ml[s] * inv;
    comb = fmaf(r[s], mk, comb);
    out[O_MASK + (size_t)(b * 9 + s) * HWp + j] = mk;
  }
  out[O_COMB + (size_t)b * HWp + j] = comb;
}

}  // namespace

// ---------------------------------------------------------------------------

extern "C" void kernel_launch(void* const* d_in, const int* in_sizes, int n_in,
                              void* d_out, int out_size, void* d_ws, size_t ws_size,
                              hipStream_t stream) {
  if (ws_size < W_TOTAL * sizeof(float)) return;

  const float* in_x       = (const float*)d_in[0];
  const float* slot_noise = (const float*)d_in[1];
  const float* enc_w1 = (const float*)d_in[2];   const float* enc_b1 = (const float*)d_in[3];
  const float* enc_w2 = (const float*)d_in[4];   const float* enc_b2 = (const float*)d_in[5];
  const float* enc_w3 = (const float*)d_in[6];   const float* enc_b3 = (const float*)d_in[7];
  const float* enc_w4 = (const float*)d_in[8];   const float* enc_b4 = (const float*)d_in[9];
  const float* pe_enc_w = (const float*)d_in[10]; const float* pe_enc_b = (const float*)d_in[11];
  const float* ln_enc_g = (const float*)d_in[12]; const float* ln_enc_b = (const float*)d_in[13];
  const float* mlp_w1 = (const float*)d_in[14];  const float* mlp_b1 = (const float*)d_in[15];
  const float* mlp_w2 = (const float*)d_in[16];  const float* mlp_b2 = (const float*)d_in[17];
  const float* slots_mu = (const float*)d_in[18]; const float* slots_sigma = (const float*)d_in[19];
  const float* ni_g = (const float*)d_in[20];    const float* ni_b = (const float*)d_in[21];
  const float* ns_g = (const float*)d_in[22];    const float* ns_b = (const float*)d_in[23];
  const float* q_w = (const float*)d_in[24];     const float* q_b = (const float*)d_in[25];
  const float* k_w = (const float*)d_in[26];     const float* k_b = (const float*)d_in[27];
  const float* v_w = (const float*)d_in[28];     const float* v_b = (const float*)d_in[29];
  const float* gru_wih = (const float*)d_in[30]; const float* gru_whh = (const float*)d_in[31];
  const float* gru_bih = (const float*)d_in[32]; const float* gru_bhh = (const float*)d_in[33];
  const float* res_ln_g = (const float*)d_in[34]; const float* res_ln_b = (const float*)d_in[35];
  const float* res_w1 = (const float*)d_in[36];  const float* res_b1 = (const float*)d_in[37];
  const float* res_w2 = (const float*)d_in[38];  const float* res_b2 = (const float*)d_in[39];
  const float* pe_dec_w = (const float*)d_in[40]; const float* pe_dec_b = (const float*)d_in[41];
  const float* dec_w1 = (const float*)d_in[42];  const float* dec_b1 = (const float*)d_in[43];
  const float* dec_w2 = (const float*)d_in[44];  const float* dec_b2 = (const float*)d_in[45];
  const float* dec_w3 = (const float*)d_in[46];  const float* dec_b3 = (const float*)d_in[47];
  const float* dec_w4 = (const float*)d_in[48];  const float* dec_b4 = (const float*)d_in[49];

  float* ws  = (float*)d_ws;
  float* out = (float*)d_out;
  ushort* wp  = (ushort*)(ws + W_WP);
  ushort* wpm = (ushort*)(ws + W_WPM);

  k_pe_maps<<<dim3(25), 256, 0, stream>>>(pe_enc_w, pe_enc_b, pe_dec_w, pe_dec_b,
                                          ws + W_PEENC, ws + W_PEDEC);

  const size_t WPSTR = 25 * 2 * 64 * 8;
  k_pack<<<dim3(25), 128, 0, stream>>>(enc_w2, wp + 0 * WPSTR, 0);
  k_pack<<<dim3(25), 128, 0, stream>>>(enc_w3, wp + 1 * WPSTR, 0);
  k_pack<<<dim3(25), 128, 0, stream>>>(enc_w4, wp + 2 * WPSTR, 0);
  k_pack<<<dim3(25), 128, 0, stream>>>(dec_w1, wp + 3 * WPSTR, 1);
  k_pack<<<dim3(25), 128, 0, stream>>>(dec_w2, wp + 4 * WPSTR, 1);
  k_pack<<<dim3(25), 128, 0, stream>>>(dec_w3, wp + 5 * WPSTR, 1);
  k_pack_mat<<<dim3(1), 128, 0, stream>>>(mlp_w1, wpm + 0 * 1024);
  k_pack_mat<<<dim3(1), 128, 0, stream>>>(mlp_w2, wpm + 1 * 1024);
  k_pack_mat<<<dim3(1), 128, 0, stream>>>(k_w,   wpm + 2 * 1024);
  k_pack_mat<<<dim3(1), 128, 0, stream>>>(v_w,   wpm + 3 * 1024);
  k_prep_tc<<<dim3(25), 1024, 0, stream>>>(dec_w1, ws + W_TC);

  ushort* base  = (ushort*)(ws + W_BASE);
  ushort* keys  = (ushort*)(ws + W_KEYS);
  ushort* vals  = (ushort*)(ws + W_VALS);
  float*  attnt = ws + W_POOL;
  ushort* E1    = (ushort*)(ws + W_POOL);
  ushort* E2    = (ushort*)(ws + W_POOL + 3276800);

  // base = convT1(pe_dec) + bias (1 img)
  k_conv_mfma<0, false><<<dim3(10, 1), 256, 0, stream>>>(
      ws + W_PEDEC, wp + 3 * WPSTR, dec_b1, base, nullptr, 0);

  // ---------------- encoder ----------------
  k_conv1<<<dim3(25, Bb), 256, 0, stream>>>(in_x, enc_w1, enc_b1, E1);
  k_conv_mfma<1, true><<<dim3(10, Bb), 256, 0, stream>>>(E1, wp + 0 * WPSTR, enc_b2, E2, nullptr, 0);
  k_conv_mfma<1, true><<<dim3(10, Bb), 256, 0, stream>>>(E2, wp + 1 * WPSTR, enc_b3, E1, nullptr, 0);
  k_conv_mfma<1, true><<<dim3(10, Bb), 256, 0, stream>>>(E1, wp + 2 * WPSTR, enc_b4, E2, nullptr, 0);

  k_hstats<<<dim3(25, Bb), 256, 0, stream>>>(E2, ws + W_PEENC, ws + W_LNPART);
  k_statsfin<<<dim3(1), 64, 0, stream>>>(ws + W_LNPART, ws + W_MEANR);
  k_lnmlpkv_mfma<<<dim3(25, Bb), 256, 0, stream>>>(E2, ws + W_PEENC, ws + W_MEANR,
                                                   ln_enc_g, ln_enc_b, wpm,
                                                   mlp_b1, mlp_b2, ni_g, ni_b,
                                                   k_b, v_b, keys, vals);

  // ---------------- slot attention ----------------
  k_init_q<<<dim3(36), 256, 0, stream>>>(slots_mu, slots_sigma, slot_noise,
                                         ns_g, ns_b, q_w, q_b, ws + W_SLOTS, ws + W_Q);
  for (int it = 0; it < 3; ++it) {
    if (it == 2)
      k_dots_upd<true><<<dim3(25, Bb), 256, 0, stream>>>(ws + W_Q, keys, vals, attnt,
                                                         ws + W_APART, ws + W_UP2);
    else
      k_dots_upd<false><<<dim3(25, Bb), 256, 0, stream>>>(ws + W_Q, keys, vals, attnt,
                                                          ws + W_APART, ws + W_UP2);
    k_gru_fused<<<dim3(36), 256, 0, stream>>>(ws + W_UP2, ws + W_APART,
                                              ws + W_SLOTS, ws + W_RSUM, ws + W_Q,
                                              gru_wih, gru_whh, gru_bih, gru_bhh,
                                              res_ln_g, res_ln_b, res_w1, res_b1,
                                              res_w2, res_b2, ns_g, ns_b, q_w, q_b);
  }
  k_attn_out<<<dim3(7200), 256, 0, stream>>>(attnt, ws + W_RSUM, out);
  k_slots_out<<<dim3(36), 256, 0, stream>>>(ws + W_SLOTS, out);

  k_ts<<<dim3(900), 256, 0, stream>>>(ws + W_TC, ws + W_SLOTS, ws + W_TS);

  // ---------------- decoder ----------------
  ushort* XA = (ushort*)(ws + W_POOL);
  ushort* XB = XA + (size_t)96 * 32 * HWp;
  for (int ch = 0; ch < 3; ++ch) {
    int n0 = ch * 96;
    k_conv_mfma<2, true><<<dim3(10, 96), 256, 0, stream>>>(base, wp + 4 * WPSTR, dec_b2, XA,
                                                           ws + W_TS, n0);
    k_conv_mfma<1, true><<<dim3(10, 96), 256, 0, stream>>>(XA, wp + 5 * WPSTR, dec_b3, XB,
                                                           nullptr, 0);
    k_conv4<<<dim3(25, 96), 256, 0, stream>>>(XB, dec_w4, dec_b4,
                                              out + O_RECON, out + O_MASK, n0);
  }

  k_final<<<dim3(25, Bb), 256, 0, stream>>>(out);
}

// Round 8
// 608.913 us; speedup vs baseline: 16.4825x; 1.0461x over previous
//
#include <hip/hip_runtime.h>
#include <cstddef>
#include <cstdint>

// ---------------------------------------------------------------------------
// STSN forward, v8: v7 + conv_mfma compute-loop restructured for row reuse
// (150 LDS reads / 500 MFMAs per wave instead of 250; bit-identical order).
// B=32, H=W=80, C=32, S=9, ITERS=3
// ---------------------------------------------------------------------------

namespace {

constexpr int Bb  = 32;
constexpr int HWp = 6400;
constexpr float SCALEf = 0.17677669529663687f;  // 32^-0.5

// output section offsets (floats)
constexpr size_t O_COMB  = 0;
constexpr size_t O_RECON = 204800;
constexpr size_t O_MASK  = 2048000;
constexpr size_t O_SLOTS = 3891200;
constexpr size_t O_ATTN  = 3900416;

// workspace layout (float offsets)
constexpr size_t W_PEENC = 0;                 // 204800 [hw][c] fp32
constexpr size_t W_PEDEC = 204800;            // 204800 [c][hw] fp32
constexpr size_t W_BASE  = 409600;            // 102400 (bf16 [hw][c])
constexpr size_t W_TC    = 512000;            // 25600
constexpr size_t W_TS    = 537600;            // 230400
constexpr size_t W_WP    = 768000;            // 76800 (packed conv weights bf16)
constexpr size_t W_WPM   = 844800;            // 2048 (packed 32x32 matrices bf16)
constexpr size_t W_LNPART= 846848;            // 1600
constexpr size_t W_MEANR = 848448;            // 64
constexpr size_t W_Q     = 848512;            // 9216
constexpr size_t W_SLOTS = 857728;            // 9216
constexpr size_t W_APART = 866944;            // 7200
constexpr size_t W_RSUM  = 874144;            // 288
constexpr size_t W_UP2   = 874432;            // 230400
constexpr size_t W_KEYS  = 1104832;           // 3276800 (bf16 [b][hw][c])
constexpr size_t W_VALS  = 4381632;           // 3276800 (bf16)
constexpr size_t W_POOL  = 7658432;           // 21456896 floats available
constexpr size_t W_TOTAL = 29115328;          // 116.5 MB
// Pool aliasing: E1/E2 (encoder) | attnt (attention) | XA/XB (decoder)

typedef __attribute__((ext_vector_type(8))) short short8;
typedef __attribute__((ext_vector_type(4))) float f32x4;

__device__ __forceinline__ ushort f2bf(float f) {
  uint u = __builtin_bit_cast(uint, f);
  uint r = (u + 0x7fffu + ((u >> 16) & 1u)) >> 16;   // RNE
  return (ushort)r;
}
__device__ __forceinline__ float bf2f(ushort b) {
  uint u = ((uint)b) << 16;
  return __builtin_bit_cast(float, u);
}
__device__ __forceinline__ void unpk2(uint w, float& a, float& b) {
  a = __builtin_bit_cast(float, w << 16);
  b = __builtin_bit_cast(float, w & 0xffff0000u);
}

__device__ __forceinline__ float lane_ln(float v, int o, const float* __restrict__ g,
                                         const float* __restrict__ b) {
  float s = v;
#pragma unroll
  for (int m = 16; m >= 1; m >>= 1) s += __shfl_xor(s, m);
  float mean = s * (1.f / 32.f);
  float d = v - mean;
  float q = d * d;
#pragma unroll
  for (int m = 16; m >= 1; m >>= 1) q += __shfl_xor(q, m);
  float rstd = rsqrtf(q * (1.f / 32.f) + 1e-5f);
  return d * rstd * g[o] + b[o];
}

// ---------------- positional-embedding maps ---------------------------------

__global__ void k_pe_maps(const float* __restrict__ pew_e, const float* __restrict__ peb_e,
                          const float* __restrict__ pew_d, const float* __restrict__ peb_d,
                          float* __restrict__ pe_enc, float* __restrict__ pe_dec) {
  int hw = blockIdx.x * 256 + threadIdx.x;
  if (hw >= HWp) return;
  int y = hw / 80, x = hw % 80;
  float g0 = y * (1.f / 79.f), g1 = x * (1.f / 79.f);
  float g2 = 1.f - g0, g3 = 1.f - g1;
#pragma unroll
  for (int c = 0; c < 32; ++c) {
    pe_enc[(size_t)hw * 32 + c] = peb_e[c] + g0 * pew_e[c * 4] + g1 * pew_e[c * 4 + 1] +
                                  g2 * pew_e[c * 4 + 2] + g3 * pew_e[c * 4 + 3];
    pe_dec[(size_t)c * HWp + hw] = peb_d[c] + g0 * pew_d[c * 4] + g1 * pew_d[c * 4 + 1] +
                                   g2 * pew_d[c * 4 + 2] + g3 * pew_d[c * 4 + 3];
  }
}

// ---------------- weight packing -------------------------------------------

__global__ void k_pack(const float* __restrict__ w, ushort* __restrict__ dst, int trans) {
  int tap = blockIdx.x;
  int grp = threadIdx.x >> 6, lane = threadIdx.x & 63;
  int ky = tap / 5, kx = tap % 5;
  int m = grp * 16 + (lane & 15);
  int kb = (lane >> 4) * 8;
  ushort* o = dst + ((size_t)(tap * 2 + grp) * 64 + lane) * 8;
#pragma unroll
  for (int j = 0; j < 8; ++j) {
    int k = kb + j;
    float v = trans ? w[(size_t)k * 800 + m * 25 + (4 - ky) * 5 + (4 - kx)]
                    : w[(size_t)m * 800 + k * 25 + ky * 5 + kx];
    o[j] = f2bf(v);
  }
}

// pack a row-major [32][32] matrix (y = x @ W^T form, A[m=o][k=c]) into A-frags
__global__ void k_pack_mat(const float* __restrict__ w, ushort* __restrict__ dst) {
  int grp = threadIdx.x >> 6, lane = threadIdx.x & 63;   // 128 threads
  int m = grp * 16 + (lane & 15), kb = (lane >> 4) * 8;
  ushort* o = dst + ((size_t)(grp * 64 + lane)) * 8;
#pragma unroll
  for (int j = 0; j < 8; ++j) o[j] = f2bf(w[m * 32 + kb + j]);
}

// ---------------- Tc / Ts for algebraic decoder conv1 ------------------------

__global__ void k_prep_tc(const float* __restrict__ w, float* __restrict__ tc) {
  const int rep[5] = {0, 1, 40, 78, 79};
  int cls = blockIdx.x;
  int yc = cls / 5, xc = cls % 5;
  int ci = threadIdx.x >> 5, co = threadIdx.x & 31;
  int yr = rep[yc], xr = rep[xc];
  float s = 0.f;
#pragma unroll
  for (int ky = 0; ky < 5; ++ky) {
    if ((unsigned)(yr + ky - 2) >= 80u) continue;
#pragma unroll
    for (int kx = 0; kx < 5; ++kx) {
      if ((unsigned)(xr + kx - 2) >= 80u) continue;
      s += w[(size_t)ci * 800 + co * 25 + (4 - ky) * 5 + (4 - kx)];
    }
  }
  tc[(size_t)cls * 1024 + ci * 32 + co] = s;
}

__global__ void k_ts(const float* __restrict__ tc, const float* __restrict__ slots,
                     float* __restrict__ ts) {
  int idx = blockIdx.x * 256 + threadIdx.x;
  if (idx >= 288 * 800) return;
  int img = idx / 800, rem = idx % 800;
  int cls = rem >> 5, o = rem & 31;
  float s = 0.f;
#pragma unroll
  for (int ci = 0; ci < 32; ++ci)
    s += tc[(size_t)cls * 1024 + ci * 32 + o] * slots[(size_t)img * 32 + ci];
  ts[idx] = s;
}

// ---------------- MFMA conv (32->32, 5x5, pad 2) -----------------------------
// MODE 0: fp32 channel-major input (base precompute). MODE 1: bf16 chlast.
// MODE 2: relu(base[hw][c] + ts[n0+img][cls(hw)][c]) fused dec1.
// Compute loop iterates over the 6 absolute input rows a wave touches; each
// B-frag read feeds up to 4 MFMAs (2 output rows x 2 co-halves). Accumulation
// order per acc is identical to the tap-major form (bit-identical result).

template <int MODE, bool RELU>
__global__ __launch_bounds__(256, 2) void k_conv_mfma(
    const void* __restrict__ in_, const ushort* __restrict__ wp,
    const float* __restrict__ bias, ushort* __restrict__ out_,
    const float* __restrict__ ts, int n0) {
  __shared__ int4 sm[4032];
  const int n = blockIdx.y, rt = blockIdx.x;
  const int t = threadIdx.x;

  for (int i = t; i < 4032; i += 256) {
    int x = i % 84, ru = i / 84;
    int r = ru >> 2, u = ru & 3;
    int gy = rt * 8 + r - 2, gx = x - 2;
    int4 pk = {0, 0, 0, 0};
    if ((unsigned)gy < 80u && (unsigned)gx < 80u) {
      int hw = gy * 80 + gx;
      if constexpr (MODE == 0) {
        const float* fp = (const float*)in_;
        ushort bb[8];
#pragma unroll
        for (int j = 0; j < 8; ++j)
          bb[j] = f2bf(fp[(size_t)(u * 8 + j) * HWp + hw]);
        pk.x = (int)((uint)bb[0] | ((uint)bb[1] << 16));
        pk.y = (int)((uint)bb[2] | ((uint)bb[3] << 16));
        pk.z = (int)((uint)bb[4] | ((uint)bb[5] << 16));
        pk.w = (int)((uint)bb[6] | ((uint)bb[7] << 16));
      } else if constexpr (MODE == 1) {
        pk = *(const int4*)((const ushort*)in_ + ((size_t)n * HWp + hw) * 32 + u * 8);
      } else {
        int4 bp = *(const int4*)((const ushort*)in_ + (size_t)hw * 32 + u * 8);
        int yc = gy < 2 ? gy : (gy > 77 ? gy - 75 : 2);
        int xc = gx < 2 ? gx : (gx > 77 ? gx - 75 : 2);
        const float* tp = ts + ((size_t)(n0 + n) * 25 + (yc * 5 + xc)) * 32 + u * 8;
        float t0, t1;
        uint* pw = (uint*)&pk;
        const uint* bw = (const uint*)&bp;
#pragma unroll
        for (int h = 0; h < 4; ++h) {
          unpk2(bw[h], t0, t1);
          float f0 = fmaxf(t0 + tp[2 * h], 0.f);
          float f1 = fmaxf(t1 + tp[2 * h + 1], 0.f);
          pw[h] = (uint)f2bf(f0) | ((uint)f2bf(f1) << 16);
        }
      }
    }
    int up = u ^ ((x >> 1) & 3);
    sm[(r * 84 + x) * 4 + up] = pk;
  }
  __syncthreads();

  const int wv = t >> 6, lane = t & 63;
  const int l15 = lane & 15, lg = lane >> 4;
  const short8* smS = (const short8*)sm;

  f32x4 acc[2][5][2];
#pragma unroll
  for (int a = 0; a < 2; ++a)
#pragma unroll
    for (int b = 0; b < 5; ++b)
#pragma unroll
      for (int c = 0; c < 2; ++c) acc[a][b][c] = f32x4{0.f, 0.f, 0.f, 0.f};

  // row-major compute: absolute row wv*2 + r6; ri=0 uses dy=r6, ri=1 uses dy=r6-1
#pragma unroll
  for (int r6 = 0; r6 < 6; ++r6) {
    const int rbase = (wv * 2 + r6) * 336;
#pragma unroll
    for (int dx = 0; dx < 5; ++dx) {
      short8 Aa0, Aa1, Ab0, Ab1;
      if (r6 <= 4) {
        int tap = r6 * 5 + dx;
        Aa0 = *(const short8*)(wp + ((size_t)(tap * 2 + 0) * 64 + lane) * 8);
        Aa1 = *(const short8*)(wp + ((size_t)(tap * 2 + 1) * 64 + lane) * 8);
      }
      if (r6 >= 1) {
        int tap = (r6 - 1) * 5 + dx;
        Ab0 = *(const short8*)(wp + ((size_t)(tap * 2 + 0) * 64 + lane) * 8);
        Ab1 = *(const short8*)(wp + ((size_t)(tap * 2 + 1) * 64 + lane) * 8);
      }
#pragma unroll
      for (int xg = 0; xg < 5; ++xg) {
        int xs = xg * 16 + l15 + dx;
        short8 Bv = smS[rbase + xs * 4 + (lg ^ ((xs >> 1) & 3))];
        if (r6 <= 4) {
          acc[0][xg][0] = __builtin_amdgcn_mfma_f32_16x16x32_bf16(Aa0, Bv, acc[0][xg][0], 0, 0, 0);
          acc[0][xg][1] = __builtin_amdgcn_mfma_f32_16x16x32_bf16(Aa1, Bv, acc[0][xg][1], 0, 0, 0);
        }
        if (r6 >= 1) {
          acc[1][xg][0] = __builtin_amdgcn_mfma_f32_16x16x32_bf16(Ab0, Bv, acc[1][xg][0], 0, 0, 0);
          acc[1][xg][1] = __builtin_amdgcn_mfma_f32_16x16x32_bf16(Ab1, Bv, acc[1][xg][1], 0, 0, 0);
        }
      }
    }
  }

  float bv[2][4];
#pragma unroll
  for (int cg = 0; cg < 2; ++cg)
#pragma unroll
    for (int q = 0; q < 4; ++q) bv[cg][q] = bias[cg * 16 + lg * 4 + q];
  int y0 = rt * 8 + wv * 2;
#pragma unroll
  for (int ri = 0; ri < 2; ++ri) {
#pragma unroll
    for (int xg = 0; xg < 5; ++xg) {
      size_t px = (size_t)n * HWp + (y0 + ri) * 80 + (xg * 16 + l15);
#pragma unroll
      for (int cg = 0; cg < 2; ++cg) {
        f32x4 v = acc[ri][xg][cg];
        float o0 = v[0] + bv[cg][0], o1 = v[1] + bv[cg][1];
        float o2 = v[2] + bv[cg][2], o3 = v[3] + bv[cg][3];
        if (RELU) {
          o0 = fmaxf(o0, 0.f); o1 = fmaxf(o1, 0.f);
          o2 = fmaxf(o2, 0.f); o3 = fmaxf(o3, 0.f);
        }
        uint2 pk;
        pk.x = (uint)f2bf(o0) | ((uint)f2bf(o1) << 16);
        pk.y = (uint)f2bf(o2) | ((uint)f2bf(o3) << 16);
        *(uint2*)(out_ + px * 32 + cg * 16 + lg * 4) = pk;
      }
    }
  }
}

// ---------------- encoder conv1 ----------------------------------------------

__global__ __launch_bounds__(256) void k_conv1(const float* __restrict__ in,
                                               const float* __restrict__ w,
                                               const float* __restrict__ b,
                                               ushort* __restrict__ out) {
  int hw = blockIdx.x * 256 + threadIdx.x;
  int n = blockIdx.y;
  int y = hw / 80, x = hw % 80;
  float xv[25];
#pragma unroll
  for (int ky = 0; ky < 5; ++ky)
#pragma unroll
    for (int kx = 0; kx < 5; ++kx) {
      int iy = y + ky - 2, ix = x + kx - 2;
      xv[ky * 5 + kx] = ((unsigned)iy < 80u && (unsigned)ix < 80u)
                            ? in[(size_t)n * HWp + iy * 80 + ix] : 0.f;
    }
  float a[32];
#pragma unroll
  for (int co = 0; co < 32; ++co) {
    float s = b[co];
#pragma unroll
    for (int tp = 0; tp < 25; ++tp) s = fmaf(xv[tp], w[co * 25 + tp], s);
    a[co] = fmaxf(s, 0.f);
  }
  ushort* op = out + ((size_t)n * HWp + hw) * 32;
#pragma unroll
  for (int g = 0; g < 4; ++g) {
    uint4 pk;
    pk.x = (uint)f2bf(a[g * 8 + 0]) | ((uint)f2bf(a[g * 8 + 1]) << 16);
    pk.y = (uint)f2bf(a[g * 8 + 2]) | ((uint)f2bf(a[g * 8 + 3]) << 16);
    pk.z = (uint)f2bf(a[g * 8 + 4]) | ((uint)f2bf(a[g * 8 + 5]) << 16);
    pk.w = (uint)f2bf(a[g * 8 + 6]) | ((uint)f2bf(a[g * 8 + 7]) << 16);
    *(uint4*)(op + g * 8) = pk;
  }
}

// ---------------- decoder conv4 (32->2, 3x3, trans) --------------------------

__global__ __launch_bounds__(256) void k_conv4(const ushort* __restrict__ in,
                                               const float* __restrict__ w,
                                               const float* __restrict__ b,
                                               float* __restrict__ outR,
                                               float* __restrict__ outM, int n0) {
  __shared__ float sw[2 * 288];
  for (int e = threadIdx.x; e < 576; e += 256) {
    int co = e / 288, rem = e % 288;
    int tap = rem / 32, ci = rem % 32;
    sw[e] = w[(size_t)(ci * 2 + co) * 9 + 8 - tap];
  }
  __syncthreads();
  int hw = blockIdx.x * 256 + threadIdx.x;
  int nl = blockIdx.y;
  int y = hw / 80, x = hw % 80;
  float a0 = b[0], a1 = b[1];
  const ushort* ip = in + (size_t)nl * HWp * 32;
#pragma unroll
  for (int ky = 0; ky < 3; ++ky) {
#pragma unroll
    for (int kx = 0; kx < 3; ++kx) {
      int iy = y + ky - 1, ix = x + kx - 1;
      if ((unsigned)iy >= 80u || (unsigned)ix >= 80u) continue;
      int tap = ky * 3 + kx;
      const int4* p = (const int4*)(ip + (size_t)(iy * 80 + ix) * 32);
      const float* w0 = sw + tap * 32;
      const float* w1 = sw + 288 + tap * 32;
#pragma unroll
      for (int u = 0; u < 4; ++u) {
        int4 ch = p[u];
        const uint* cw = (const uint*)&ch;
#pragma unroll
        for (int h = 0; h < 4; ++h) {
          float v0, v1;
          unpk2(cw[h], v0, v1);
          int ci = u * 8 + h * 2;
          a0 = fmaf(v0, w0[ci], a0);     a1 = fmaf(v0, w1[ci], a1);
          a0 = fmaf(v1, w0[ci + 1], a0); a1 = fmaf(v1, w1[ci + 1], a1);
        }
      }
    }
  }
  outR[(size_t)(n0 + nl) * HWp + hw] = a0;
  outM[(size_t)(n0 + nl) * HWp + hw] = a1;
}

// ---------------- big-LN stats from E2+PE ------------------------------------

__global__ __launch_bounds__(256) void k_hstats(const ushort* __restrict__ enc,
                                                const float* __restrict__ pe_enc,
                                                float* __restrict__ lnpart) {
  int b = blockIdx.y;
  int hw = blockIdx.x * 256 + threadIdx.x;
  const int4* ep = (const int4*)(enc + ((size_t)b * HWp + hw) * 32);
  float v[32];
#pragma unroll
  for (int u = 0; u < 4; ++u) {
    int4 ch = ep[u];
    const uint* cw = (const uint*)&ch;
#pragma unroll
    for (int h = 0; h < 4; ++h) unpk2(cw[h], v[u * 8 + h * 2], v[u * 8 + h * 2 + 1]);
  }
  float s = 0.f, ss = 0.f;
#pragma unroll
  for (int c = 0; c < 32; ++c) {
    v[c] += pe_enc[(size_t)hw * 32 + c];
    s += v[c]; ss += v[c] * v[c];
  }
  __shared__ float r1[256], r2[256];
  r1[threadIdx.x] = s; r2[threadIdx.x] = ss;
  __syncthreads();
  for (int off = 128; off > 0; off >>= 1) {
    if (threadIdx.x < off) { r1[threadIdx.x] += r1[threadIdx.x + off]; r2[threadIdx.x] += r2[threadIdx.x + off]; }
    __syncthreads();
  }
  if (threadIdx.x == 0) {
    lnpart[(size_t)(b * 25 + blockIdx.x) * 2] = r1[0];
    lnpart[(size_t)(b * 25 + blockIdx.x) * 2 + 1] = r2[0];
  }
}

__global__ void k_statsfin(const float* __restrict__ lnpart, float* __restrict__ meanr) {
  int b = threadIdx.x;
  if (b >= 32) return;
  float s = 0.f, ss = 0.f;
  for (int k = 0; k < 25; ++k) {
    s += lnpart[(size_t)(b * 25 + k) * 2];
    ss += lnpart[(size_t)(b * 25 + k) * 2 + 1];
  }
  float m = s * (1.f / 204800.f);
  float var = ss * (1.f / 204800.f) - m * m;
  meanr[b * 2] = m;
  meanr[b * 2 + 1] = rsqrtf(var + 1e-5f);
}

// ---------------- MFMA lnmlpkv ----------------------------------------------

__global__ __launch_bounds__(256) void k_lnmlpkv_mfma(
    const ushort* __restrict__ enc, const float* __restrict__ pe,
    const float* __restrict__ meanr,
    const float* __restrict__ g, const float* __restrict__ bb,
    const ushort* __restrict__ wm,
    const float* __restrict__ b1, const float* __restrict__ b2,
    const float* __restrict__ nig, const float* __restrict__ nib,
    const float* __restrict__ kb, const float* __restrict__ vb,
    ushort* __restrict__ keys, ushort* __restrict__ vals) {
  __shared__ ushort ls[256 * 32];   // 16 KB bounce buffer
  const int b = blockIdx.y, jb = blockIdx.x;
  const int t = threadIdx.x, wv = t >> 6, lane = t & 63;
  const int l15 = lane & 15, lg = lane >> 4;
  const int skey = l15 & 3;

  short8 A[4][2];
#pragma unroll
  for (int mt = 0; mt < 4; ++mt)
#pragma unroll
    for (int gr = 0; gr < 2; ++gr)
      A[mt][gr] = *(const short8*)(wm + ((size_t)(mt * 2 + gr) * 64 + lane) * 8);

  float4 b1v0 = *(const float4*)(b1 + lg * 4),  b1v1 = *(const float4*)(b1 + 16 + lg * 4);
  float4 b2v0 = *(const float4*)(b2 + lg * 4),  b2v1 = *(const float4*)(b2 + 16 + lg * 4);
  float4 ng0  = *(const float4*)(nig + lg * 4), ng1  = *(const float4*)(nig + 16 + lg * 4);
  float4 nb0  = *(const float4*)(nib + lg * 4), nb1  = *(const float4*)(nib + 16 + lg * 4);
  float4 kbv0 = *(const float4*)(kb + lg * 4),  kbv1 = *(const float4*)(kb + 16 + lg * 4);
  float4 vbv0 = *(const float4*)(vb + lg * 4),  vbv1 = *(const float4*)(vb + 16 + lg * 4);

  const float m_ = meanr[b * 2], rs_ = meanr[b * 2 + 1];

  short8 bx[4];
#pragma unroll
  for (int g2 = 0; g2 < 4; ++g2) {
    int pos = jb * 256 + wv * 64 + g2 * 16 + l15;
    int4 e = *(const int4*)(enc + ((size_t)b * HWp + pos) * 32 + lg * 8);
    float xv[8];
    const uint* ew = (const uint*)&e;
#pragma unroll
    for (int h = 0; h < 4; ++h) unpk2(ew[h], xv[2 * h], xv[2 * h + 1]);
    float4 p0 = *(const float4*)(pe + (size_t)pos * 32 + lg * 8);
    float4 p1 = *(const float4*)(pe + (size_t)pos * 32 + lg * 8 + 4);
    float4 g0 = *(const float4*)(g + (size_t)pos * 32 + lg * 8);
    float4 g1 = *(const float4*)(g + (size_t)pos * 32 + lg * 8 + 4);
    float4 q0 = *(const float4*)(bb + (size_t)pos * 32 + lg * 8);
    float4 q1 = *(const float4*)(bb + (size_t)pos * 32 + lg * 8 + 4);
    float pv[8] = {p0.x, p0.y, p0.z, p0.w, p1.x, p1.y, p1.z, p1.w};
    float gv[8] = {g0.x, g0.y, g0.z, g0.w, g1.x, g1.y, g1.z, g1.w};
    float qv[8] = {q0.x, q0.y, q0.z, q0.w, q1.x, q1.y, q1.z, q1.w};
    uint pk[4];
#pragma unroll
    for (int h = 0; h < 4; ++h) {
      float f0 = (xv[2 * h] + pv[2 * h] - m_) * rs_ * gv[2 * h] + qv[2 * h];
      float f1 = (xv[2 * h + 1] + pv[2 * h + 1] - m_) * rs_ * gv[2 * h + 1] + qv[2 * h + 1];
      pk[h] = (uint)f2bf(f0) | ((uint)f2bf(f1) << 16);
    }
    bx[g2] = __builtin_bit_cast(short8, *(int4*)pk);
  }

  auto lds_write = [&](int posl, int cg, const f32x4& v) {
    int u = cg * 2 + (lg >> 1);
    int us = u ^ skey;
    uint2 pk;
    pk.x = (uint)f2bf(v[0]) | ((uint)f2bf(v[1]) << 16);
    pk.y = (uint)f2bf(v[2]) | ((uint)f2bf(v[3]) << 16);
    *(uint2*)(ls + (size_t)posl * 32 + us * 8 + (lg & 1) * 4) = pk;
  };

#pragma unroll
  for (int g2 = 0; g2 < 4; ++g2) {
    int posl = wv * 64 + g2 * 16 + l15;
    f32x4 a0 = __builtin_amdgcn_mfma_f32_16x16x32_bf16(A[0][0], bx[g2], f32x4{0, 0, 0, 0}, 0, 0, 0);
    f32x4 a1 = __builtin_amdgcn_mfma_f32_16x16x32_bf16(A[0][1], bx[g2], f32x4{0, 0, 0, 0}, 0, 0, 0);
    f32x4 r0, r1;
#pragma unroll
    for (int q = 0; q < 4; ++q) {
      r0[q] = fmaxf(a0[q] + (&b1v0.x)[q], 0.f);
      r1[q] = fmaxf(a1[q] + (&b1v1.x)[q], 0.f);
    }
    lds_write(posl, 0, r0);
    lds_write(posl, 1, r1);
  }
  __syncthreads();
  short8 t0f[4];
#pragma unroll
  for (int g2 = 0; g2 < 4; ++g2) {
    int posl = wv * 64 + g2 * 16 + l15;
    t0f[g2] = *(const short8*)(ls + (size_t)posl * 32 + (lg ^ skey) * 8);
  }
  __syncthreads();

#pragma unroll
  for (int g2 = 0; g2 < 4; ++g2) {
    int posl = wv * 64 + g2 * 16 + l15;
    f32x4 c0 = __builtin_amdgcn_mfma_f32_16x16x32_bf16(A[1][0], t0f[g2], f32x4{0, 0, 0, 0}, 0, 0, 0);
    f32x4 c1 = __builtin_amdgcn_mfma_f32_16x16x32_bf16(A[1][1], t0f[g2], f32x4{0, 0, 0, 0}, 0, 0, 0);
#pragma unroll
    for (int q = 0; q < 4; ++q) { c0[q] += (&b2v0.x)[q]; c1[q] += (&b2v1.x)[q]; }
    float s = 0.f;
#pragma unroll
    for (int q = 0; q < 4; ++q) s += c0[q] + c1[q];
    s += __shfl_xor(s, 16); s += __shfl_xor(s, 32);
    float mean = s * (1.f / 32.f);
    float var = 0.f;
#pragma unroll
    for (int q = 0; q < 4; ++q) {
      float d0 = c0[q] - mean, d1 = c1[q] - mean;
      var += d0 * d0 + d1 * d1;
    }
    var += __shfl_xor(var, 16); var += __shfl_xor(var, 32);
    float rstd = rsqrtf(var * (1.f / 32.f) + 1e-5f);
    f32x4 y0, y1;
#pragma unroll
    for (int q = 0; q < 4; ++q) {
      y0[q] = (c0[q] - mean) * rstd * (&ng0.x)[q] + (&nb0.x)[q];
      y1[q] = (c1[q] - mean) * rstd * (&ng1.x)[q] + (&nb1.x)[q];
    }
    lds_write(posl, 0, y0);
    lds_write(posl, 1, y1);
  }
  __syncthreads();
  short8 xnf[4];
#pragma unroll
  for (int g2 = 0; g2 < 4; ++g2) {
    int posl = wv * 64 + g2 * 16 + l15;
    xnf[g2] = *(const short8*)(ls + (size_t)posl * 32 + (lg ^ skey) * 8);
  }

#pragma unroll
  for (int g2 = 0; g2 < 4; ++g2) {
    int pos = jb * 256 + wv * 64 + g2 * 16 + l15;
    size_t px = ((size_t)b * HWp + pos) * 32;
    f32x4 k0 = __builtin_amdgcn_mfma_f32_16x16x32_bf16(A[2][0], xnf[g2], f32x4{0, 0, 0, 0}, 0, 0, 0);
    f32x4 k1 = __builtin_amdgcn_mfma_f32_16x16x32_bf16(A[2][1], xnf[g2], f32x4{0, 0, 0, 0}, 0, 0, 0);
    f32x4 v0 = __builtin_amdgcn_mfma_f32_16x16x32_bf16(A[3][0], xnf[g2], f32x4{0, 0, 0, 0}, 0, 0, 0);
    f32x4 v1 = __builtin_amdgcn_mfma_f32_16x16x32_bf16(A[3][1], xnf[g2], f32x4{0, 0, 0, 0}, 0, 0, 0);
    uint2 pk;
    pk.x = (uint)f2bf(k0[0] + kbv0.x) | ((uint)f2bf(k0[1] + kbv0.y) << 16);
    pk.y = (uint)f2bf(k0[2] + kbv0.z) | ((uint)f2bf(k0[3] + kbv0.w) << 16);
    *(uint2*)(keys + px + lg * 4) = pk;
    pk.x = (uint)f2bf(k1[0] + kbv1.x) | ((uint)f2bf(k1[1] + kbv1.y) << 16);
    pk.y = (uint)f2bf(k1[2] + kbv1.z) | ((uint)f2bf(k1[3] + kbv1.w) << 16);
    *(uint2*)(keys + px + 16 + lg * 4) = pk;
    pk.x = (uint)f2bf(v0[0] + vbv0.x) | ((uint)f2bf(v0[1] + vbv0.y) << 16);
    pk.y = (uint)f2bf(v0[2] + vbv0.z) | ((uint)f2bf(v0[3] + vbv0.w) << 16);
    *(uint2*)(vals + px + lg * 4) = pk;
    pk.x = (uint)f2bf(v1[0] + vbv1.x) | ((uint)f2bf(v1[1] + vbv1.y) << 16);
    pk.y = (uint)f2bf(v1[2] + vbv1.z) | ((uint)f2bf(v1[3] + vbv1.w) << 16);
    *(uint2*)(vals + px + 16 + lg * 4) = pk;
  }
}

// ---------------- slot attention -------------------------------------------

__global__ __launch_bounds__(256) void k_init_q(
    const float* __restrict__ mu, const float* __restrict__ sig,
    const float* __restrict__ noise,
    const float* __restrict__ nsg, const float* __restrict__ nsb,
    const float* __restrict__ qw, const float* __restrict__ qb,
    float* __restrict__ slots, float* __restrict__ qbuf) {
  int rl = threadIdx.x >> 5, o = threadIdx.x & 31;
  int r = blockIdx.x * 8 + rl;
  float s = mu[o] + sig[o] * noise[(size_t)r * 32 + o];
  slots[(size_t)r * 32 + o] = s;
  float y = lane_ln(s, o, nsg, nsb);
  __shared__ float S[8][32];
  S[rl][o] = y;
  __syncthreads();
  float qv = qb[o];
#pragma unroll
  for (int c = 0; c < 32; ++c) qv = fmaf(S[rl][c], qw[o * 32 + c], qv);
  qbuf[(size_t)r * 32 + o] = qv;
}

template <bool LAST>
__global__ __launch_bounds__(256) void k_dots_upd(
    const float* __restrict__ qbuf, const ushort* __restrict__ keys,
    const ushort* __restrict__ vals, float* __restrict__ attnt,
    float* __restrict__ apart, float* __restrict__ up2) {
  int b = blockIdx.y, jb = blockIdx.x;
  int t = threadIdx.x;
  int j = jb * 256 + t;
  __shared__ float qs[288];
  __shared__ float aL[2304];
  __shared__ float wr[36];
  for (int e = t; e < 288; e += 256) qs[e] = qbuf[(size_t)b * 288 + e];
  __syncthreads();
  float k[32];
  const int4* kp = (const int4*)(keys + ((size_t)b * HWp + j) * 32);
#pragma unroll
  for (int u = 0; u < 4; ++u) {
    int4 ch = kp[u];
    const uint* cw = (const uint*)&ch;
#pragma unroll
    for (int h = 0; h < 4; ++h) unpk2(cw[h], k[u * 8 + h * 2], k[u * 8 + h * 2 + 1]);
  }
  float d[9];
#pragma unroll
  for (int i = 0; i < 9; ++i) {
    float a = 0.f;
#pragma unroll
    for (int c = 0; c < 32; ++c) a = fmaf(qs[i * 32 + c], k[c], a);
    d[i] = a * SCALEf;
  }
  float mx = d[0];
#pragma unroll
  for (int i = 1; i < 9; ++i) mx = fmaxf(mx, d[i]);
  float sum = 0.f;
#pragma unroll
  for (int i = 0; i < 9; ++i) { d[i] = __expf(d[i] - mx); sum += d[i]; }
  float inv = 1.f / sum;
  float a9[9];
#pragma unroll
  for (int i = 0; i < 9; ++i) {
    a9[i] = d[i] * inv + 1e-8f;
    if (LAST) attnt[((size_t)b * 9 + i) * HWp + j] = a9[i];
    aL[t * 9 + i] = a9[i];
  }
  int lane = t & 63, wid = t >> 6;
#pragma unroll
  for (int i = 0; i < 9; ++i) {
    float v = a9[i];
    for (int off = 32; off > 0; off >>= 1) v += __shfl_down(v, off);
    if (lane == 0) wr[wid * 9 + i] = v;
  }
  __syncthreads();
  if (t < 9)
    apart[(size_t)(b * 9 + t) * 25 + jb] = wr[t] + wr[9 + t] + wr[18 + t] + wr[27 + t];
  int c = t & 31, g = t >> 5;
  float acc[9];
#pragma unroll
  for (int i = 0; i < 9; ++i) acc[i] = 0.f;
  const ushort* vp = vals + ((size_t)b * HWp + jb * 256) * 32 + c;
  for (int jj = g; jj < 256; jj += 8) {
    float v = bf2f(vp[(size_t)jj * 32]);
#pragma unroll
    for (int i = 0; i < 9; ++i) acc[i] = fmaf(v, aL[jj * 9 + i], acc[i]);
  }
  __syncthreads();
#pragma unroll
  for (int i = 0; i < 9; ++i) aL[(i * 8 + g) * 32 + c] = acc[i];
  __syncthreads();
  for (int i = g; i < 9; i += 8) {
    float s = 0.f;
#pragma unroll
    for (int g2 = 0; g2 < 8; ++g2) s += aL[(i * 8 + g2) * 32 + c];
    up2[(((size_t)b * 25 + jb) * 9 + i) * 32 + c] = s;
  }
}

__global__ __launch_bounds__(256) void k_gru_fused(
    const float* __restrict__ up2, const float* __restrict__ apart,
    float* __restrict__ slots, float* __restrict__ rowsum, float* __restrict__ qbuf,
    const float* __restrict__ wih, const float* __restrict__ whh,
    const float* __restrict__ bih, const float* __restrict__ bhh,
    const float* __restrict__ rlg, const float* __restrict__ rlb,
    const float* __restrict__ rw1, const float* __restrict__ rb1,
    const float* __restrict__ rw2, const float* __restrict__ rb2,
    const float* __restrict__ nsg, const float* __restrict__ nsb,
    const float* __restrict__ qw, const float* __restrict__ qb) {
  int rl = threadIdx.x >> 5, o = threadIdx.x & 31;
  int r = blockIdx.x * 8 + rl;
  int b = r / 9, i = r - b * 9;

  float rs = 0.f;
#pragma unroll
  for (int k = 0; k < 25; ++k) rs += apart[(size_t)(b * 9 + i) * 25 + k];
  if (o == 0) rowsum[r] = rs;

  float uo = 0.f;
#pragma unroll
  for (int jc = 0; jc < 25; ++jc) uo += up2[(((size_t)b * 25 + jc) * 9 + i) * 32 + o];
  uo /= rs;
  float ho = slots[(size_t)r * 32 + o];

  __shared__ float Us[8][32], Hs[8][32];
  Us[rl][o] = uo; Hs[rl][o] = ho;
  __syncthreads();

  float xr = bih[o], xz = bih[32 + o], xc = bih[64 + o];
  float hr = bhh[o], hz = bhh[32 + o], hc = bhh[64 + o];
#pragma unroll
  for (int c = 0; c < 32; ++c) {
    float u = Us[rl][c], h = Hs[rl][c];
    xr = fmaf(u, wih[o * 32 + c], xr);          hr = fmaf(h, whh[o * 32 + c], hr);
    xz = fmaf(u, wih[(32 + o) * 32 + c], xz);   hz = fmaf(h, whh[(32 + o) * 32 + c], hz);
    xc = fmaf(u, wih[(64 + o) * 32 + c], xc);   hc = fmaf(h, whh[(64 + o) * 32 + c], hc);
  }
  float rr = 1.f / (1.f + __expf(-(xr + hr)));
  float zz = 1.f / (1.f + __expf(-(xz + hz)));
  float cand = tanhf(xc + rr * hc);
  float sm = (1.f - zz) * cand + zz * ho;

  float y = lane_ln(sm, o, rlg, rlb);
  __syncthreads();
  Us[rl][o] = y;
  __syncthreads();
  float t1 = rb1[o];
#pragma unroll
  for (int c = 0; c < 32; ++c) t1 = fmaf(Us[rl][c], rw1[o * 32 + c], t1);
  t1 = fmaxf(t1, 0.f);
  Hs[rl][o] = t1;
  __syncthreads();
  float res = rb2[o];
#pragma unroll
  for (int c = 0; c < 32; ++c) res = fmaf(Hs[rl][c], rw2[o * 32 + c], res);
  float ns = sm + res;
  slots[(size_t)r * 32 + o] = ns;

  float y2 = lane_ln(ns, o, nsg, nsb);
  __syncthreads();
  Us[rl][o] = y2;
  __syncthreads();
  float qv = qb[o];
#pragma unroll
  for (int c = 0; c < 32; ++c) qv = fmaf(Us[rl][c], qw[o * 32 + c], qv);
  qbuf[(size_t)r * 32 + o] = qv;
}

// ---------------- outputs ----------------------------------------------------

__global__ void k_attn_out(const float* __restrict__ attnt, const float* __restrict__ rsum,
                           float* __restrict__ out) {
  size_t idx = (size_t)blockIdx.x * 256 + threadIdx.x;
  out[O_ATTN + idx] = attnt[idx] / rsum[idx / HWp];
}

__global__ void k_slots_out(const float* __restrict__ slots, float* __restrict__ out) {
  int idx = blockIdx.x * 256 + threadIdx.x;
  if (idx < 9216) out[O_SLOTS + idx] = slots[idx];
}

__global__ __launch_bounds__(256) void k_final(float* __restrict__ out) {
  int b = blockIdx.y;
  int j = blockIdx.x * 256 + threadIdx.x;
  float r[9], ml[9];
#pragma unroll
  for (int s = 0; s < 9; ++s) {
    r[s]  = out[O_RECON + (size_t)(b * 9 + s) * HWp + j];
    ml[s] = out[O_MASK  + (size_t)(b * 9 + s) * HWp + j];
  }
  float mx = ml[0];
#pragma unroll
  for (int s = 1; s < 9; ++s) mx = fmaxf(mx, ml[s]);
  float sum = 0.f;
#pragma unroll
  for (int s = 0; s < 9; ++s) { ml[s] = __expf(ml[s] - mx); sum += ml[s]; }
  float inv = 1.f / sum;
  float comb = 0.f;
#pragma unroll
  for (int s = 0; s < 9; ++s) {
    float mk = ml[s] * inv;
    comb = fmaf(r[s], mk, comb);
    out[O_MASK + (size_t)(b * 9 + s) * HWp + j] = mk;
  }
  out[O_COMB + (size_t)b * HWp + j] = comb;
}

}  // namespace

// ---------------------------------------------------------------------------

extern "C" void kernel_launch(void* const* d_in, const int* in_sizes, int n_in,
                              void* d_out, int out_size, void* d_ws, size_t ws_size,
                              hipStream_t stream) {
  if (ws_size < W_TOTAL * sizeof(float)) return;

  const float* in_x       = (const float*)d_in[0];
  const float* slot_noise = (const float*)d_in[1];
  const float* enc_w1 = (const float*)d_in[2];   const float* enc_b1 = (const float*)d_in[3];
  const float* enc_w2 = (const float*)d_in[4];   const float* enc_b2 = (const float*)d_in[5];
  const float* enc_w3 = (const float*)d_in[6];   const float* enc_b3 = (const float*)d_in[7];
  const float* enc_w4 = (const float*)d_in[8];   const float* enc_b4 = (const float*)d_in[9];
  const float* pe_enc_w = (const float*)d_in[10]; const float* pe_enc_b = (const float*)d_in[11];
  const float* ln_enc_g = (const float*)d_in[12]; const float* ln_enc_b = (const float*)d_in[13];
  const float* mlp_w1 = (const float*)d_in[14];  const float* mlp_b1 = (const float*)d_in[15];
  const float* mlp_w2 = (const float*)d_in[16];  const float* mlp_b2 = (const float*)d_in[17];
  const float* slots_mu = (const float*)d_in[18]; const float* slots_sigma = (const float*)d_in[19];
  const float* ni_g = (const float*)d_in[20];    const float* ni_b = (const float*)d_in[21];
  const float* ns_g = (const float*)d_in[22];    const float* ns_b = (const float*)d_in[23];
  const float* q_w = (const float*)d_in[24];     const float* q_b = (const float*)d_in[25];
  const float* k_w = (const float*)d_in[26];     const float* k_b = (const float*)d_in[27];
  const float* v_w = (const float*)d_in[28];     const float* v_b = (const float*)d_in[29];
  const float* gru_wih = (const float*)d_in[30]; const float* gru_whh = (const float*)d_in[31];
  const float* gru_bih = (const float*)d_in[32]; const float* gru_bhh = (const float*)d_in[33];
  const float* res_ln_g = (const float*)d_in[34]; const float* res_ln_b = (const float*)d_in[35];
  const float* res_w1 = (const float*)d_in[36];  const float* res_b1 = (const float*)d_in[37];
  const float* res_w2 = (const float*)d_in[38];  const float* res_b2 = (const float*)d_in[39];
  const float* pe_dec_w = (const float*)d_in[40]; const float* pe_dec_b = (const float*)d_in[41];
  const float* dec_w1 = (const float*)d_in[42];  const float* dec_b1 = (const float*)d_in[43];
  const float* dec_w2 = (const float*)d_in[44];  const float* dec_b2 = (const float*)d_in[45];
  const float* dec_w3 = (const float*)d_in[46];  const float* dec_b3 = (const float*)d_in[47];
  const float* dec_w4 = (const float*)d_in[48];  const float* dec_b4 = (const float*)d_in[49];

  float* ws  = (float*)d_ws;
  float* out = (float*)d_out;
  ushort* wp  = (ushort*)(ws + W_WP);
  ushort* wpm = (ushort*)(ws + W_WPM);

  k_pe_maps<<<dim3(25), 256, 0, stream>>>(pe_enc_w, pe_enc_b, pe_dec_w, pe_dec_b,
                                          ws + W_PEENC, ws + W_PEDEC);

  const size_t WPSTR = 25 * 2 * 64 * 8;
  k_pack<<<dim3(25), 128, 0, stream>>>(enc_w2, wp + 0 * WPSTR, 0);
  k_pack<<<dim3(25), 128, 0, stream>>>(enc_w3, wp + 1 * WPSTR, 0);
  k_pack<<<dim3(25), 128, 0, stream>>>(enc_w4, wp + 2 * WPSTR, 0);
  k_pack<<<dim3(25), 128, 0, stream>>>(dec_w1, wp + 3 * WPSTR, 1);
  k_pack<<<dim3(25), 128, 0, stream>>>(dec_w2, wp + 4 * WPSTR, 1);
  k_pack<<<dim3(25), 128, 0, stream>>>(dec_w3, wp + 5 * WPSTR, 1);
  k_pack_mat<<<dim3(1), 128, 0, stream>>>(mlp_w1, wpm + 0 * 1024);
  k_pack_mat<<<dim3(1), 128, 0, stream>>>(mlp_w2, wpm + 1 * 1024);
  k_pack_mat<<<dim3(1), 128, 0, stream>>>(k_w,   wpm + 2 * 1024);
  k_pack_mat<<<dim3(1), 128, 0, stream>>>(v_w,   wpm + 3 * 1024);
  k_prep_tc<<<dim3(25), 1024, 0, stream>>>(dec_w1, ws + W_TC);

  ushort* base  = (ushort*)(ws + W_BASE);
  ushort* keys  = (ushort*)(ws + W_KEYS);
  ushort* vals  = (ushort*)(ws + W_VALS);
  float*  attnt = ws + W_POOL;
  ushort* E1    = (ushort*)(ws + W_POOL);
  ushort* E2    = (ushort*)(ws + W_POOL + 3276800);

  // base = convT1(pe_dec) + bias (1 img)
  k_conv_mfma<0, false><<<dim3(10, 1), 256, 0, stream>>>(
      ws + W_PEDEC, wp + 3 * WPSTR, dec_b1, base, nullptr, 0);

  // ---------------- encoder ----------------
  k_conv1<<<dim3(25, Bb), 256, 0, stream>>>(in_x, enc_w1, enc_b1, E1);
  k_conv_mfma<1, true><<<dim3(10, Bb), 256, 0, stream>>>(E1, wp + 0 * WPSTR, enc_b2, E2, nullptr, 0);
  k_conv_mfma<1, true><<<dim3(10, Bb), 256, 0, stream>>>(E2, wp + 1 * WPSTR, enc_b3, E1, nullptr, 0);
  k_conv_mfma<1, true><<<dim3(10, Bb), 256, 0, stream>>>(E1, wp + 2 * WPSTR, enc_b4, E2, nullptr, 0);

  k_hstats<<<dim3(25, Bb), 256, 0, stream>>>(E2, ws + W_PEENC, ws + W_LNPART);
  k_statsfin<<<dim3(1), 64, 0, stream>>>(ws + W_LNPART, ws + W_MEANR);
  k_lnmlpkv_mfma<<<dim3(25, Bb), 256, 0, stream>>>(E2, ws + W_PEENC, ws + W_MEANR,
                                                   ln_enc_g, ln_enc_b, wpm,
                                                   mlp_b1, mlp_b2, ni_g, ni_b,
                                                   k_b, v_b, keys, vals);

  // ---------------- slot attention ----------------
  k_init_q<<<dim3(36), 256, 0, stream>>>(slots_mu, slots_sigma, slot_noise,
                                         ns_g, ns_b, q_w, q_b, ws + W_SLOTS, ws + W_Q);
  for (int it = 0; it < 3; ++it) {
    if (it == 2)
      k_dots_upd<true><<<dim3(25, Bb), 256, 0, stream>>>(ws + W_Q, keys, vals, attnt,
                                                         ws + W_APART, ws + W_UP2);
    else
      k_dots_upd<false><<<dim3(25, Bb), 256, 0, stream>>>(ws + W_Q, keys, vals, attnt,
                                                          ws + W_APART, ws + W_UP2);
    k_gru_fused<<<dim3(36), 256, 0, stream>>>(ws + W_UP2, ws + W_APART,
                                              ws + W_SLOTS, ws + W_RSUM, ws + W_Q,
                                              gru_wih, gru_whh, gru_bih, gru_bhh,
                                              res_ln_g, res_ln_b, res_w1, res_b1,
                                              res_w2, res_b2, ns_g, ns_b, q_w, q_b);
  }
  k_attn_out<<<dim3(7200), 256, 0, stream>>>(attnt, ws + W_RSUM, out);
  k_slots_out<<<dim3(36), 256, 0, stream>>>(ws + W_SLOTS, out);

  k_ts<<<dim3(900), 256, 0, stream>>>(ws + W_TC, ws + W_SLOTS, ws + W_TS);

  // ---------------- decoder ----------------
  ushort* XA = (ushort*)(ws + W_POOL);
  ushort* XB = XA + (size_t)96 * 32 * HWp;
  for (int ch = 0; ch < 3; ++ch) {
    int n0 = ch * 96;
    k_conv_mfma<2, true><<<dim3(10, 96), 256, 0, stream>>>(base, wp + 4 * WPSTR, dec_b2, XA,
                                                           ws + W_TS, n0);
    k_conv_mfma<1, true><<<dim3(10, 96), 256, 0, stream>>>(XA, wp + 5 * WPSTR, dec_b3, XB,
                                                           nullptr, 0);
    k_conv4<<<dim3(25, 96), 256, 0, stream>>>(XB, dec_w4, dec_b4,
                                              out + O_RECON, out + O_MASK, n0);
  }

  k_final<<<dim3(25, Bb), 256, 0, stream>>>(out);
}

// Round 9
// 582.223 us; speedup vs baseline: 17.2380x; 1.0458x over previous
//
#include <hip/hip_runtime.h>
#include <cstddef>
#include <cstdint>

// ---------------------------------------------------------------------------
// STSN forward, v9: v8 with conv_mfma retiled to 16x16 (LDS 64.5->25.6 KB,
// occupancy 2->4+ blocks/CU). Accumulation order unchanged (bit-identical).
// B=32, H=W=80, C=32, S=9, ITERS=3
// ---------------------------------------------------------------------------

namespace {

constexpr int Bb  = 32;
constexpr int HWp = 6400;
constexpr float SCALEf = 0.17677669529663687f;  // 32^-0.5

// output section offsets (floats)
constexpr size_t O_COMB  = 0;
constexpr size_t O_RECON = 204800;
constexpr size_t O_MASK  = 2048000;
constexpr size_t O_SLOTS = 3891200;
constexpr size_t O_ATTN  = 3900416;

// workspace layout (float offsets)
constexpr size_t W_PEENC = 0;                 // 204800 [hw][c] fp32
constexpr size_t W_PEDEC = 204800;            // 204800 [c][hw] fp32
constexpr size_t W_BASE  = 409600;            // 102400 (bf16 [hw][c])
constexpr size_t W_TC    = 512000;            // 25600
constexpr size_t W_TS    = 537600;            // 230400
constexpr size_t W_WP    = 768000;            // 76800 (packed conv weights bf16)
constexpr size_t W_WPM   = 844800;            // 2048 (packed 32x32 matrices bf16)
constexpr size_t W_LNPART= 846848;            // 1600
constexpr size_t W_MEANR = 848448;            // 64
constexpr size_t W_Q     = 848512;            // 9216
constexpr size_t W_SLOTS = 857728;            // 9216
constexpr size_t W_APART = 866944;            // 7200
constexpr size_t W_RSUM  = 874144;            // 288
constexpr size_t W_UP2   = 874432;            // 230400
constexpr size_t W_KEYS  = 1104832;           // 3276800 (bf16 [b][hw][c])
constexpr size_t W_VALS  = 4381632;           // 3276800 (bf16)
constexpr size_t W_POOL  = 7658432;           // 21456896 floats available
constexpr size_t W_TOTAL = 29115328;          // 116.5 MB
// Pool aliasing: E1/E2 (encoder) | attnt (attention) | XA/XB (decoder)

typedef __attribute__((ext_vector_type(8))) short short8;
typedef __attribute__((ext_vector_type(4))) float f32x4;

__device__ __forceinline__ ushort f2bf(float f) {
  uint u = __builtin_bit_cast(uint, f);
  uint r = (u + 0x7fffu + ((u >> 16) & 1u)) >> 16;   // RNE
  return (ushort)r;
}
__device__ __forceinline__ float bf2f(ushort b) {
  uint u = ((uint)b) << 16;
  return __builtin_bit_cast(float, u);
}
__device__ __forceinline__ void unpk2(uint w, float& a, float& b) {
  a = __builtin_bit_cast(float, w << 16);
  b = __builtin_bit_cast(float, w & 0xffff0000u);
}

__device__ __forceinline__ float lane_ln(float v, int o, const float* __restrict__ g,
                                         const float* __restrict__ b) {
  float s = v;
#pragma unroll
  for (int m = 16; m >= 1; m >>= 1) s += __shfl_xor(s, m);
  float mean = s * (1.f / 32.f);
  float d = v - mean;
  float q = d * d;
#pragma unroll
  for (int m = 16; m >= 1; m >>= 1) q += __shfl_xor(q, m);
  float rstd = rsqrtf(q * (1.f / 32.f) + 1e-5f);
  return d * rstd * g[o] + b[o];
}

// ---------------- positional-embedding maps ---------------------------------

__global__ void k_pe_maps(const float* __restrict__ pew_e, const float* __restrict__ peb_e,
                          const float* __restrict__ pew_d, const float* __restrict__ peb_d,
                          float* __restrict__ pe_enc, float* __restrict__ pe_dec) {
  int hw = blockIdx.x * 256 + threadIdx.x;
  if (hw >= HWp) return;
  int y = hw / 80, x = hw % 80;
  float g0 = y * (1.f / 79.f), g1 = x * (1.f / 79.f);
  float g2 = 1.f - g0, g3 = 1.f - g1;
#pragma unroll
  for (int c = 0; c < 32; ++c) {
    pe_enc[(size_t)hw * 32 + c] = peb_e[c] + g0 * pew_e[c * 4] + g1 * pew_e[c * 4 + 1] +
                                  g2 * pew_e[c * 4 + 2] + g3 * pew_e[c * 4 + 3];
    pe_dec[(size_t)c * HWp + hw] = peb_d[c] + g0 * pew_d[c * 4] + g1 * pew_d[c * 4 + 1] +
                                   g2 * pew_d[c * 4 + 2] + g3 * pew_d[c * 4 + 3];
  }
}

// ---------------- weight packing -------------------------------------------

__global__ void k_pack(const float* __restrict__ w, ushort* __restrict__ dst, int trans) {
  int tap = blockIdx.x;
  int grp = threadIdx.x >> 6, lane = threadIdx.x & 63;
  int ky = tap / 5, kx = tap % 5;
  int m = grp * 16 + (lane & 15);
  int kb = (lane >> 4) * 8;
  ushort* o = dst + ((size_t)(tap * 2 + grp) * 64 + lane) * 8;
#pragma unroll
  for (int j = 0; j < 8; ++j) {
    int k = kb + j;
    float v = trans ? w[(size_t)k * 800 + m * 25 + (4 - ky) * 5 + (4 - kx)]
                    : w[(size_t)m * 800 + k * 25 + ky * 5 + kx];
    o[j] = f2bf(v);
  }
}

// pack a row-major [32][32] matrix (y = x @ W^T form, A[m=o][k=c]) into A-frags
__global__ void k_pack_mat(const float* __restrict__ w, ushort* __restrict__ dst) {
  int grp = threadIdx.x >> 6, lane = threadIdx.x & 63;   // 128 threads
  int m = grp * 16 + (lane & 15), kb = (lane >> 4) * 8;
  ushort* o = dst + ((size_t)(grp * 64 + lane)) * 8;
#pragma unroll
  for (int j = 0; j < 8; ++j) o[j] = f2bf(w[m * 32 + kb + j]);
}

// ---------------- Tc / Ts for algebraic decoder conv1 ------------------------

__global__ void k_prep_tc(const float* __restrict__ w, float* __restrict__ tc) {
  const int rep[5] = {0, 1, 40, 78, 79};
  int cls = blockIdx.x;
  int yc = cls / 5, xc = cls % 5;
  int ci = threadIdx.x >> 5, co = threadIdx.x & 31;
  int yr = rep[yc], xr = rep[xc];
  float s = 0.f;
#pragma unroll
  for (int ky = 0; ky < 5; ++ky) {
    if ((unsigned)(yr + ky - 2) >= 80u) continue;
#pragma unroll
    for (int kx = 0; kx < 5; ++kx) {
      if ((unsigned)(xr + kx - 2) >= 80u) continue;
      s += w[(size_t)ci * 800 + co * 25 + (4 - ky) * 5 + (4 - kx)];
    }
  }
  tc[(size_t)cls * 1024 + ci * 32 + co] = s;
}

__global__ void k_ts(const float* __restrict__ tc, const float* __restrict__ slots,
                     float* __restrict__ ts) {
  int idx = blockIdx.x * 256 + threadIdx.x;
  if (idx >= 288 * 800) return;
  int img = idx / 800, rem = idx % 800;
  int cls = rem >> 5, o = rem & 31;
  float s = 0.f;
#pragma unroll
  for (int ci = 0; ci < 32; ++ci)
    s += tc[(size_t)cls * 1024 + ci * 32 + o] * slots[(size_t)img * 32 + ci];
  ts[idx] = s;
}

// ---------------- MFMA conv (32->32, 5x5, pad 2), 16x16 tile -----------------
// MODE 0: fp32 channel-major input (base precompute). MODE 1: bf16 chlast.
// MODE 2: relu(base[hw][c] + ts[n0+img][cls(hw)][c]) fused dec1.
// Block: 256 thr, tile 16x16 px; LDS 20x20 halo x 32ch = 25.6 KB.
// Wave wv owns output rows wv*4..wv*4+3. Tap-major loop, (dy,dx) lexicographic
// per accumulator (bit-identical to v7/v8).

template <int MODE, bool RELU>
__global__ __launch_bounds__(256, 4) void k_conv_mfma(
    const void* __restrict__ in_, const ushort* __restrict__ wp,
    const float* __restrict__ bias, ushort* __restrict__ out_,
    const float* __restrict__ ts, int n0) {
  __shared__ int4 sm[1600];  // 20 rows * 20 px * 4 units of 16B
  const int n = blockIdx.y;
  const int ty = blockIdx.x / 5, tx = blockIdx.x % 5;
  const int t = threadIdx.x;

  for (int i = t; i < 1600; i += 256) {
    int u = i & 3, px = i >> 2;       // px 0..399
    int x = px % 20, r = px / 20;
    int gy = ty * 16 + r - 2, gx = tx * 16 + x - 2;
    int4 pk = {0, 0, 0, 0};
    if ((unsigned)gy < 80u && (unsigned)gx < 80u) {
      int hw = gy * 80 + gx;
      if constexpr (MODE == 0) {
        const float* fp = (const float*)in_;
        ushort bb[8];
#pragma unroll
        for (int j = 0; j < 8; ++j)
          bb[j] = f2bf(fp[(size_t)(u * 8 + j) * HWp + hw]);
        pk.x = (int)((uint)bb[0] | ((uint)bb[1] << 16));
        pk.y = (int)((uint)bb[2] | ((uint)bb[3] << 16));
        pk.z = (int)((uint)bb[4] | ((uint)bb[5] << 16));
        pk.w = (int)((uint)bb[6] | ((uint)bb[7] << 16));
      } else if constexpr (MODE == 1) {
        pk = *(const int4*)((const ushort*)in_ + ((size_t)n * HWp + hw) * 32 + u * 8);
      } else {
        int4 bp = *(const int4*)((const ushort*)in_ + (size_t)hw * 32 + u * 8);
        int yc = gy < 2 ? gy : (gy > 77 ? gy - 75 : 2);
        int xc = gx < 2 ? gx : (gx > 77 ? gx - 75 : 2);
        const float* tp = ts + ((size_t)(n0 + n) * 25 + (yc * 5 + xc)) * 32 + u * 8;
        float t0, t1;
        uint* pw = (uint*)&pk;
        const uint* bw = (const uint*)&bp;
#pragma unroll
        for (int h = 0; h < 4; ++h) {
          unpk2(bw[h], t0, t1);
          float f0 = fmaxf(t0 + tp[2 * h], 0.f);
          float f1 = fmaxf(t1 + tp[2 * h + 1], 0.f);
          pw[h] = (uint)f2bf(f0) | ((uint)f2bf(f1) << 16);
        }
      }
    }
    int up = u ^ ((x >> 1) & 3);
    sm[(r * 20 + x) * 4 + up] = pk;
  }
  __syncthreads();

  const int wv = t >> 6, lane = t & 63;
  const int l15 = lane & 15, lg = lane >> 4;
  const short8* smS = (const short8*)sm;

  f32x4 acc[4][2];
#pragma unroll
  for (int o = 0; o < 4; ++o)
#pragma unroll
    for (int c = 0; c < 2; ++c) acc[o][c] = f32x4{0.f, 0.f, 0.f, 0.f};

  const int xs = l15;   // dx added per-tap
#pragma unroll
  for (int dy = 0; dy < 5; ++dy) {
#pragma unroll
    for (int dx = 0; dx < 5; ++dx) {
      int tap = dy * 5 + dx;
      short8 A0 = *(const short8*)(wp + ((size_t)(tap * 2 + 0) * 64 + lane) * 8);
      short8 A1 = *(const short8*)(wp + ((size_t)(tap * 2 + 1) * 64 + lane) * 8);
      int xx = xs + dx;
      int us = lg ^ ((xx >> 1) & 3);
#pragma unroll
      for (int o = 0; o < 4; ++o) {
        int srow = wv * 4 + o + dy;
        short8 Bv = smS[(srow * 20 + xx) * 4 + us];
        acc[o][0] = __builtin_amdgcn_mfma_f32_16x16x32_bf16(A0, Bv, acc[o][0], 0, 0, 0);
        acc[o][1] = __builtin_amdgcn_mfma_f32_16x16x32_bf16(A1, Bv, acc[o][1], 0, 0, 0);
      }
    }
  }

  float bv[2][4];
#pragma unroll
  for (int cg = 0; cg < 2; ++cg)
#pragma unroll
    for (int q = 0; q < 4; ++q) bv[cg][q] = bias[cg * 16 + lg * 4 + q];
  const int ybase = ty * 16 + wv * 4, xbase = tx * 16 + l15;
#pragma unroll
  for (int o = 0; o < 4; ++o) {
    size_t px = (size_t)n * HWp + (ybase + o) * 80 + xbase;
#pragma unroll
    for (int cg = 0; cg < 2; ++cg) {
      f32x4 v = acc[o][cg];
      float o0 = v[0] + bv[cg][0], o1 = v[1] + bv[cg][1];
      float o2 = v[2] + bv[cg][2], o3 = v[3] + bv[cg][3];
      if (RELU) {
        o0 = fmaxf(o0, 0.f); o1 = fmaxf(o1, 0.f);
        o2 = fmaxf(o2, 0.f); o3 = fmaxf(o3, 0.f);
      }
      uint2 pk;
      pk.x = (uint)f2bf(o0) | ((uint)f2bf(o1) << 16);
      pk.y = (uint)f2bf(o2) | ((uint)f2bf(o3) << 16);
      *(uint2*)(out_ + px * 32 + cg * 16 + lg * 4) = pk;
    }
  }
}

// ---------------- encoder conv1 ----------------------------------------------

__global__ __launch_bounds__(256) void k_conv1(const float* __restrict__ in,
                                               const float* __restrict__ w,
                                               const float* __restrict__ b,
                                               ushort* __restrict__ out) {
  int hw = blockIdx.x * 256 + threadIdx.x;
  int n = blockIdx.y;
  int y = hw / 80, x = hw % 80;
  float xv[25];
#pragma unroll
  for (int ky = 0; ky < 5; ++ky)
#pragma unroll
    for (int kx = 0; kx < 5; ++kx) {
      int iy = y + ky - 2, ix = x + kx - 2;
      xv[ky * 5 + kx] = ((unsigned)iy < 80u && (unsigned)ix < 80u)
                            ? in[(size_t)n * HWp + iy * 80 + ix] : 0.f;
    }
  float a[32];
#pragma unroll
  for (int co = 0; co < 32; ++co) {
    float s = b[co];
#pragma unroll
    for (int tp = 0; tp < 25; ++tp) s = fmaf(xv[tp], w[co * 25 + tp], s);
    a[co] = fmaxf(s, 0.f);
  }
  ushort* op = out + ((size_t)n * HWp + hw) * 32;
#pragma unroll
  for (int g = 0; g < 4; ++g) {
    uint4 pk;
    pk.x = (uint)f2bf(a[g * 8 + 0]) | ((uint)f2bf(a[g * 8 + 1]) << 16);
    pk.y = (uint)f2bf(a[g * 8 + 2]) | ((uint)f2bf(a[g * 8 + 3]) << 16);
    pk.z = (uint)f2bf(a[g * 8 + 4]) | ((uint)f2bf(a[g * 8 + 5]) << 16);
    pk.w = (uint)f2bf(a[g * 8 + 6]) | ((uint)f2bf(a[g * 8 + 7]) << 16);
    *(uint4*)(op + g * 8) = pk;
  }
}

// ---------------- decoder conv4 (32->2, 3x3, trans) --------------------------

__global__ __launch_bounds__(256) void k_conv4(const ushort* __restrict__ in,
                                               const float* __restrict__ w,
                                               const float* __restrict__ b,
                                               float* __restrict__ outR,
                                               float* __restrict__ outM, int n0) {
  __shared__ float sw[2 * 288];
  for (int e = threadIdx.x; e < 576; e += 256) {
    int co = e / 288, rem = e % 288;
    int tap = rem / 32, ci = rem % 32;
    sw[e] = w[(size_t)(ci * 2 + co) * 9 + 8 - tap];
  }
  __syncthreads();
  int hw = blockIdx.x * 256 + threadIdx.x;
  int nl = blockIdx.y;
  int y = hw / 80, x = hw % 80;
  float a0 = b[0], a1 = b[1];
  const ushort* ip = in + (size_t)nl * HWp * 32;
#pragma unroll
  for (int ky = 0; ky < 3; ++ky) {
#pragma unroll
    for (int kx = 0; kx < 3; ++kx) {
      int iy = y + ky - 1, ix = x + kx - 1;
      if ((unsigned)iy >= 80u || (unsigned)ix >= 80u) continue;
      int tap = ky * 3 + kx;
      const int4* p = (const int4*)(ip + (size_t)(iy * 80 + ix) * 32);
      const float* w0 = sw + tap * 32;
      const float* w1 = sw + 288 + tap * 32;
#pragma unroll
      for (int u = 0; u < 4; ++u) {
        int4 ch = p[u];
        const uint* cw = (const uint*)&ch;
#pragma unroll
        for (int h = 0; h < 4; ++h) {
          float v0, v1;
          unpk2(cw[h], v0, v1);
          int ci = u * 8 + h * 2;
          a0 = fmaf(v0, w0[ci], a0);     a1 = fmaf(v0, w1[ci], a1);
          a0 = fmaf(v1, w0[ci + 1], a0); a1 = fmaf(v1, w1[ci + 1], a1);
        }
      }
    }
  }
  outR[(size_t)(n0 + nl) * HWp + hw] = a0;
  outM[(size_t)(n0 + nl) * HWp + hw] = a1;
}

// ---------------- big-LN stats from E2+PE ------------------------------------

__global__ __launch_bounds__(256) void k_hstats(const ushort* __restrict__ enc,
                                                const float* __restrict__ pe_enc,
                                                float* __restrict__ lnpart) {
  int b = blockIdx.y;
  int hw = blockIdx.x * 256 + threadIdx.x;
  const int4* ep = (const int4*)(enc + ((size_t)b * HWp + hw) * 32);
  float v[32];
#pragma unroll
  for (int u = 0; u < 4; ++u) {
    int4 ch = ep[u];
    const uint* cw = (const uint*)&ch;
#pragma unroll
    for (int h = 0; h < 4; ++h) unpk2(cw[h], v[u * 8 + h * 2], v[u * 8 + h * 2 + 1]);
  }
  float s = 0.f, ss = 0.f;
#pragma unroll
  for (int c = 0; c < 32; ++c) {
    v[c] += pe_enc[(size_t)hw * 32 + c];
    s += v[c]; ss += v[c] * v[c];
  }
  __shared__ float r1[256], r2[256];
  r1[threadIdx.x] = s; r2[threadIdx.x] = ss;
  __syncthreads();
  for (int off = 128; off > 0; off >>= 1) {
    if (threadIdx.x < off) { r1[threadIdx.x] += r1[threadIdx.x + off]; r2[threadIdx.x] += r2[threadIdx.x + off]; }
    __syncthreads();
  }
  if (threadIdx.x == 0) {
    lnpart[(size_t)(b * 25 + blockIdx.x) * 2] = r1[0];
    lnpart[(size_t)(b * 25 + blockIdx.x) * 2 + 1] = r2[0];
  }
}

__global__ void k_statsfin(const float* __restrict__ lnpart, float* __restrict__ meanr) {
  int b = threadIdx.x;
  if (b >= 32) return;
  float s = 0.f, ss = 0.f;
  for (int k = 0; k < 25; ++k) {
    s += lnpart[(size_t)(b * 25 + k) * 2];
    ss += lnpart[(size_t)(b * 25 + k) * 2 + 1];
  }
  float m = s * (1.f / 204800.f);
  float var = ss * (1.f / 204800.f) - m * m;
  meanr[b * 2] = m;
  meanr[b * 2 + 1] = rsqrtf(var + 1e-5f);
}

// ---------------- MFMA lnmlpkv ----------------------------------------------

__global__ __launch_bounds__(256) void k_lnmlpkv_mfma(
    const ushort* __restrict__ enc, const float* __restrict__ pe,
    const float* __restrict__ meanr,
    const float* __restrict__ g, const float* __restrict__ bb,
    const ushort* __restrict__ wm,
    const float* __restrict__ b1, const float* __restrict__ b2,
    const float* __restrict__ nig, const float* __restrict__ nib,
    const float* __restrict__ kb, const float* __restrict__ vb,
    ushort* __restrict__ keys, ushort* __restrict__ vals) {
  __shared__ ushort ls[256 * 32];   // 16 KB bounce buffer
  const int b = blockIdx.y, jb = blockIdx.x;
  const int t = threadIdx.x, wv = t >> 6, lane = t & 63;
  const int l15 = lane & 15, lg = lane >> 4;
  const int skey = l15 & 3;

  short8 A[4][2];
#pragma unroll
  for (int mt = 0; mt < 4; ++mt)
#pragma unroll
    for (int gr = 0; gr < 2; ++gr)
      A[mt][gr] = *(const short8*)(wm + ((size_t)(mt * 2 + gr) * 64 + lane) * 8);

  float4 b1v0 = *(const float4*)(b1 + lg * 4),  b1v1 = *(const float4*)(b1 + 16 + lg * 4);
  float4 b2v0 = *(const float4*)(b2 + lg * 4),  b2v1 = *(const float4*)(b2 + 16 + lg * 4);
  float4 ng0  = *(const float4*)(nig + lg * 4), ng1  = *(const float4*)(nig + 16 + lg * 4);
  float4 nb0  = *(const float4*)(nib + lg * 4), nb1  = *(const float4*)(nib + 16 + lg * 4);
  float4 kbv0 = *(const float4*)(kb + lg * 4),  kbv1 = *(const float4*)(kb + 16 + lg * 4);
  float4 vbv0 = *(const float4*)(vb + lg * 4),  vbv1 = *(const float4*)(vb + 16 + lg * 4);

  const float m_ = meanr[b * 2], rs_ = meanr[b * 2 + 1];

  short8 bx[4];
#pragma unroll
  for (int g2 = 0; g2 < 4; ++g2) {
    int pos = jb * 256 + wv * 64 + g2 * 16 + l15;
    int4 e = *(const int4*)(enc + ((size_t)b * HWp + pos) * 32 + lg * 8);
    float xv[8];
    const uint* ew = (const uint*)&e;
#pragma unroll
    for (int h = 0; h < 4; ++h) unpk2(ew[h], xv[2 * h], xv[2 * h + 1]);
    float4 p0 = *(const float4*)(pe + (size_t)pos * 32 + lg * 8);
    float4 p1 = *(const float4*)(pe + (size_t)pos * 32 + lg * 8 + 4);
    float4 g0 = *(const float4*)(g + (size_t)pos * 32 + lg * 8);
    float4 g1 = *(const float4*)(g + (size_t)pos * 32 + lg * 8 + 4);
    float4 q0 = *(const float4*)(bb + (size_t)pos * 32 + lg * 8);
    float4 q1 = *(const float4*)(bb + (size_t)pos * 32 + lg * 8 + 4);
    float pv[8] = {p0.x, p0.y, p0.z, p0.w, p1.x, p1.y, p1.z, p1.w};
    float gv[8] = {g0.x, g0.y, g0.z, g0.w, g1.x, g1.y, g1.z, g1.w};
    float qv[8] = {q0.x, q0.y, q0.z, q0.w, q1.x, q1.y, q1.z, q1.w};
    uint pk[4];
#pragma unroll
    for (int h = 0; h < 4; ++h) {
      float f0 = (xv[2 * h] + pv[2 * h] - m_) * rs_ * gv[2 * h] + qv[2 * h];
      float f1 = (xv[2 * h + 1] + pv[2 * h + 1] - m_) * rs_ * gv[2 * h + 1] + qv[2 * h + 1];
      pk[h] = (uint)f2bf(f0) | ((uint)f2bf(f1) << 16);
    }
    bx[g2] = __builtin_bit_cast(short8, *(int4*)pk);
  }

  auto lds_write = [&](int posl, int cg, const f32x4& v) {
    int u = cg * 2 + (lg >> 1);
    int us = u ^ skey;
    uint2 pk;
    pk.x = (uint)f2bf(v[0]) | ((uint)f2bf(v[1]) << 16);
    pk.y = (uint)f2bf(v[2]) | ((uint)f2bf(v[3]) << 16);
    *(uint2*)(ls + (size_t)posl * 32 + us * 8 + (lg & 1) * 4) = pk;
  };

#pragma unroll
  for (int g2 = 0; g2 < 4; ++g2) {
    int posl = wv * 64 + g2 * 16 + l15;
    f32x4 a0 = __builtin_amdgcn_mfma_f32_16x16x32_bf16(A[0][0], bx[g2], f32x4{0, 0, 0, 0}, 0, 0, 0);
    f32x4 a1 = __builtin_amdgcn_mfma_f32_16x16x32_bf16(A[0][1], bx[g2], f32x4{0, 0, 0, 0}, 0, 0, 0);
    f32x4 r0, r1;
#pragma unroll
    for (int q = 0; q < 4; ++q) {
      r0[q] = fmaxf(a0[q] + (&b1v0.x)[q], 0.f);
      r1[q] = fmaxf(a1[q] + (&b1v1.x)[q], 0.f);
    }
    lds_write(posl, 0, r0);
    lds_write(posl, 1, r1);
  }
  __syncthreads();
  short8 t0f[4];
#pragma unroll
  for (int g2 = 0; g2 < 4; ++g2) {
    int posl = wv * 64 + g2 * 16 + l15;
    t0f[g2] = *(const short8*)(ls + (size_t)posl * 32 + (lg ^ skey) * 8);
  }
  __syncthreads();

#pragma unroll
  for (int g2 = 0; g2 < 4; ++g2) {
    int posl = wv * 64 + g2 * 16 + l15;
    f32x4 c0 = __builtin_amdgcn_mfma_f32_16x16x32_bf16(A[1][0], t0f[g2], f32x4{0, 0, 0, 0}, 0, 0, 0);
    f32x4 c1 = __builtin_amdgcn_mfma_f32_16x16x32_bf16(A[1][1], t0f[g2], f32x4{0, 0, 0, 0}, 0, 0, 0);
#pragma unroll
    for (int q = 0; q < 4; ++q) { c0[q] += (&b2v0.x)[q]; c1[q] += (&b2v1.x)[q]; }
    float s = 0.f;
#pragma unroll
    for (int q = 0; q < 4; ++q) s += c0[q] + c1[q];
    s += __shfl_xor(s, 16); s += __shfl_xor(s, 32);
    float mean = s * (1.f / 32.f);
    float var = 0.f;
#pragma unroll
    for (int q = 0; q < 4; ++q) {
      float d0 = c0[q] - mean, d1 = c1[q] - mean;
      var += d0 * d0 + d1 * d1;
    }
    var += __shfl_xor(var, 16); var += __shfl_xor(var, 32);
    float rstd = rsqrtf(var * (1.f / 32.f) + 1e-5f);
    f32x4 y0, y1;
#pragma unroll
    for (int q = 0; q < 4; ++q) {
      y0[q] = (c0[q] - mean) * rstd * (&ng0.x)[q] + (&nb0.x)[q];
      y1[q] = (c1[q] - mean) * rstd * (&ng1.x)[q] + (&nb1.x)[q];
    }
    lds_write(posl, 0, y0);
    lds_write(posl, 1, y1);
  }
  __syncthreads();
  short8 xnf[4];
#pragma unroll
  for (int g2 = 0; g2 < 4; ++g2) {
    int posl = wv * 64 + g2 * 16 + l15;
    xnf[g2] = *(const short8*)(ls + (size_t)posl * 32 + (lg ^ skey) * 8);
  }

#pragma unroll
  for (int g2 = 0; g2 < 4; ++g2) {
    int pos = jb * 256 + wv * 64 + g2 * 16 + l15;
    size_t px = ((size_t)b * HWp + pos) * 32;
    f32x4 k0 = __builtin_amdgcn_mfma_f32_16x16x32_bf16(A[2][0], xnf[g2], f32x4{0, 0, 0, 0}, 0, 0, 0);
    f32x4 k1 = __builtin_amdgcn_mfma_f32_16x16x32_bf16(A[2][1], xnf[g2], f32x4{0, 0, 0, 0}, 0, 0, 0);
    f32x4 v0 = __builtin_amdgcn_mfma_f32_16x16x32_bf16(A[3][0], xnf[g2], f32x4{0, 0, 0, 0}, 0, 0, 0);
    f32x4 v1 = __builtin_amdgcn_mfma_f32_16x16x32_bf16(A[3][1], xnf[g2], f32x4{0, 0, 0, 0}, 0, 0, 0);
    uint2 pk;
    pk.x = (uint)f2bf(k0[0] + kbv0.x) | ((uint)f2bf(k0[1] + kbv0.y) << 16);
    pk.y = (uint)f2bf(k0[2] + kbv0.z) | ((uint)f2bf(k0[3] + kbv0.w) << 16);
    *(uint2*)(keys + px + lg * 4) = pk;
    pk.x = (uint)f2bf(k1[0] + kbv1.x) | ((uint)f2bf(k1[1] + kbv1.y) << 16);
    pk.y = (uint)f2bf(k1[2] + kbv1.z) | ((uint)f2bf(k1[3] + kbv1.w) << 16);
    *(uint2*)(keys + px + 16 + lg * 4) = pk;
    pk.x = (uint)f2bf(v0[0] + vbv0.x) | ((uint)f2bf(v0[1] + vbv0.y) << 16);
    pk.y = (uint)f2bf(v0[2] + vbv0.z) | ((uint)f2bf(v0[3] + vbv0.w) << 16);
    *(uint2*)(vals + px + lg * 4) = pk;
    pk.x = (uint)f2bf(v1[0] + vbv1.x) | ((uint)f2bf(v1[1] + vbv1.y) << 16);
    pk.y = (uint)f2bf(v1[2] + vbv1.z) | ((uint)f2bf(v1[3] + vbv1.w) << 16);
    *(uint2*)(vals + px + 16 + lg * 4) = pk;
  }
}

// ---------------- slot attention -------------------------------------------

__global__ __launch_bounds__(256) void k_init_q(
    const float* __restrict__ mu, const float* __restrict__ sig,
    const float* __restrict__ noise,
    const float* __restrict__ nsg, const float* __restrict__ nsb,
    const float* __restrict__ qw, const float* __restrict__ qb,
    float* __restrict__ slots, float* __restrict__ qbuf) {
  int rl = threadIdx.x >> 5, o = threadIdx.x & 31;
  int r = blockIdx.x * 8 + rl;
  float s = mu[o] + sig[o] * noise[(size_t)r * 32 + o];
  slots[(size_t)r * 32 + o] = s;
  float y = lane_ln(s, o, nsg, nsb);
  __shared__ float S[8][32];
  S[rl][o] = y;
  __syncthreads();
  float qv = qb[o];
#pragma unroll
  for (int c = 0; c < 32; ++c) qv = fmaf(S[rl][c], qw[o * 32 + c], qv);
  qbuf[(size_t)r * 32 + o] = qv;
}

template <bool LAST>
__global__ __launch_bounds__(256) void k_dots_upd(
    const float* __restrict__ qbuf, const ushort* __restrict__ keys,
    const ushort* __restrict__ vals, float* __restrict__ attnt,
    float* __restrict__ apart, float* __restrict__ up2) {
  int b = blockIdx.y, jb = blockIdx.x;
  int t = threadIdx.x;
  int j = jb * 256 + t;
  __shared__ float qs[288];
  __shared__ float aL[2304];
  __shared__ float wr[36];
  for (int e = t; e < 288; e += 256) qs[e] = qbuf[(size_t)b * 288 + e];
  __syncthreads();
  float k[32];
  const int4* kp = (const int4*)(keys + ((size_t)b * HWp + j) * 32);
#pragma unroll
  for (int u = 0; u < 4; ++u) {
    int4 ch = kp[u];
    const uint* cw = (const uint*)&ch;
#pragma unroll
    for (int h = 0; h < 4; ++h) unpk2(cw[h], k[u * 8 + h * 2], k[u * 8 + h * 2 + 1]);
  }
  float d[9];
#pragma unroll
  for (int i = 0; i < 9; ++i) {
    float a = 0.f;
#pragma unroll
    for (int c = 0; c < 32; ++c) a = fmaf(qs[i * 32 + c], k[c], a);
    d[i] = a * SCALEf;
  }
  float mx = d[0];
#pragma unroll
  for (int i = 1; i < 9; ++i) mx = fmaxf(mx, d[i]);
  float sum = 0.f;
#pragma unroll
  for (int i = 0; i < 9; ++i) { d[i] = __expf(d[i] - mx); sum += d[i]; }
  float inv = 1.f / sum;
  float a9[9];
#pragma unroll
  for (int i = 0; i < 9; ++i) {
    a9[i] = d[i] * inv + 1e-8f;
    if (LAST) attnt[((size_t)b * 9 + i) * HWp + j] = a9[i];
    aL[t * 9 + i] = a9[i];
  }
  int lane = t & 63, wid = t >> 6;
#pragma unroll
  for (int i = 0; i < 9; ++i) {
    float v = a9[i];
    for (int off = 32; off > 0; off >>= 1) v += __shfl_down(v, off);
    if (lane == 0) wr[wid * 9 + i] = v;
  }
  __syncthreads();
  if (t < 9)
    apart[(size_t)(b * 9 + t) * 25 + jb] = wr[t] + wr[9 + t] + wr[18 + t] + wr[27 + t];
  int c = t & 31, g = t >> 5;
  float acc[9];
#pragma unroll
  for (int i = 0; i < 9; ++i) acc[i] = 0.f;
  const ushort* vp = vals + ((size_t)b * HWp + jb * 256) * 32 + c;
  for (int jj = g; jj < 256; jj += 8) {
    float v = bf2f(vp[(size_t)jj * 32]);
#pragma unroll
    for (int i = 0; i < 9; ++i) acc[i] = fmaf(v, aL[jj * 9 + i], acc[i]);
  }
  __syncthreads();
#pragma unroll
  for (int i = 0; i < 9; ++i) aL[(i * 8 + g) * 32 + c] = acc[i];
  __syncthreads();
  for (int i = g; i < 9; i += 8) {
    float s = 0.f;
#pragma unroll
    for (int g2 = 0; g2 < 8; ++g2) s += aL[(i * 8 + g2) * 32 + c];
    up2[(((size_t)b * 25 + jb) * 9 + i) * 32 + c] = s;
  }
}

__global__ __launch_bounds__(256) void k_gru_fused(
    const float* __restrict__ up2, const float* __restrict__ apart,
    float* __restrict__ slots, float* __restrict__ rowsum, float* __restrict__ qbuf,
    const float* __restrict__ wih, const float* __restrict__ whh,
    const float* __restrict__ bih, const float* __restrict__ bhh,
    const float* __restrict__ rlg, const float* __restrict__ rlb,
    const float* __restrict__ rw1, const float* __restrict__ rb1,
    const float* __restrict__ rw2, const float* __restrict__ rb2,
    const float* __restrict__ nsg, const float* __restrict__ nsb,
    const float* __restrict__ qw, const float* __restrict__ qb) {
  int rl = threadIdx.x >> 5, o = threadIdx.x & 31;
  int r = blockIdx.x * 8 + rl;
  int b = r / 9, i = r - b * 9;

  float rs = 0.f;
#pragma unroll
  for (int k = 0; k < 25; ++k) rs += apart[(size_t)(b * 9 + i) * 25 + k];
  if (o == 0) rowsum[r] = rs;

  float uo = 0.f;
#pragma unroll
  for (int jc = 0; jc < 25; ++jc) uo += up2[(((size_t)b * 25 + jc) * 9 + i) * 32 + o];
  uo /= rs;
  float ho = slots[(size_t)r * 32 + o];

  __shared__ float Us[8][32], Hs[8][32];
  Us[rl][o] = uo; Hs[rl][o] = ho;
  __syncthreads();

  float xr = bih[o], xz = bih[32 + o], xc = bih[64 + o];
  float hr = bhh[o], hz = bhh[32 + o], hc = bhh[64 + o];
#pragma unroll
  for (int c = 0; c < 32; ++c) {
    float u = Us[rl][c], h = Hs[rl][c];
    xr = fmaf(u, wih[o * 32 + c], xr);          hr = fmaf(h, whh[o * 32 + c], hr);
    xz = fmaf(u, wih[(32 + o) * 32 + c], xz);   hz = fmaf(h, whh[(32 + o) * 32 + c], hz);
    xc = fmaf(u, wih[(64 + o) * 32 + c], xc);   hc = fmaf(h, whh[(64 + o) * 32 + c], hc);
  }
  float rr = 1.f / (1.f + __expf(-(xr + hr)));
  float zz = 1.f / (1.f + __expf(-(xz + hz)));
  float cand = tanhf(xc + rr * hc);
  float sm = (1.f - zz) * cand + zz * ho;

  float y = lane_ln(sm, o, rlg, rlb);
  __syncthreads();
  Us[rl][o] = y;
  __syncthreads();
  float t1 = rb1[o];
#pragma unroll
  for (int c = 0; c < 32; ++c) t1 = fmaf(Us[rl][c], rw1[o * 32 + c], t1);
  t1 = fmaxf(t1, 0.f);
  Hs[rl][o] = t1;
  __syncthreads();
  float res = rb2[o];
#pragma unroll
  for (int c = 0; c < 32; ++c) res = fmaf(Hs[rl][c], rw2[o * 32 + c], res);
  float ns = sm + res;
  slots[(size_t)r * 32 + o] = ns;

  float y2 = lane_ln(ns, o, nsg, nsb);
  __syncthreads();
  Us[rl][o] = y2;
  __syncthreads();
  float qv = qb[o];
#pragma unroll
  for (int c = 0; c < 32; ++c) qv = fmaf(Us[rl][c], qw[o * 32 + c], qv);
  qbuf[(size_t)r * 32 + o] = qv;
}

// ---------------- outputs ----------------------------------------------------

__global__ void k_attn_out(const float* __restrict__ attnt, const float* __restrict__ rsum,
                           float* __restrict__ out) {
  size_t idx = (size_t)blockIdx.x * 256 + threadIdx.x;
  out[O_ATTN + idx] = attnt[idx] / rsum[idx / HWp];
}

__global__ void k_slots_out(const float* __restrict__ slots, float* __restrict__ out) {
  int idx = blockIdx.x * 256 + threadIdx.x;
  if (idx < 9216) out[O_SLOTS + idx] = slots[idx];
}

__global__ __launch_bounds__(256) void k_final(float* __restrict__ out) {
  int b = blockIdx.y;
  int j = blockIdx.x * 256 + threadIdx.x;
  float r[9], ml[9];
#pragma unroll
  for (int s = 0; s < 9; ++s) {
    r[s]  = out[O_RECON + (size_t)(b * 9 + s) * HWp + j];
    ml[s] = out[O_MASK  + (size_t)(b * 9 + s) * HWp + j];
  }
  float mx = ml[0];
#pragma unroll
  for (int s = 1; s < 9; ++s) mx = fmaxf(mx, ml[s]);
  float sum = 0.f;
#pragma unroll
  for (int s = 0; s < 9; ++s) { ml[s] = __expf(ml[s] - mx); sum += ml[s]; }
  float inv = 1.f / sum;
  float comb = 0.f;
#pragma unroll
  for (int s = 0; s < 9; ++s) {
    float mk = ml[s] * inv;
    comb = fmaf(r[s], mk, comb);
    out[O_MASK + (size_t)(b * 9 + s) * HWp + j] = mk;
  }
  out[O_COMB + (size_t)b * HWp + j] = comb;
}

}  // namespace

// ---------------------------------------------------------------------------

extern "C" void kernel_launch(void* const* d_in, const int* in_sizes, int n_in,
                              void* d_out, int out_size, void* d_ws, size_t ws_size,
                              hipStream_t stream) {
  if (ws_size < W_TOTAL * sizeof(float)) return;

  const float* in_x       = (const float*)d_in[0];
  const float* slot_noise = (const float*)d_in[1];
  const float* enc_w1 = (const float*)d_in[2];   const float* enc_b1 = (const float*)d_in[3];
  const float* enc_w2 = (const float*)d_in[4];   const float* enc_b2 = (const float*)d_in[5];
  const float* enc_w3 = (const float*)d_in[6];   const float* enc_b3 = (const float*)d_in[7];
  const float* enc_w4 = (const float*)d_in[8];   const float* enc_b4 = (const float*)d_in[9];
  const float* pe_enc_w = (const float*)d_in[10]; const float* pe_enc_b = (const float*)d_in[11];
  const float* ln_enc_g = (const float*)d_in[12]; const float* ln_enc_b = (const float*)d_in[13];
  const float* mlp_w1 = (const float*)d_in[14];  const float* mlp_b1 = (const float*)d_in[15];
  const float* mlp_w2 = (const float*)d_in[16];  const float* mlp_b2 = (const float*)d_in[17];
  const float* slots_mu = (const float*)d_in[18]; const float* slots_sigma = (const float*)d_in[19];
  const float* ni_g = (const float*)d_in[20];    const float* ni_b = (const float*)d_in[21];
  const float* ns_g = (const float*)d_in[22];    const float* ns_b = (const float*)d_in[23];
  const float* q_w = (const float*)d_in[24];     const float* q_b = (const float*)d_in[25];
  const float* k_w = (const float*)d_in[26];     const float* k_b = (const float*)d_in[27];
  const float* v_w = (const float*)d_in[28];     const float* v_b = (const float*)d_in[29];
  const float* gru_wih = (const float*)d_in[30]; const float* gru_whh = (const float*)d_in[31];
  const float* gru_bih = (const float*)d_in[32]; const float* gru_bhh = (const float*)d_in[33];
  const float* res_ln_g = (const float*)d_in[34]; const float* res_ln_b = (const float*)d_in[35];
  const float* res_w1 = (const float*)d_in[36];  const float* res_b1 = (const float*)d_in[37];
  const float* res_w2 = (const float*)d_in[38];  const float* res_b2 = (const float*)d_in[39];
  const float* pe_dec_w = (const float*)d_in[40]; const float* pe_dec_b = (const float*)d_in[41];
  const float* dec_w1 = (const float*)d_in[42];  const float* dec_b1 = (const float*)d_in[43];
  const float* dec_w2 = (const float*)d_in[44];  const float* dec_b2 = (const float*)d_in[45];
  const float* dec_w3 = (const float*)d_in[46];  const float* dec_b3 = (const float*)d_in[47];
  const float* dec_w4 = (const float*)d_in[48];  const float* dec_b4 = (const float*)d_in[49];

  float* ws  = (float*)d_ws;
  float* out = (float*)d_out;
  ushort* wp  = (ushort*)(ws + W_WP);
  ushort* wpm = (ushort*)(ws + W_WPM);

  k_pe_maps<<<dim3(25), 256, 0, stream>>>(pe_enc_w, pe_enc_b, pe_dec_w, pe_dec_b,
                                          ws + W_PEENC, ws + W_PEDEC);

  const size_t WPSTR = 25 * 2 * 64 * 8;
  k_pack<<<dim3(25), 128, 0, stream>>>(enc_w2, wp + 0 * WPSTR, 0);
  k_pack<<<dim3(25), 128, 0, stream>>>(enc_w3, wp + 1 * WPSTR, 0);
  k_pack<<<dim3(25), 128, 0, stream>>>(enc_w4, wp + 2 * WPSTR, 0);
  k_pack<<<dim3(25), 128, 0, stream>>>(dec_w1, wp + 3 * WPSTR, 1);
  k_pack<<<dim3(25), 128, 0, stream>>>(dec_w2, wp + 4 * WPSTR, 1);
  k_pack<<<dim3(25), 128, 0, stream>>>(dec_w3, wp + 5 * WPSTR, 1);
  k_pack_mat<<<dim3(1), 128, 0, stream>>>(mlp_w1, wpm + 0 * 1024);
  k_pack_mat<<<dim3(1), 128, 0, stream>>>(mlp_w2, wpm + 1 * 1024);
  k_pack_mat<<<dim3(1), 128, 0, stream>>>(k_w,   wpm + 2 * 1024);
  k_pack_mat<<<dim3(1), 128, 0, stream>>>(v_w,   wpm + 3 * 1024);
  k_prep_tc<<<dim3(25), 1024, 0, stream>>>(dec_w1, ws + W_TC);

  ushort* base  = (ushort*)(ws + W_BASE);
  ushort* keys  = (ushort*)(ws + W_KEYS);
  ushort* vals  = (ushort*)(ws + W_VALS);
  float*  attnt = ws + W_POOL;
  ushort* E1    = (ushort*)(ws + W_POOL);
  ushort* E2    = (ushort*)(ws + W_POOL + 3276800);

  // base = convT1(pe_dec) + bias (1 img)
  k_conv_mfma<0, false><<<dim3(25, 1), 256, 0, stream>>>(
      ws + W_PEDEC, wp + 3 * WPSTR, dec_b1, base, nullptr, 0);

  // ---------------- encoder ----------------
  k_conv1<<<dim3(25, Bb), 256, 0, stream>>>(in_x, enc_w1, enc_b1, E1);
  k_conv_mfma<1, true><<<dim3(25, Bb), 256, 0, stream>>>(E1, wp + 0 * WPSTR, enc_b2, E2, nullptr, 0);
  k_conv_mfma<1, true><<<dim3(25, Bb), 256, 0, stream>>>(E2, wp + 1 * WPSTR, enc_b3, E1, nullptr, 0);
  k_conv_mfma<1, true><<<dim3(25, Bb), 256, 0, stream>>>(E1, wp + 2 * WPSTR, enc_b4, E2, nullptr, 0);

  k_hstats<<<dim3(25, Bb), 256, 0, stream>>>(E2, ws + W_PEENC, ws + W_LNPART);
  k_statsfin<<<dim3(1), 64, 0, stream>>>(ws + W_LNPART, ws + W_MEANR);
  k_lnmlpkv_mfma<<<dim3(25, Bb), 256, 0, stream>>>(E2, ws + W_PEENC, ws + W_MEANR,
                                                   ln_enc_g, ln_enc_b, wpm,
                                                   mlp_b1, mlp_b2, ni_g, ni_b,
                                                   k_b, v_b, keys, vals);

  // ---------------- slot attention ----------------
  k_init_q<<<dim3(36), 256, 0, stream>>>(slots_mu, slots_sigma, slot_noise,
                                         ns_g, ns_b, q_w, q_b, ws + W_SLOTS, ws + W_Q);
  for (int it = 0; it < 3; ++it) {
    if (it == 2)
      k_dots_upd<true><<<dim3(25, Bb), 256, 0, stream>>>(ws + W_Q, keys, vals, attnt,
                                                         ws + W_APART, ws + W_UP2);
    else
      k_dots_upd<false><<<dim3(25, Bb), 256, 0, stream>>>(ws + W_Q, keys, vals, attnt,
                                                          ws + W_APART, ws + W_UP2);
    k_gru_fused<<<dim3(36), 256, 0, stream>>>(ws + W_UP2, ws + W_APART,
                                              ws + W_SLOTS, ws + W_RSUM, ws + W_Q,
                                              gru_wih, gru_whh, gru_bih, gru_bhh,
                                              res_ln_g, res_ln_b, res_w1, res_b1,
                                              res_w2, res_b2, ns_g, ns_b, q_w, q_b);
  }
  k_attn_out<<<dim3(7200), 256, 0, stream>>>(attnt, ws + W_RSUM, out);
  k_slots_out<<<dim3(36), 256, 0, stream>>>(ws + W_SLOTS, out);

  k_ts<<<dim3(900), 256, 0, stream>>>(ws + W_TC, ws + W_SLOTS, ws + W_TS);

  // ---------------- decoder ----------------
  ushort* XA = (ushort*)(ws + W_POOL);
  ushort* XB = XA + (size_t)96 * 32 * HWp;
  for (int ch = 0; ch < 3; ++ch) {
    int n0 = ch * 96;
    k_conv_mfma<2, true><<<dim3(25, 96), 256, 0, stream>>>(base, wp + 4 * WPSTR, dec_b2, XA,
                                                           ws + W_TS, n0);
    k_conv_mfma<1, true><<<dim3(25, 96), 256, 0, stream>>>(XA, wp + 5 * WPSTR, dec_b3, XB,
                                                           nullptr, 0);
    k_conv4<<<dim3(25, 96), 256, 0, stream>>>(XB, dec_w4, dec_b4,
                                              out + O_RECON, out + O_MASK, n0);
  }

  k_final<<<dim3(25, Bb), 256, 0, stream>>>(out);
}

// Round 11
// 565.327 us; speedup vs baseline: 17.7532x; 1.0299x over previous
//
#include <hip/hip_runtime.h>
#include <cstddef>
#include <cstdint>

// ---------------------------------------------------------------------------
// STSN forward, v10b: v9 with conv_mfma inner loop restructured dx-outer:
// per-dx A-frag register cache (5 pairs) + 8-row sweep B reuse.
// B reads 100->40 per wave, A loads stay 50, MFMAs 200. (v10 resubmit after
// infra failure; r9 loop bound fixed 9->8, removes dead OOB-indexed read.)
// B=32, H=W=80, C=32, S=9, ITERS=3
// ---------------------------------------------------------------------------

namespace {

constexpr int Bb  = 32;
constexpr int HWp = 6400;
constexpr float SCALEf = 0.17677669529663687f;  // 32^-0.5

// output section offsets (floats)
constexpr size_t O_COMB  = 0;
constexpr size_t O_RECON = 204800;
constexpr size_t O_MASK  = 2048000;
constexpr size_t O_SLOTS = 3891200;
constexpr size_t O_ATTN  = 3900416;

// workspace layout (float offsets)
constexpr size_t W_PEENC = 0;                 // 204800 [hw][c] fp32
constexpr size_t W_PEDEC = 204800;            // 204800 [c][hw] fp32
constexpr size_t W_BASE  = 409600;            // 102400 (bf16 [hw][c])
constexpr size_t W_TC    = 512000;            // 25600
constexpr size_t W_TS    = 537600;            // 230400
constexpr size_t W_WP    = 768000;            // 76800 (packed conv weights bf16)
constexpr size_t W_WPM   = 844800;            // 2048 (packed 32x32 matrices bf16)
constexpr size_t W_LNPART= 846848;            // 1600
constexpr size_t W_MEANR = 848448;            // 64
constexpr size_t W_Q     = 848512;            // 9216
constexpr size_t W_SLOTS = 857728;            // 9216
constexpr size_t W_APART = 866944;            // 7200
constexpr size_t W_RSUM  = 874144;            // 288
constexpr size_t W_UP2   = 874432;            // 230400
constexpr size_t W_KEYS  = 1104832;           // 3276800 (bf16 [b][hw][c])
constexpr size_t W_VALS  = 4381632;           // 3276800 (bf16)
constexpr size_t W_POOL  = 7658432;           // 21456896 floats available
constexpr size_t W_TOTAL = 29115328;          // 116.5 MB
// Pool aliasing: E1/E2 (encoder) | attnt (attention) | XA/XB (decoder)

typedef __attribute__((ext_vector_type(8))) short short8;
typedef __attribute__((ext_vector_type(4))) float f32x4;

__device__ __forceinline__ ushort f2bf(float f) {
  uint u = __builtin_bit_cast(uint, f);
  uint r = (u + 0x7fffu + ((u >> 16) & 1u)) >> 16;   // RNE
  return (ushort)r;
}
__device__ __forceinline__ float bf2f(ushort b) {
  uint u = ((uint)b) << 16;
  return __builtin_bit_cast(float, u);
}
__device__ __forceinline__ void unpk2(uint w, float& a, float& b) {
  a = __builtin_bit_cast(float, w << 16);
  b = __builtin_bit_cast(float, w & 0xffff0000u);
}

__device__ __forceinline__ float lane_ln(float v, int o, const float* __restrict__ g,
                                         const float* __restrict__ b) {
  float s = v;
#pragma unroll
  for (int m = 16; m >= 1; m >>= 1) s += __shfl_xor(s, m);
  float mean = s * (1.f / 32.f);
  float d = v - mean;
  float q = d * d;
#pragma unroll
  for (int m = 16; m >= 1; m >>= 1) q += __shfl_xor(q, m);
  float rstd = rsqrtf(q * (1.f / 32.f) + 1e-5f);
  return d * rstd * g[o] + b[o];
}

// ---------------- positional-embedding maps ---------------------------------

__global__ void k_pe_maps(const float* __restrict__ pew_e, const float* __restrict__ peb_e,
                          const float* __restrict__ pew_d, const float* __restrict__ peb_d,
                          float* __restrict__ pe_enc, float* __restrict__ pe_dec) {
  int hw = blockIdx.x * 256 + threadIdx.x;
  if (hw >= HWp) return;
  int y = hw / 80, x = hw % 80;
  float g0 = y * (1.f / 79.f), g1 = x * (1.f / 79.f);
  float g2 = 1.f - g0, g3 = 1.f - g1;
#pragma unroll
  for (int c = 0; c < 32; ++c) {
    pe_enc[(size_t)hw * 32 + c] = peb_e[c] + g0 * pew_e[c * 4] + g1 * pew_e[c * 4 + 1] +
                                  g2 * pew_e[c * 4 + 2] + g3 * pew_e[c * 4 + 3];
    pe_dec[(size_t)c * HWp + hw] = peb_d[c] + g0 * pew_d[c * 4] + g1 * pew_d[c * 4 + 1] +
                                   g2 * pew_d[c * 4 + 2] + g3 * pew_d[c * 4 + 3];
  }
}

// ---------------- weight packing -------------------------------------------

__global__ void k_pack(const float* __restrict__ w, ushort* __restrict__ dst, int trans) {
  int tap = blockIdx.x;
  int grp = threadIdx.x >> 6, lane = threadIdx.x & 63;
  int ky = tap / 5, kx = tap % 5;
  int m = grp * 16 + (lane & 15);
  int kb = (lane >> 4) * 8;
  ushort* o = dst + ((size_t)(tap * 2 + grp) * 64 + lane) * 8;
#pragma unroll
  for (int j = 0; j < 8; ++j) {
    int k = kb + j;
    float v = trans ? w[(size_t)k * 800 + m * 25 + (4 - ky) * 5 + (4 - kx)]
                    : w[(size_t)m * 800 + k * 25 + ky * 5 + kx];
    o[j] = f2bf(v);
  }
}

// pack a row-major [32][32] matrix (y = x @ W^T form, A[m=o][k=c]) into A-frags
__global__ void k_pack_mat(const float* __restrict__ w, ushort* __restrict__ dst) {
  int grp = threadIdx.x >> 6, lane = threadIdx.x & 63;   // 128 threads
  int m = grp * 16 + (lane & 15), kb = (lane >> 4) * 8;
  ushort* o = dst + ((size_t)(grp * 64 + lane)) * 8;
#pragma unroll
  for (int j = 0; j < 8; ++j) o[j] = f2bf(w[m * 32 + kb + j]);
}

// ---------------- Tc / Ts for algebraic decoder conv1 ------------------------

__global__ void k_prep_tc(const float* __restrict__ w, float* __restrict__ tc) {
  const int rep[5] = {0, 1, 40, 78, 79};
  int cls = blockIdx.x;
  int yc = cls / 5, xc = cls % 5;
  int ci = threadIdx.x >> 5, co = threadIdx.x & 31;
  int yr = rep[yc], xr = rep[xc];
  float s = 0.f;
#pragma unroll
  for (int ky = 0; ky < 5; ++ky) {
    if ((unsigned)(yr + ky - 2) >= 80u) continue;
#pragma unroll
    for (int kx = 0; kx < 5; ++kx) {
      if ((unsigned)(xr + kx - 2) >= 80u) continue;
      s += w[(size_t)ci * 800 + co * 25 + (4 - ky) * 5 + (4 - kx)];
    }
  }
  tc[(size_t)cls * 1024 + ci * 32 + co] = s;
}

__global__ void k_ts(const float* __restrict__ tc, const float* __restrict__ slots,
                     float* __restrict__ ts) {
  int idx = blockIdx.x * 256 + threadIdx.x;
  if (idx >= 288 * 800) return;
  int img = idx / 800, rem = idx % 800;
  int cls = rem >> 5, o = rem & 31;
  float s = 0.f;
#pragma unroll
  for (int ci = 0; ci < 32; ++ci)
    s += tc[(size_t)cls * 1024 + ci * 32 + o] * slots[(size_t)img * 32 + ci];
  ts[idx] = s;
}

// ---------------- MFMA conv (32->32, 5x5, pad 2), 16x16 tile -----------------
// MODE 0: fp32 channel-major input (base precompute). MODE 1: bf16 chlast.
// MODE 2: relu(base[hw][c] + ts[n0+img][cls(hw)][c]) fused dec1.
// Block: 256 thr, tile 16x16 px; LDS 20x20 halo x 32ch = 25.6 KB.
// Compute: dx outer (A-frag column cached in 40 VGPRs), 8-row sweep inner —
// each B-frag LDS read feeds all valid (o, dy=r8-o) pairs. 40 B reads,
// 50 A loads, 200 MFMAs per wave.

template <int MODE, bool RELU>
__global__ __launch_bounds__(256, 4) void k_conv_mfma(
    const void* __restrict__ in_, const ushort* __restrict__ wp,
    const float* __restrict__ bias, ushort* __restrict__ out_,
    const float* __restrict__ ts, int n0) {
  __shared__ int4 sm[1600];  // 20 rows * 20 px * 4 units of 16B
  const int n = blockIdx.y;
  const int ty = blockIdx.x / 5, tx = blockIdx.x % 5;
  const int t = threadIdx.x;

  for (int i = t; i < 1600; i += 256) {
    int u = i & 3, px = i >> 2;       // px 0..399
    int x = px % 20, r = px / 20;
    int gy = ty * 16 + r - 2, gx = tx * 16 + x - 2;
    int4 pk = {0, 0, 0, 0};
    if ((unsigned)gy < 80u && (unsigned)gx < 80u) {
      int hw = gy * 80 + gx;
      if constexpr (MODE == 0) {
        const float* fp = (const float*)in_;
        ushort bb[8];
#pragma unroll
        for (int j = 0; j < 8; ++j)
          bb[j] = f2bf(fp[(size_t)(u * 8 + j) * HWp + hw]);
        pk.x = (int)((uint)bb[0] | ((uint)bb[1] << 16));
        pk.y = (int)((uint)bb[2] | ((uint)bb[3] << 16));
        pk.z = (int)((uint)bb[4] | ((uint)bb[5] << 16));
        pk.w = (int)((uint)bb[6] | ((uint)bb[7] << 16));
      } else if constexpr (MODE == 1) {
        pk = *(const int4*)((const ushort*)in_ + ((size_t)n * HWp + hw) * 32 + u * 8);
      } else {
        int4 bp = *(const int4*)((const ushort*)in_ + (size_t)hw * 32 + u * 8);
        int yc = gy < 2 ? gy : (gy > 77 ? gy - 75 : 2);
        int xc = gx < 2 ? gx : (gx > 77 ? gx - 75 : 2);
        const float* tp = ts + ((size_t)(n0 + n) * 25 + (yc * 5 + xc)) * 32 + u * 8;
        float t0, t1;
        uint* pw = (uint*)&pk;
        const uint* bw = (const uint*)&bp;
#pragma unroll
        for (int h = 0; h < 4; ++h) {
          unpk2(bw[h], t0, t1);
          float f0 = fmaxf(t0 + tp[2 * h], 0.f);
          float f1 = fmaxf(t1 + tp[2 * h + 1], 0.f);
          pw[h] = (uint)f2bf(f0) | ((uint)f2bf(f1) << 16);
        }
      }
    }
    int up = u ^ ((x >> 1) & 3);
    sm[(r * 20 + x) * 4 + up] = pk;
  }
  __syncthreads();

  const int wv = t >> 6, lane = t & 63;
  const int l15 = lane & 15, lg = lane >> 4;
  const short8* smS = (const short8*)sm;

  f32x4 acc[4][2];
#pragma unroll
  for (int o = 0; o < 4; ++o)
#pragma unroll
    for (int c = 0; c < 2; ++c) acc[o][c] = f32x4{0.f, 0.f, 0.f, 0.f};

#pragma unroll
  for (int dx = 0; dx < 5; ++dx) {
    // cache this dx-column's A-fragments (5 dy x 2 cg)
    short8 Adx[5][2];
#pragma unroll
    for (int dy = 0; dy < 5; ++dy) {
      int tap = dy * 5 + dx;
      Adx[dy][0] = *(const short8*)(wp + ((size_t)(tap * 2 + 0) * 64 + lane) * 8);
      Adx[dy][1] = *(const short8*)(wp + ((size_t)(tap * 2 + 1) * 64 + lane) * 8);
    }
    const int xx = l15 + dx;
    const int us = lg ^ ((xx >> 1) & 3);
#pragma unroll
    for (int r8 = 0; r8 < 8; ++r8) {   // r8 = o + dy, valid range 0..7
      short8 Bv = smS[((wv * 4 + r8) * 20 + xx) * 4 + us];
#pragma unroll
      for (int o = 0; o < 4; ++o) {
        int dy = r8 - o;
        if (dy < 0 || dy > 4) continue;
        acc[o][0] = __builtin_amdgcn_mfma_f32_16x16x32_bf16(Adx[dy][0], Bv, acc[o][0], 0, 0, 0);
        acc[o][1] = __builtin_amdgcn_mfma_f32_16x16x32_bf16(Adx[dy][1], Bv, acc[o][1], 0, 0, 0);
      }
    }
  }

  float bv[2][4];
#pragma unroll
  for (int cg = 0; cg < 2; ++cg)
#pragma unroll
    for (int q = 0; q < 4; ++q) bv[cg][q] = bias[cg * 16 + lg * 4 + q];
  const int ybase = ty * 16 + wv * 4, xbase = tx * 16 + l15;
#pragma unroll
  for (int o = 0; o < 4; ++o) {
    size_t px = (size_t)n * HWp + (ybase + o) * 80 + xbase;
#pragma unroll
    for (int cg = 0; cg < 2; ++cg) {
      f32x4 v = acc[o][cg];
      float o0 = v[0] + bv[cg][0], o1 = v[1] + bv[cg][1];
      float o2 = v[2] + bv[cg][2], o3 = v[3] + bv[cg][3];
      if (RELU) {
        o0 = fmaxf(o0, 0.f); o1 = fmaxf(o1, 0.f);
        o2 = fmaxf(o2, 0.f); o3 = fmaxf(o3, 0.f);
      }
      uint2 pk;
      pk.x = (uint)f2bf(o0) | ((uint)f2bf(o1) << 16);
      pk.y = (uint)f2bf(o2) | ((uint)f2bf(o3) << 16);
      *(uint2*)(out_ + px * 32 + cg * 16 + lg * 4) = pk;
    }
  }
}

// ---------------- encoder conv1 ----------------------------------------------

__global__ __launch_bounds__(256) void k_conv1(const float* __restrict__ in,
                                               const float* __restrict__ w,
                                               const float* __restrict__ b,
                                               ushort* __restrict__ out) {
  int hw = blockIdx.x * 256 + threadIdx.x;
  int n = blockIdx.y;
  int y = hw / 80, x = hw % 80;
  float xv[25];
#pragma unroll
  for (int ky = 0; ky < 5; ++ky)
#pragma unroll
    for (int kx = 0; kx < 5; ++kx) {
      int iy = y + ky - 2, ix = x + kx - 2;
      xv[ky * 5 + kx] = ((unsigned)iy < 80u && (unsigned)ix < 80u)
                            ? in[(size_t)n * HWp + iy * 80 + ix] : 0.f;
    }
  float a[32];
#pragma unroll
  for (int co = 0; co < 32; ++co) {
    float s = b[co];
#pragma unroll
    for (int tp = 0; tp < 25; ++tp) s = fmaf(xv[tp], w[co * 25 + tp], s);
    a[co] = fmaxf(s, 0.f);
  }
  ushort* op = out + ((size_t)n * HWp + hw) * 32;
#pragma unroll
  for (int g = 0; g < 4; ++g) {
    uint4 pk;
    pk.x = (uint)f2bf(a[g * 8 + 0]) | ((uint)f2bf(a[g * 8 + 1]) << 16);
    pk.y = (uint)f2bf(a[g * 8 + 2]) | ((uint)f2bf(a[g * 8 + 3]) << 16);
    pk.z = (uint)f2bf(a[g * 8 + 4]) | ((uint)f2bf(a[g * 8 + 5]) << 16);
    pk.w = (uint)f2bf(a[g * 8 + 6]) | ((uint)f2bf(a[g * 8 + 7]) << 16);
    *(uint4*)(op + g * 8) = pk;
  }
}

// ---------------- decoder conv4 (32->2, 3x3, trans) --------------------------

__global__ __launch_bounds__(256) void k_conv4(const ushort* __restrict__ in,
                                               const float* __restrict__ w,
                                               const float* __restrict__ b,
                                               float* __restrict__ outR,
                                               float* __restrict__ outM, int n0) {
  __shared__ float sw[2 * 288];
  for (int e = threadIdx.x; e < 576; e += 256) {
    int co = e / 288, rem = e % 288;
    int tap = rem / 32, ci = rem % 32;
    sw[e] = w[(size_t)(ci * 2 + co) * 9 + 8 - tap];
  }
  __syncthreads();
  int hw = blockIdx.x * 256 + threadIdx.x;
  int nl = blockIdx.y;
  int y = hw / 80, x = hw % 80;
  float a0 = b[0], a1 = b[1];
  const ushort* ip = in + (size_t)nl * HWp * 32;
#pragma unroll
  for (int ky = 0; ky < 3; ++ky) {
#pragma unroll
    for (int kx = 0; kx < 3; ++kx) {
      int iy = y + ky - 1, ix = x + kx - 1;
      if ((unsigned)iy >= 80u || (unsigned)ix >= 80u) continue;
      int tap = ky * 3 + kx;
      const int4* p = (const int4*)(ip + (size_t)(iy * 80 + ix) * 32);
      const float* w0 = sw + tap * 32;
      const float* w1 = sw + 288 + tap * 32;
#pragma unroll
      for (int u = 0; u < 4; ++u) {
        int4 ch = p[u];
        const uint* cw = (const uint*)&ch;
#pragma unroll
        for (int h = 0; h < 4; ++h) {
          float v0, v1;
          unpk2(cw[h], v0, v1);
          int ci = u * 8 + h * 2;
          a0 = fmaf(v0, w0[ci], a0);     a1 = fmaf(v0, w1[ci], a1);
          a0 = fmaf(v1, w0[ci + 1], a0); a1 = fmaf(v1, w1[ci + 1], a1);
        }
      }
    }
  }
  outR[(size_t)(n0 + nl) * HWp + hw] = a0;
  outM[(size_t)(n0 + nl) * HWp + hw] = a1;
}

// ---------------- big-LN stats from E2+PE ------------------------------------

__global__ __launch_bounds__(256) void k_hstats(const ushort* __restrict__ enc,
                                                const float* __restrict__ pe_enc,
                                                float* __restrict__ lnpart) {
  int b = blockIdx.y;
  int hw = blockIdx.x * 256 + threadIdx.x;
  const int4* ep = (const int4*)(enc + ((size_t)b * HWp + hw) * 32);
  float v[32];
#pragma unroll
  for (int u = 0; u < 4; ++u) {
    int4 ch = ep[u];
    const uint* cw = (const uint*)&ch;
#pragma unroll
    for (int h = 0; h < 4; ++h) unpk2(cw[h], v[u * 8 + h * 2], v[u * 8 + h * 2 + 1]);
  }
  float s = 0.f, ss = 0.f;
#pragma unroll
  for (int c = 0; c < 32; ++c) {
    v[c] += pe_enc[(size_t)hw * 32 + c];
    s += v[c]; ss += v[c] * v[c];
  }
  __shared__ float r1[256], r2[256];
  r1[threadIdx.x] = s; r2[threadIdx.x] = ss;
  __syncthreads();
  for (int off = 128; off > 0; off >>= 1) {
    if (threadIdx.x < off) { r1[threadIdx.x] += r1[threadIdx.x + off]; r2[threadIdx.x] += r2[threadIdx.x + off]; }
    __syncthreads();
  }
  if (threadIdx.x == 0) {
    lnpart[(size_t)(b * 25 + blockIdx.x) * 2] = r1[0];
    lnpart[(size_t)(b * 25 + blockIdx.x) * 2 + 1] = r2[0];
  }
}

__global__ void k_statsfin(const float* __restrict__ lnpart, float* __restrict__ meanr) {
  int b = threadIdx.x;
  if (b >= 32) return;
  float s = 0.f, ss = 0.f;
  for (int k = 0; k < 25; ++k) {
    s += lnpart[(size_t)(b * 25 + k) * 2];
    ss += lnpart[(size_t)(b * 25 + k) * 2 + 1];
  }
  float m = s * (1.f / 204800.f);
  float var = ss * (1.f / 204800.f) - m * m;
  meanr[b * 2] = m;
  meanr[b * 2 + 1] = rsqrtf(var + 1e-5f);
}

// ---------------- MFMA lnmlpkv ----------------------------------------------

__global__ __launch_bounds__(256) void k_lnmlpkv_mfma(
    const ushort* __restrict__ enc, const float* __restrict__ pe,
    const float* __restrict__ meanr,
    const float* __restrict__ g, const float* __restrict__ bb,
    const ushort* __restrict__ wm,
    const float* __restrict__ b1, const float* __restrict__ b2,
    const float* __restrict__ nig, const float* __restrict__ nib,
    const float* __restrict__ kb, const float* __restrict__ vb,
    ushort* __restrict__ keys, ushort* __restrict__ vals) {
  __shared__ ushort ls[256 * 32];   // 16 KB bounce buffer
  const int b = blockIdx.y, jb = blockIdx.x;
  const int t = threadIdx.x, wv = t >> 6, lane = t & 63;
  const int l15 = lane & 15, lg = lane >> 4;
  const int skey = l15 & 3;

  short8 A[4][2];
#pragma unroll
  for (int mt = 0; mt < 4; ++mt)
#pragma unroll
    for (int gr = 0; gr < 2; ++gr)
      A[mt][gr] = *(const short8*)(wm + ((size_t)(mt * 2 + gr) * 64 + lane) * 8);

  float4 b1v0 = *(const float4*)(b1 + lg * 4),  b1v1 = *(const float4*)(b1 + 16 + lg * 4);
  float4 b2v0 = *(const float4*)(b2 + lg * 4),  b2v1 = *(const float4*)(b2 + 16 + lg * 4);
  float4 ng0  = *(const float4*)(nig + lg * 4), ng1  = *(const float4*)(nig + 16 + lg * 4);
  float4 nb0  = *(const float4*)(nib + lg * 4), nb1  = *(const float4*)(nib + 16 + lg * 4);
  float4 kbv0 = *(const float4*)(kb + lg * 4),  kbv1 = *(const float4*)(kb + 16 + lg * 4);
  float4 vbv0 = *(const float4*)(vb + lg * 4),  vbv1 = *(const float4*)(vb + 16 + lg * 4);

  const float m_ = meanr[b * 2], rs_ = meanr[b * 2 + 1];

  short8 bx[4];
#pragma unroll
  for (int g2 = 0; g2 < 4; ++g2) {
    int pos = jb * 256 + wv * 64 + g2 * 16 + l15;
    int4 e = *(const int4*)(enc + ((size_t)b * HWp + pos) * 32 + lg * 8);
    float xv[8];
    const uint* ew = (const uint*)&e;
#pragma unroll
    for (int h = 0; h < 4; ++h) unpk2(ew[h], xv[2 * h], xv[2 * h + 1]);
    float4 p0 = *(const float4*)(pe + (size_t)pos * 32 + lg * 8);
    float4 p1 = *(const float4*)(pe + (size_t)pos * 32 + lg * 8 + 4);
    float4 g0 = *(const float4*)(g + (size_t)pos * 32 + lg * 8);
    float4 g1 = *(const float4*)(g + (size_t)pos * 32 + lg * 8 + 4);
    float4 q0 = *(const float4*)(bb + (size_t)pos * 32 + lg * 8);
    float4 q1 = *(const float4*)(bb + (size_t)pos * 32 + lg * 8 + 4);
    float pv[8] = {p0.x, p0.y, p0.z, p0.w, p1.x, p1.y, p1.z, p1.w};
    float gv[8] = {g0.x, g0.y, g0.z, g0.w, g1.x, g1.y, g1.z, g1.w};
    float qv[8] = {q0.x, q0.y, q0.z, q0.w, q1.x, q1.y, q1.z, q1.w};
    uint pk[4];
#pragma unroll
    for (int h = 0; h < 4; ++h) {
      float f0 = (xv[2 * h] + pv[2 * h] - m_) * rs_ * gv[2 * h] + qv[2 * h];
      float f1 = (xv[2 * h + 1] + pv[2 * h + 1] - m_) * rs_ * gv[2 * h + 1] + qv[2 * h + 1];
      pk[h] = (uint)f2bf(f0) | ((uint)f2bf(f1) << 16);
    }
    bx[g2] = __builtin_bit_cast(short8, *(int4*)pk);
  }

  auto lds_write = [&](int posl, int cg, const f32x4& v) {
    int u = cg * 2 + (lg >> 1);
    int us = u ^ skey;
    uint2 pk;
    pk.x = (uint)f2bf(v[0]) | ((uint)f2bf(v[1]) << 16);
    pk.y = (uint)f2bf(v[2]) | ((uint)f2bf(v[3]) << 16);
    *(uint2*)(ls + (size_t)posl * 32 + us * 8 + (lg & 1) * 4) = pk;
  };

#pragma unroll
  for (int g2 = 0; g2 < 4; ++g2) {
    int posl = wv * 64 + g2 * 16 + l15;
    f32x4 a0 = __builtin_amdgcn_mfma_f32_16x16x32_bf16(A[0][0], bx[g2], f32x4{0, 0, 0, 0}, 0, 0, 0);
    f32x4 a1 = __builtin_amdgcn_mfma_f32_16x16x32_bf16(A[0][1], bx[g2], f32x4{0, 0, 0, 0}, 0, 0, 0);
    f32x4 r0, r1;
#pragma unroll
    for (int q = 0; q < 4; ++q) {
      r0[q] = fmaxf(a0[q] + (&b1v0.x)[q], 0.f);
      r1[q] = fmaxf(a1[q] + (&b1v1.x)[q], 0.f);
    }
    lds_write(posl, 0, r0);
    lds_write(posl, 1, r1);
  }
  __syncthreads();
  short8 t0f[4];
#pragma unroll
  for (int g2 = 0; g2 < 4; ++g2) {
    int posl = wv * 64 + g2 * 16 + l15;
    t0f[g2] = *(const short8*)(ls + (size_t)posl * 32 + (lg ^ skey) * 8);
  }
  __syncthreads();

#pragma unroll
  for (int g2 = 0; g2 < 4; ++g2) {
    int posl = wv * 64 + g2 * 16 + l15;
    f32x4 c0 = __builtin_amdgcn_mfma_f32_16x16x32_bf16(A[1][0], t0f[g2], f32x4{0, 0, 0, 0}, 0, 0, 0);
    f32x4 c1 = __builtin_amdgcn_mfma_f32_16x16x32_bf16(A[1][1], t0f[g2], f32x4{0, 0, 0, 0}, 0, 0, 0);
#pragma unroll
    for (int q = 0; q < 4; ++q) { c0[q] += (&b2v0.x)[q]; c1[q] += (&b2v1.x)[q]; }
    float s = 0.f;
#pragma unroll
    for (int q = 0; q < 4; ++q) s += c0[q] + c1[q];
    s += __shfl_xor(s, 16); s += __shfl_xor(s, 32);
    float mean = s * (1.f / 32.f);
    float var = 0.f;
#pragma unroll
    for (int q = 0; q < 4; ++q) {
      float d0 = c0[q] - mean, d1 = c1[q] - mean;
      var += d0 * d0 + d1 * d1;
    }
    var += __shfl_xor(var, 16); var += __shfl_xor(var, 32);
    float rstd = rsqrtf(var * (1.f / 32.f) + 1e-5f);
    f32x4 y0, y1;
#pragma unroll
    for (int q = 0; q < 4; ++q) {
      y0[q] = (c0[q] - mean) * rstd * (&ng0.x)[q] + (&nb0.x)[q];
      y1[q] = (c1[q] - mean) * rstd * (&ng1.x)[q] + (&nb1.x)[q];
    }
    lds_write(posl, 0, y0);
    lds_write(posl, 1, y1);
  }
  __syncthreads();
  short8 xnf[4];
#pragma unroll
  for (int g2 = 0; g2 < 4; ++g2) {
    int posl = wv * 64 + g2 * 16 + l15;
    xnf[g2] = *(const short8*)(ls + (size_t)posl * 32 + (lg ^ skey) * 8);
  }

#pragma unroll
  for (int g2 = 0; g2 < 4; ++g2) {
    int pos = jb * 256 + wv * 64 + g2 * 16 + l15;
    size_t px = ((size_t)b * HWp + pos) * 32;
    f32x4 k0 = __builtin_amdgcn_mfma_f32_16x16x32_bf16(A[2][0], xnf[g2], f32x4{0, 0, 0, 0}, 0, 0, 0);
    f32x4 k1 = __builtin_amdgcn_mfma_f32_16x16x32_bf16(A[2][1], xnf[g2], f32x4{0, 0, 0, 0}, 0, 0, 0);
    f32x4 v0 = __builtin_amdgcn_mfma_f32_16x16x32_bf16(A[3][0], xnf[g2], f32x4{0, 0, 0, 0}, 0, 0, 0);
    f32x4 v1 = __builtin_amdgcn_mfma_f32_16x16x32_bf16(A[3][1], xnf[g2], f32x4{0, 0, 0, 0}, 0, 0, 0);
    uint2 pk;
    pk.x = (uint)f2bf(k0[0] + kbv0.x) | ((uint)f2bf(k0[1] + kbv0.y) << 16);
    pk.y = (uint)f2bf(k0[2] + kbv0.z) | ((uint)f2bf(k0[3] + kbv0.w) << 16);
    *(uint2*)(keys + px + lg * 4) = pk;
    pk.x = (uint)f2bf(k1[0] + kbv1.x) | ((uint)f2bf(k1[1] + kbv1.y) << 16);
    pk.y = (uint)f2bf(k1[2] + kbv1.z) | ((uint)f2bf(k1[3] + kbv1.w) << 16);
    *(uint2*)(keys + px + 16 + lg * 4) = pk;
    pk.x = (uint)f2bf(v0[0] + vbv0.x) | ((uint)f2bf(v0[1] + vbv0.y) << 16);
    pk.y = (uint)f2bf(v0[2] + vbv0.z) | ((uint)f2bf(v0[3] + vbv0.w) << 16);
    *(uint2*)(vals + px + lg * 4) = pk;
    pk.x = (uint)f2bf(v1[0] + vbv1.x) | ((uint)f2bf(v1[1] + vbv1.y) << 16);
    pk.y = (uint)f2bf(v1[2] + vbv1.z) | ((uint)f2bf(v1[3] + vbv1.w) << 16);
    *(uint2*)(vals + px + 16 + lg * 4) = pk;
  }
}

// ---------------- slot attention -------------------------------------------

__global__ __launch_bounds__(256) void k_init_q(
    const float* __restrict__ mu, const float* __restrict__ sig,
    const float* __restrict__ noise,
    const float* __restrict__ nsg, const float* __restrict__ nsb,
    const float* __restrict__ qw, const float* __restrict__ qb,
    float* __restrict__ slots, float* __restrict__ qbuf) {
  int rl = threadIdx.x >> 5, o = threadIdx.x & 31;
  int r = blockIdx.x * 8 + rl;
  float s = mu[o] + sig[o] * noise[(size_t)r * 32 + o];
  slots[(size_t)r * 32 + o] = s;
  float y = lane_ln(s, o, nsg, nsb);
  __shared__ float S[8][32];
  S[rl][o] = y;
  __syncthreads();
  float qv = qb[o];
#pragma unroll
  for (int c = 0; c < 32; ++c) qv = fmaf(S[rl][c], qw[o * 32 + c], qv);
  qbuf[(size_t)r * 32 + o] = qv;
}

template <bool LAST>
__global__ __launch_bounds__(256) void k_dots_upd(
    const float* __restrict__ qbuf, const ushort* __restrict__ keys,
    const ushort* __restrict__ vals, float* __restrict__ attnt,
    float* __restrict__ apart, float* __restrict__ up2) {
  int b = blockIdx.y, jb = blockIdx.x;
  int t = threadIdx.x;
  int j = jb * 256 + t;
  __shared__ float qs[288];
  __shared__ float aL[2304];
  __shared__ float wr[36];
  for (int e = t; e < 288; e += 256) qs[e] = qbuf[(size_t)b * 288 + e];
  __syncthreads();
  float k[32];
  const int4* kp = (const int4*)(keys + ((size_t)b * HWp + j) * 32);
#pragma unroll
  for (int u = 0; u < 4; ++u) {
    int4 ch = kp[u];
    const uint* cw = (const uint*)&ch;
#pragma unroll
    for (int h = 0; h < 4; ++h) unpk2(cw[h], k[u * 8 + h * 2], k[u * 8 + h * 2 + 1]);
  }
  float d[9];
#pragma unroll
  for (int i = 0; i < 9; ++i) {
    float a = 0.f;
#pragma unroll
    for (int c = 0; c < 32; ++c) a = fmaf(qs[i * 32 + c], k[c], a);
    d[i] = a * SCALEf;
  }
  float mx = d[0];
#pragma unroll
  for (int i = 1; i < 9; ++i) mx = fmaxf(mx, d[i]);
  float sum = 0.f;
#pragma unroll
  for (int i = 0; i < 9; ++i) { d[i] = __expf(d[i] - mx); sum += d[i]; }
  float inv = 1.f / sum;
  float a9[9];
#pragma unroll
  for (int i = 0; i < 9; ++i) {
    a9[i] = d[i] * inv + 1e-8f;
    if (LAST) attnt[((size_t)b * 9 + i) * HWp + j] = a9[i];
    aL[t * 9 + i] = a9[i];
  }
  int lane = t & 63, wid = t >> 6;
#pragma unroll
  for (int i = 0; i < 9; ++i) {
    float v = a9[i];
    for (int off = 32; off > 0; off >>= 1) v += __shfl_down(v, off);
    if (lane == 0) wr[wid * 9 + i] = v;
  }
  __syncthreads();
  if (t < 9)
    apart[(size_t)(b * 9 + t) * 25 + jb] = wr[t] + wr[9 + t] + wr[18 + t] + wr[27 + t];
  int c = t & 31, g = t >> 5;
  float acc[9];
#pragma unroll
  for (int i = 0; i < 9; ++i) acc[i] = 0.f;
  const ushort* vp = vals + ((size_t)b * HWp + jb * 256) * 32 + c;
  for (int jj = g; jj < 256; jj += 8) {
    float v = bf2f(vp[(size_t)jj * 32]);
#pragma unroll
    for (int i = 0; i < 9; ++i) acc[i] = fmaf(v, aL[jj * 9 + i], acc[i]);
  }
  __syncthreads();
#pragma unroll
  for (int i = 0; i < 9; ++i) aL[(i * 8 + g) * 32 + c] = acc[i];
  __syncthreads();
  for (int i = g; i < 9; i += 8) {
    float s = 0.f;
#pragma unroll
    for (int g2 = 0; g2 < 8; ++g2) s += aL[(i * 8 + g2) * 32 + c];
    up2[(((size_t)b * 25 + jb) * 9 + i) * 32 + c] = s;
  }
}

__global__ __launch_bounds__(256) void k_gru_fused(
    const float* __restrict__ up2, const float* __restrict__ apart,
    float* __restrict__ slots, float* __restrict__ rowsum, float* __restrict__ qbuf,
    const float* __restrict__ wih, const float* __restrict__ whh,
    const float* __restrict__ bih, const float* __restrict__ bhh,
    const float* __restrict__ rlg, const float* __restrict__ rlb,
    const float* __restrict__ rw1, const float* __restrict__ rb1,
    const float* __restrict__ rw2, const float* __restrict__ rb2,
    const float* __restrict__ nsg, const float* __restrict__ nsb,
    const float* __restrict__ qw, const float* __restrict__ qb) {
  int rl = threadIdx.x >> 5, o = threadIdx.x & 31;
  int r = blockIdx.x * 8 + rl;
  int b = r / 9, i = r - b * 9;

  float rs = 0.f;
#pragma unroll
  for (int k = 0; k < 25; ++k) rs += apart[(size_t)(b * 9 + i) * 25 + k];
  if (o == 0) rowsum[r] = rs;

  float uo = 0.f;
#pragma unroll
  for (int jc = 0; jc < 25; ++jc) uo += up2[(((size_t)b * 25 + jc) * 9 + i) * 32 + o];
  uo /= rs;
  float ho = slots[(size_t)r * 32 + o];

  __shared__ float Us[8][32], Hs[8][32];
  Us[rl][o] = uo; Hs[rl][o] = ho;
  __syncthreads();

  float xr = bih[o], xz = bih[32 + o], xc = bih[64 + o];
  float hr = bhh[o], hz = bhh[32 + o], hc = bhh[64 + o];
#pragma unroll
  for (int c = 0; c < 32; ++c) {
    float u = Us[rl][c], h = Hs[rl][c];
    xr = fmaf(u, wih[o * 32 + c], xr);          hr = fmaf(h, whh[o * 32 + c], hr);
    xz = fmaf(u, wih[(32 + o) * 32 + c], xz);   hz = fmaf(h, whh[(32 + o) * 32 + c], hz);
    xc = fmaf(u, wih[(64 + o) * 32 + c], xc);   hc = fmaf(h, whh[(64 + o) * 32 + c], hc);
  }
  float rr = 1.f / (1.f + __expf(-(xr + hr)));
  float zz = 1.f / (1.f + __expf(-(xz + hz)));
  float cand = tanhf(xc + rr * hc);
  float sm = (1.f - zz) * cand + zz * ho;

  float y = lane_ln(sm, o, rlg, rlb);
  __syncthreads();
  Us[rl][o] = y;
  __syncthreads();
  float t1 = rb1[o];
#pragma unroll
  for (int c = 0; c < 32; ++c) t1 = fmaf(Us[rl][c], rw1[o * 32 + c], t1);
  t1 = fmaxf(t1, 0.f);
  Hs[rl][o] = t1;
  __syncthreads();
  float res = rb2[o];
#pragma unroll
  for (int c = 0; c < 32; ++c) res = fmaf(Hs[rl][c], rw2[o * 32 + c], res);
  float ns = sm + res;
  slots[(size_t)r * 32 + o] = ns;

  float y2 = lane_ln(ns, o, nsg, nsb);
  __syncthreads();
  Us[rl][o] = y2;
  __syncthreads();
  float qv = qb[o];
#pragma unroll
  for (int c = 0; c < 32; ++c) qv = fmaf(Us[rl][c], qw[o * 32 + c], qv);
  qbuf[(size_t)r * 32 + o] = qv;
}

// ---------------- outputs ----------------------------------------------------

__global__ void k_attn_out(const float* __restrict__ attnt, const float* __restrict__ rsum,
                           float* __restrict__ out) {
  size_t idx = (size_t)blockIdx.x * 256 + threadIdx.x;
  out[O_ATTN + idx] = attnt[idx] / rsum[idx / HWp];
}

__global__ void k_slots_out(const float* __restrict__ slots, float* __restrict__ out) {
  int idx = blockIdx.x * 256 + threadIdx.x;
  if (idx < 9216) out[O_SLOTS + idx] = slots[idx];
}

__global__ __launch_bounds__(256) void k_final(float* __restrict__ out) {
  int b = blockIdx.y;
  int j = blockIdx.x * 256 + threadIdx.x;
  float r[9], ml[9];
#pragma unroll
  for (int s = 0; s < 9; ++s) {
    r[s]  = out[O_RECON + (size_t)(b * 9 + s) * HWp + j];
    ml[s] = out[O_MASK  + (size_t)(b * 9 + s) * HWp + j];
  }
  float mx = ml[0];
#pragma unroll
  for (int s = 1; s < 9; ++s) mx = fmaxf(mx, ml[s]);
  float sum = 0.f;
#pragma unroll
  for (int s = 0; s < 9; ++s) { ml[s] = __expf(ml[s] - mx); sum += ml[s]; }
  float inv = 1.f / sum;
  float comb = 0.f;
#pragma unroll
  for (int s = 0; s < 9; ++s) {
    float mk = ml[s] * inv;
    comb = fmaf(r[s], mk, comb);
    out[O_MASK + (size_t)(b * 9 + s) * HWp + j] = mk;
  }
  out[O_COMB + (size_t)b * HWp + j] = comb;
}

}  // namespace

// ---------------------------------------------------------------------------

extern "C" void kernel_launch(void* const* d_in, const int* in_sizes, int n_in,
                              void* d_out, int out_size, void* d_ws, size_t ws_size,
                              hipStream_t stream) {
  if (ws_size < W_TOTAL * sizeof(float)) return;

  const float* in_x       = (const float*)d_in[0];
  const float* slot_noise = (const float*)d_in[1];
  const float* enc_w1 = (const float*)d_in[2];   const float* enc_b1 = (const float*)d_in[3];
  const float* enc_w2 = (const float*)d_in[4];   const float* enc_b2 = (const float*)d_in[5];
  const float* enc_w3 = (const float*)d_in[6];   const float* enc_b3 = (const float*)d_in[7];
  const float* enc_w4 = (const float*)d_in[8];   const float* enc_b4 = (const float*)d_in[9];
  const float* pe_enc_w = (const float*)d_in[10]; const float* pe_enc_b = (const float*)d_in[11];
  const float* ln_enc_g = (const float*)d_in[12]; const float* ln_enc_b = (const float*)d_in[13];
  const float* mlp_w1 = (const float*)d_in[14];  const float* mlp_b1 = (const float*)d_in[15];
  const float* mlp_w2 = (const float*)d_in[16];  const float* mlp_b2 = (const float*)d_in[17];
  const float* slots_mu = (const float*)d_in[18]; const float* slots_sigma = (const float*)d_in[19];
  const float* ni_g = (const float*)d_in[20];    const float* ni_b = (const float*)d_in[21];
  const float* ns_g = (const float*)d_in[22];    const float* ns_b = (const float*)d_in[23];
  const float* q_w = (const float*)d_in[24];     const float* q_b = (const float*)d_in[25];
  const float* k_w = (const float*)d_in[26];     const float* k_b = (const float*)d_in[27];
  const float* v_w = (const float*)d_in[28];     const float* v_b = (const float*)d_in[29];
  const float* gru_wih = (const float*)d_in[30]; const float* gru_whh = (const float*)d_in[31];
  const float* gru_bih = (const float*)d_in[32]; const float* gru_bhh = (const float*)d_in[33];
  const float* res_ln_g = (const float*)d_in[34]; const float* res_ln_b = (const float*)d_in[35];
  const float* res_w1 = (const float*)d_in[36];  const float* res_b1 = (const float*)d_in[37];
  const float* res_w2 = (const float*)d_in[38];  const float* res_b2 = (const float*)d_in[39];
  const float* pe_dec_w = (const float*)d_in[40]; const float* pe_dec_b = (const float*)d_in[41];
  const float* dec_w1 = (const float*)d_in[42];  const float* dec_b1 = (const float*)d_in[43];
  const float* dec_w2 = (const float*)d_in[44];  const float* dec_b2 = (const float*)d_in[45];
  const float* dec_w3 = (const float*)d_in[46];  const float* dec_b3 = (const float*)d_in[47];
  const float* dec_w4 = (const float*)d_in[48];  const float* dec_b4 = (const float*)d_in[49];

  float* ws  = (float*)d_ws;
  float* out = (float*)d_out;
  ushort* wp  = (ushort*)(ws + W_WP);
  ushort* wpm = (ushort*)(ws + W_WPM);

  k_pe_maps<<<dim3(25), 256, 0, stream>>>(pe_enc_w, pe_enc_b, pe_dec_w, pe_dec_b,
                                          ws + W_PEENC, ws + W_PEDEC);

  const size_t WPSTR = 25 * 2 * 64 * 8;
  k_pack<<<dim3(25), 128, 0, stream>>>(enc_w2, wp + 0 * WPSTR, 0);
  k_pack<<<dim3(25), 128, 0, stream>>>(enc_w3, wp + 1 * WPSTR, 0);
  k_pack<<<dim3(25), 128, 0, stream>>>(enc_w4, wp + 2 * WPSTR, 0);
  k_pack<<<dim3(25), 128, 0, stream>>>(dec_w1, wp + 3 * WPSTR, 1);
  k_pack<<<dim3(25), 128, 0, stream>>>(dec_w2, wp + 4 * WPSTR, 1);
  k_pack<<<dim3(25), 128, 0, stream>>>(dec_w3, wp + 5 * WPSTR, 1);
  k_pack_mat<<<dim3(1), 128, 0, stream>>>(mlp_w1, wpm + 0 * 1024);
  k_pack_mat<<<dim3(1), 128, 0, stream>>>(mlp_w2, wpm + 1 * 1024);
  k_pack_mat<<<dim3(1), 128, 0, stream>>>(k_w,   wpm + 2 * 1024);
  k_pack_mat<<<dim3(1), 128, 0, stream>>>(v_w,   wpm + 3 * 1024);
  k_prep_tc<<<dim3(25), 1024, 0, stream>>>(dec_w1, ws + W_TC);

  ushort* base  = (ushort*)(ws + W_BASE);
  ushort* keys  = (ushort*)(ws + W_KEYS);
  ushort* vals  = (ushort*)(ws + W_VALS);
  float*  attnt = ws + W_POOL;
  ushort* E1    = (ushort*)(ws + W_POOL);
  ushort* E2    = (ushort*)(ws + W_POOL + 3276800);

  // base = convT1(pe_dec) + bias (1 img)
  k_conv_mfma<0, false><<<dim3(25, 1), 256, 0, stream>>>(
      ws + W_PEDEC, wp + 3 * WPSTR, dec_b1, base, nullptr, 0);

  // ---------------- encoder ----------------
  k_conv1<<<dim3(25, Bb), 256, 0, stream>>>(in_x, enc_w1, enc_b1, E1);
  k_conv_mfma<1, true><<<dim3(25, Bb), 256, 0, stream>>>(E1, wp + 0 * WPSTR, enc_b2, E2, nullptr, 0);
  k_conv_mfma<1, true><<<dim3(25, Bb), 256, 0, stream>>>(E2, wp + 1 * WPSTR, enc_b3, E1, nullptr, 0);
  k_conv_mfma<1, true><<<dim3(25, Bb), 256, 0, stream>>>(E1, wp + 2 * WPSTR, enc_b4, E2, nullptr, 0);

  k_hstats<<<dim3(25, Bb), 256, 0, stream>>>(E2, ws + W_PEENC, ws + W_LNPART);
  k_statsfin<<<dim3(1), 64, 0, stream>>>(ws + W_LNPART, ws + W_MEANR);
  k_lnmlpkv_mfma<<<dim3(25, Bb), 256, 0, stream>>>(E2, ws + W_PEENC, ws + W_MEANR,
                                                   ln_enc_g, ln_enc_b, wpm,
                                                   mlp_b1, mlp_b2, ni_g, ni_b,
                                                   k_b, v_b, keys, vals);

  // ---------------- slot attention ----------------
  k_init_q<<<dim3(36), 256, 0, stream>>>(slots_mu, slots_sigma, slot_noise,
                                         ns_g, ns_b, q_w, q_b, ws + W_SLOTS, ws + W_Q);
  for (int it = 0; it < 3; ++it) {
    if (it == 2)
      k_dots_upd<true><<<dim3(25, Bb), 256, 0, stream>>>(ws + W_Q, keys, vals, attnt,
                                                         ws + W_APART, ws + W_UP2);
    else
      k_dots_upd<false><<<dim3(25, Bb), 256, 0, stream>>>(ws + W_Q, keys, vals, attnt,
                                                          ws + W_APART, ws + W_UP2);
    k_gru_fused<<<dim3(36), 256, 0, stream>>>(ws + W_UP2, ws + W_APART,
                                              ws + W_SLOTS, ws + W_RSUM, ws + W_Q,
                                              gru_wih, gru_whh, gru_bih, gru_bhh,
                                              res_ln_g, res_ln_b, res_w1, res_b1,
                                              res_w2, res_b2, ns_g, ns_b, q_w, q_b);
  }
  k_attn_out<<<dim3(7200), 256, 0, stream>>>(attnt, ws + W_RSUM, out);
  k_slots_out<<<dim3(36), 256, 0, stream>>>(ws + W_SLOTS, out);

  k_ts<<<dim3(900), 256, 0, stream>>>(ws + W_TC, ws + W_SLOTS, ws + W_TS);

  // ---------------- decoder ----------------
  ushort* XA = (ushort*)(ws + W_POOL);
  ushort* XB = XA + (size_t)96 * 32 * HWp;
  for (int ch = 0; ch < 3; ++ch) {
    int n0 = ch * 96;
    k_conv_mfma<2, true><<<dim3(25, 96), 256, 0, stream>>>(base, wp + 4 * WPSTR, dec_b2, XA,
                                                           ws + W_TS, n0);
    k_conv_mfma<1, true><<<dim3(25, 96), 256, 0, stream>>>(XA, wp + 5 * WPSTR, dec_b3, XB,
                                                           nullptr, 0);
    k_conv4<<<dim3(25, 96), 256, 0, stream>>>(XB, dec_w4, dec_b4,
                                              out + O_RECON, out + O_MASK, n0);
  }

  k_final<<<dim3(25, Bb), 256, 0, stream>>>(out);
}